// Round 1
// baseline (14850.229 us; speedup 1.0000x reference)
//
#include <hip/hip_runtime.h>
#include <math.h>

// Problem constants (match reference)
#define NB    4096   // batch
#define NV    120    // NVAR
#define NCN   240    // num constraints
#define HIDD  1024   // GRU hidden
#define RINN  1080   // GRU input dim
#define NOUTD 360    // NC+NVAR
#define NITER 8
#define REGEPS 1e-4f
#define NPART 64     // partial blocks for G reduction

// ---------------------------------------------------------------------------
// Build A = H + C^T C + REG*I (which==0) and A0 = H + REG*I (which==1)
__global__ void k_buildA(const float* __restrict__ H, const float* __restrict__ C,
                         float* __restrict__ A, float* __restrict__ A0) {
    int i = blockIdx.x;
    int which = blockIdx.y;
    for (int j = threadIdx.x; j < NV; j += blockDim.x) {
        float v = H[i*NV + j] + (i == j ? REGEPS : 0.f);
        if (which == 0) {
            float acc = 0.f;
            for (int k = 0; k < NCN; ++k) acc += C[k*NV + i] * C[k*NV + j];
            A[i*NV + j] = v + acc;   // RHO = 1
        } else {
            A0[i*NV + j] = v;
        }
    }
}

// In-place Gauss-Jordan inverse of a 120x120 SPD matrix (one block per matrix).
__global__ __launch_bounds__(256) void k_invert(const float* __restrict__ Ain,
                                                const float* __restrict__ A0in,
                                                float* __restrict__ Qi,
                                                float* __restrict__ Qi0) {
    __shared__ float M[NV][NV + 1];
    __shared__ float fac[NV];
    const float* src = (blockIdx.x == 0) ? Ain : A0in;
    float* dst = (blockIdx.x == 0) ? Qi : Qi0;
    int t = threadIdx.x;
    for (int idx = t; idx < NV*NV; idx += 256) M[idx/NV][idx%NV] = src[idx];
    __syncthreads();
    for (int k = 0; k < NV; ++k) {
        for (int i = t; i < NV; i += 256) fac[i] = M[i][k];
        __syncthreads();
        float p = 1.0f / fac[k];
        for (int j = t; j < NV; j += 256) M[k][j] = (j == k) ? p : M[k][j] * p;
        __syncthreads();
        for (int idx = t; idx < NV*NV; idx += 256) {
            int i = idx / NV, j = idx % NV;
            if (i != k) {
                M[i][j] = (j == k) ? (-fac[i] * p) : (M[i][j] - fac[i] * M[k][j]);
            }
        }
        __syncthreads();
    }
    for (int idx = t; idx < NV*NV; idx += 256) dst[idx] = M[idx/NV][idx%NV];
}

// xi0 = (-g) @ Qinv0^T ; s0 = max(0, c - C xi0)   (batch-constant vectors)
__global__ void k_s0(const float* __restrict__ Qi0, const float* __restrict__ g,
                     const float* __restrict__ C, const float* __restrict__ c,
                     float* __restrict__ s0v) {
    __shared__ float xi0[NV];
    int t = threadIdx.x;
    if (t < NV) {
        float a = 0.f;
        for (int j = 0; j < NV; ++j) a += Qi0[t*NV + j] * g[j];
        xi0[t] = -a;
    }
    __syncthreads();
    if (t < NCN) {
        float a = 0.f;
        for (int j = 0; j < NV; ++j) a += C[t*NV + j] * xi0[j];
        s0v[t] = fmaxf(0.f, c[t] - a);
    }
}

// Initialize state: s = broadcast(s0), lam = lamda_init, h = h_0
__global__ void k_init(const float* __restrict__ s0v, const float* __restrict__ lam0,
                       const float* __restrict__ h0,
                       float* __restrict__ s, float* __restrict__ lam, float* __restrict__ h) {
    int b0 = blockIdx.x * 8;
    int t = threadIdx.x;
    for (int idx = t; idx < 8*NCN; idx += 256) {
        int m = idx / NCN, k = idx % NCN;
        s[(size_t)(b0 + m)*NCN + k] = s0v[k];
    }
    for (int idx = t; idx < 8*NV; idx += 256) lam[(size_t)b0*NV + idx] = lam0[(size_t)b0*NV + idx];
    for (int idx = t; idx < 8*HIDD; idx += 256) h[(size_t)b0*HIDD + idx] = h0[(size_t)b0*HIDD + idx];
}

// xi = (lam - g + (c-s)@C) @ Qinv ; also Y = xi@H, w = xi@g   (16 batches/block)
__global__ __launch_bounds__(256) void k_xi(const float* __restrict__ s, const float* __restrict__ lam,
                    const float* __restrict__ C, const float* __restrict__ c,
                    const float* __restrict__ g, const float* __restrict__ Qi,
                    const float* __restrict__ H,
                    float* __restrict__ xi, float* __restrict__ Y, float* __restrict__ wv) {
    __shared__ float bd[16][NCN];
    __shared__ float ul[16][NV];
    __shared__ float xl[16][NV];
    int b0 = blockIdx.x * 16;
    int t = threadIdx.x;
    for (int idx = t; idx < 16*NCN; idx += 256) {
        int m = idx / NCN, k = idx % NCN;
        bd[m][k] = c[k] - s[(size_t)(b0 + m)*NCN + k];
    }
    __syncthreads();
    for (int idx = t; idx < 16*NV; idx += 256) {
        int m = idx / NV, j = idx % NV;
        float a = lam[(size_t)(b0 + m)*NV + j] - g[j];
        for (int k = 0; k < NCN; ++k) a += bd[m][k] * C[k*NV + j];
        ul[m][j] = a;
    }
    __syncthreads();
    for (int idx = t; idx < 16*NV; idx += 256) {
        int m = idx / NV, i = idx % NV;
        float a = 0.f;
        for (int j = 0; j < NV; ++j) a += Qi[j*NV + i] * ul[m][j];  // Qinv symmetric
        xl[m][i] = a;
        xi[(size_t)(b0 + m)*NV + i] = a;
    }
    __syncthreads();
    for (int idx = t; idx < 16*NV; idx += 256) {
        int m = idx / NV, i = idx % NV;
        float a = 0.f;
        for (int j = 0; j < NV; ++j) a += xl[m][j] * H[j*NV + i];
        Y[(size_t)(b0 + m)*NV + i] = a;
    }
    if (t < 16) {
        float a = 0.f;
        for (int j = 0; j < NV; ++j) a += xl[t][j] * g[j];
        wv[b0 + t] = a;
    }
}

// Axi, s_new, res_norm, lam_new ; also builds GRU input r (all 6 blocks)
__global__ __launch_bounds__(256) void k_proj(const float* __restrict__ xi, const float* __restrict__ s,
                      const float* __restrict__ lam, const float* __restrict__ C,
                      const float* __restrict__ c,
                      float* __restrict__ snew, float* __restrict__ lamn,
                      float* __restrict__ r, float* __restrict__ primal) {
    __shared__ float xl[16][NV];
    __shared__ float resl[16][NCN];
    int b0 = blockIdx.x * 16;
    int t = threadIdx.x;
    for (int idx = t; idx < 16*NV; idx += 256) xl[idx/NV][idx%NV] = xi[(size_t)b0*NV + idx];
    __syncthreads();
    for (int idx = t; idx < 16*NCN; idx += 256) {
        int m = idx / NCN, k = idx % NCN;
        float a = 0.f;
        for (int j = 0; j < NV; ++j) a += C[k*NV + j] * xl[m][j];
        float sn = fmaxf(0.f, c[k] - a);
        float rv = a - c[k] + sn;
        resl[m][k] = rv;
        int b = b0 + m;
        snew[(size_t)b*NCN + k] = sn;
        float so = s[(size_t)b*NCN + k];
        r[(size_t)b*RINN + k]       = so;
        r[(size_t)b*RINN + 360 + k] = sn;
        r[(size_t)b*RINN + 720 + k] = sn - so;
    }
    __syncthreads();
    if (t < 16) {
        float a = 0.f;
        for (int k = 0; k < NCN; ++k) a += resl[t][k] * resl[t][k];
        primal[b0 + t] = sqrtf(a);
    }
    for (int idx = t; idx < 16*NV; idx += 256) {
        int m = idx / NV, i = idx % NV;
        float a = 0.f;
        for (int k = 0; k < NCN; ++k) a += resl[m][k] * C[k*NV + i];
        int b = b0 + m;
        float lo = lam[(size_t)b*NV + i];
        float ln = lo - a;
        lamn[(size_t)b*NV + i] = ln;
        r[(size_t)b*RINN + 240 + i] = lo;
        r[(size_t)b*RINN + 600 + i] = ln;
        r[(size_t)b*RINN + 960 + i] = ln - lo;
    }
}

// Partial Gram: G_p = sum_m xi_m xi_m^T, v_p = sum_m w_m xi_m, S_p = sum w^2 (64 batches/block)
__global__ __launch_bounds__(256) void k_qp_part(const float* __restrict__ xi, const float* __restrict__ wv,
                         double* __restrict__ Gp, double* __restrict__ vp, double* __restrict__ Sp) {
    __shared__ float xl[64][NV];
    __shared__ float wl[64];
    int p = blockIdx.x;
    int b0 = p * 64;
    int t = threadIdx.x;
    for (int idx = t; idx < 64*NV; idx += 256) xl[idx/NV][idx%NV] = xi[(size_t)b0*NV + idx];
    if (t < 64) wl[t] = wv[b0 + t];
    __syncthreads();
    for (int idx = t; idx < NV*NV; idx += 256) {
        int i = idx / NV, j = idx % NV;
        double a = 0.0;
        for (int m = 0; m < 64; ++m) a += (double)xl[m][i] * (double)xl[m][j];
        Gp[(size_t)p*NV*NV + idx] = a;
    }
    if (t < NV) {
        double a = 0.0;
        for (int m = 0; m < 64; ++m) a += (double)wl[m] * (double)xl[m][t];
        vp[(size_t)p*NV + t] = a;
    }
    if (t == 0) {
        double a = 0.0;
        for (int m = 0; m < 64; ++m) a += (double)wl[m] * (double)wl[m];
        Sp[p] = a;
    }
}

__global__ void k_qp_red(const double* __restrict__ Gp, const double* __restrict__ vp,
                         const double* __restrict__ Sp,
                         double* __restrict__ G, double* __restrict__ v, double* __restrict__ S) {
    int idx = blockIdx.x * 256 + threadIdx.x;
    if (idx < NV*NV) {
        double a = 0.0;
        for (int p = 0; p < NPART; ++p) a += Gp[(size_t)p*NV*NV + idx];
        G[idx] = a;
    }
    if (idx < NV) {
        double a = 0.0;
        for (int p = 0; p < NPART; ++p) a += vp[(size_t)p*NV + idx];
        v[idx] = a;
    }
    if (idx == 0) {
        double a = 0.0;
        for (int p = 0; p < NPART; ++p) a += Sp[p];
        S[0] = a;
    }
}

// qp_norm[b] = sqrt(0.25*Y^T G Y + Y.v + S)
__global__ __launch_bounds__(256) void k_qp_norm(const float* __restrict__ Y, const double* __restrict__ G,
                         const double* __restrict__ v, const double* __restrict__ S,
                         float* __restrict__ qp) {
    __shared__ float Yl[16][NV];
    __shared__ double tl[16][NV];
    int b0 = blockIdx.x * 16;
    int t = threadIdx.x;
    for (int idx = t; idx < 16*NV; idx += 256) Yl[idx/NV][idx%NV] = Y[(size_t)b0*NV + idx];
    __syncthreads();
    for (int idx = t; idx < 16*NV; idx += 256) {
        int m = idx / NV, i = idx % NV;
        double a = 0.0;
        for (int j = 0; j < NV; ++j) a += G[j*NV + i] * (double)Yl[m][j];  // G symmetric
        tl[m][i] = a;
    }
    __syncthreads();
    if (t < 16) {
        double a = 0.0, bv = 0.0;
        for (int i = 0; i < NV; ++i) { a += (double)Yl[t][i] * tl[t][i]; bv += (double)Yl[t][i] * v[i]; }
        double q = 0.25 * a + bv + S[0];
        qp[b0 + t] = (float)sqrt(q > 0.0 ? q : 0.0);
    }
}

// Fused GRU cell: h_next = GRUCell(r, h). BM=64 rows x BN=32 cols per block.
#define GBM 64
#define GBN 32
#define GBK 16
__global__ __launch_bounds__(256) void k_gru(
        const float* __restrict__ r, const float* __restrict__ h,
        const float* __restrict__ Wih, const float* __restrict__ Whh,
        const float* __restrict__ bih, const float* __restrict__ bhh,
        float* __restrict__ hn) {
    __shared__ float As[GBK][GBM + 4];
    __shared__ float Ws[3][GBK][GBN + 4];
    int b0 = blockIdx.x * GBM;
    int n0 = blockIdx.y * GBN;
    int t = threadIdx.x;
    int tx = t % GBN;      // col within BN
    int ty = t / GBN;      // 0..7 -> row group of 8
    float aR[8] = {0}, aZ[8] = {0}, aN[8] = {0};
    float hR[8] = {0}, hZ[8] = {0}, hN[8] = {0};

    // Phase 1: gi partials over K = RIN
    for (int k0 = 0; k0 < RINN; k0 += GBK) {
        for (int idx = t; idx < GBM*GBK; idx += 256) {
            int m = idx / GBK, kk = idx % GBK;
            int kg = k0 + kk;
            As[kk][m] = (kg < RINN) ? r[(size_t)(b0 + m)*RINN + kg] : 0.f;
        }
        for (int idx = t; idx < 3*GBN*GBK; idx += 256) {
            int gs = idx / (GBN*GBK);
            int rem = idx % (GBN*GBK);
            int n = rem / GBK, kk = rem % GBK;
            int kg = k0 + kk;
            Ws[gs][kk][n] = (kg < RINN) ? Wih[(size_t)(gs*HIDD + n0 + n)*RINN + kg] : 0.f;
        }
        __syncthreads();
        #pragma unroll
        for (int kk = 0; kk < GBK; ++kk) {
            float w0 = Ws[0][kk][tx], w1 = Ws[1][kk][tx], w2 = Ws[2][kk][tx];
            #pragma unroll
            for (int rr = 0; rr < 8; ++rr) {
                float av = As[kk][ty*8 + rr];
                aR[rr] += av * w0; aZ[rr] += av * w1; aN[rr] += av * w2;
            }
        }
        __syncthreads();
    }
    // Phase 2: gh partials over K = HID
    for (int k0 = 0; k0 < HIDD; k0 += GBK) {
        for (int idx = t; idx < GBM*GBK; idx += 256) {
            int m = idx / GBK, kk = idx % GBK;
            As[kk][m] = h[(size_t)(b0 + m)*HIDD + k0 + kk];
        }
        for (int idx = t; idx < 3*GBN*GBK; idx += 256) {
            int gs = idx / (GBN*GBK);
            int rem = idx % (GBN*GBK);
            int n = rem / GBK, kk = rem % GBK;
            Ws[gs][kk][n] = Whh[(size_t)(gs*HIDD + n0 + n)*HIDD + k0 + kk];
        }
        __syncthreads();
        #pragma unroll
        for (int kk = 0; kk < GBK; ++kk) {
            float w0 = Ws[0][kk][tx], w1 = Ws[1][kk][tx], w2 = Ws[2][kk][tx];
            #pragma unroll
            for (int rr = 0; rr < 8; ++rr) {
                float av = As[kk][ty*8 + rr];
                hR[rr] += av * w0; hZ[rr] += av * w1; hN[rr] += av * w2;
            }
        }
        __syncthreads();
    }
    int j = n0 + tx;
    float bir = bih[j], biz = bih[HIDD + j], bin = bih[2*HIDD + j];
    float bhr = bhh[j], bhz = bhh[HIDD + j], bhn = bhh[2*HIDD + j];
    #pragma unroll
    for (int rr = 0; rr < 8; ++rr) {
        int m = b0 + ty*8 + rr;
        float rg = 1.f / (1.f + expf(-((aR[rr] + bir) + (hR[rr] + bhr))));
        float zg = 1.f / (1.f + expf(-((aZ[rr] + biz) + (hZ[rr] + bhz))));
        float ng = tanhf((aN[rr] + bin) + rg * (hN[rr] + bhn));
        float hv = h[(size_t)m*HIDD + j];
        hn[(size_t)m*HIDD + j] = (1.f - zg) * ng + zg * hv;
    }
}

// out = h_new @ W_out^T + b_out   (M=4096, N=360, K=1024)
__global__ __launch_bounds__(256) void k_outg(
        const float* __restrict__ hcur, const float* __restrict__ Wo,
        const float* __restrict__ bo, float* __restrict__ outb) {
    __shared__ float As[GBK][GBM + 4];
    __shared__ float Ws[GBK][GBN + 4];
    int b0 = blockIdx.x * GBM;
    int n0 = blockIdx.y * GBN;
    int t = threadIdx.x;
    int tx = t % GBN, ty = t / GBN;
    float acc[8] = {0};
    for (int k0 = 0; k0 < HIDD; k0 += GBK) {
        for (int idx = t; idx < GBM*GBK; idx += 256) {
            int m = idx / GBK, kk = idx % GBK;
            As[kk][m] = hcur[(size_t)(b0 + m)*HIDD + k0 + kk];
        }
        for (int idx = t; idx < GBN*GBK; idx += 256) {
            int n = idx / GBK, kk = idx % GBK;
            int ng = n0 + n;
            Ws[kk][n] = (ng < NOUTD) ? Wo[(size_t)ng*HIDD + k0 + kk] : 0.f;
        }
        __syncthreads();
        #pragma unroll
        for (int kk = 0; kk < GBK; ++kk) {
            float wv = Ws[kk][tx];
            #pragma unroll
            for (int rr = 0; rr < 8; ++rr) acc[rr] += As[kk][ty*8 + rr] * wv;
        }
        __syncthreads();
    }
    int n = n0 + tx;
    if (n < NOUTD) {
        float bb = bo[n];
        #pragma unroll
        for (int rr = 0; rr < 8; ++rr) {
            int m = b0 + ty*8 + rr;
            outb[(size_t)m*NOUTD + n] = acc[rr] + bb;
        }
    }
}

// s_fin/lam_fin (+ in-place state update) and fixed-point residual norm
__global__ __launch_bounds__(256) void k_fin(const float* __restrict__ snew, const float* __restrict__ lamn,
                     const float* __restrict__ outb,
                     float* __restrict__ s, float* __restrict__ lam,
                     float* __restrict__ fx) {
    __shared__ float redS[16][17];
    __shared__ float redL[16][17];
    int b0 = blockIdx.x * 16;
    int tm = threadIdx.x / 16;
    int tk = threadIdx.x % 16;
    int b = b0 + tm;
    float ds2 = 0.f, dl2 = 0.f;
    for (int k = tk; k < NCN; k += 16) {
        float o = outb[(size_t)b*NOUTD + k];
        float sf = fmaxf(0.f, snew[(size_t)b*NCN + k] + o);
        float so = s[(size_t)b*NCN + k];
        s[(size_t)b*NCN + k] = sf;
        float d = so - sf;
        ds2 += d * d;
    }
    for (int i = tk; i < NV; i += 16) {
        float o = outb[(size_t)b*NOUTD + NCN + i];
        float lf = lamn[(size_t)b*NV + i] + o;
        float lo = lam[(size_t)b*NV + i];
        lam[(size_t)b*NV + i] = lf;
        float d = lo - lf;
        dl2 += d * d;
    }
    redS[tm][tk] = ds2;
    redL[tm][tk] = dl2;
    __syncthreads();
    if (tk == 0) {
        float a = 0.f, l = 0.f;
        for (int q = 0; q < 16; ++q) { a += redS[tm][q]; l += redL[tm][q]; }
        fx[b] = sqrtf(l) + sqrtf(a);
    }
}

// ---------------------------------------------------------------------------
extern "C" void kernel_launch(void* const* d_in, const int* in_sizes, int n_in,
                              void* d_out, int out_size, void* d_ws, size_t ws_size,
                              hipStream_t stream) {
    const float* lamda_init = (const float*)d_in[0];
    // d_in[1] = s_init (unused: multiplied by 0 in reference)
    const float* h0    = (const float*)d_in[2];
    const float* H     = (const float*)d_in[3];
    const float* g     = (const float*)d_in[4];
    const float* C     = (const float*)d_in[5];
    const float* c     = (const float*)d_in[6];
    const float* W_ih  = (const float*)d_in[7];
    const float* b_ih  = (const float*)d_in[8];
    const float* W_hh  = (const float*)d_in[9];
    const float* b_hh  = (const float*)d_in[10];
    const float* W_out = (const float*)d_in[11];
    const float* b_out = (const float*)d_in[12];

    float* out    = (float*)d_out;
    float* xi_out = out;                       // [B,120]
    float* primal = out + (size_t)NB*NV;       // [8,B]
    float* fixedo = primal + (size_t)NITER*NB; // [8,B]
    float* qpres  = fixedo + (size_t)NITER*NB; // [8,B]

    // workspace carve-out (~81 MB total)
    char* wp = (char*)d_ws;
    auto alloc = [&](size_t nfloats) {
        float* p = (float*)wp;
        wp += ((nfloats*sizeof(float) + 255) / 256) * 256;
        return p;
    };
    float* Amat  = alloc(NV*NV);
    float* A0m   = alloc(NV*NV);
    float* Qinv  = alloc(NV*NV);
    float* Qinv0 = alloc(NV*NV);
    float* s0v   = alloc(NCN);
    float* sbuf  = alloc((size_t)NB*NCN);
    float* snew  = alloc((size_t)NB*NCN);
    float* lam   = alloc((size_t)NB*NV);
    float* lamn  = alloc((size_t)NB*NV);
    float* hA    = alloc((size_t)NB*HIDD);
    float* hB    = alloc((size_t)NB*HIDD);
    float* xib   = alloc((size_t)NB*NV);
    float* Yb    = alloc((size_t)NB*NV);
    float* wb    = alloc(NB);
    float* rbuf  = alloc((size_t)NB*RINN);
    float* outb  = alloc((size_t)NB*NOUTD);
    double* Gpart = (double*)alloc((size_t)NPART*NV*NV*2);
    double* vpart = (double*)alloc((size_t)NPART*NV*2);
    double* Spart = (double*)alloc(NPART*2);
    double* Gfin  = (double*)alloc(NV*NV*2);
    double* vfin  = (double*)alloc(NV*2);
    double* Sfin  = (double*)alloc(2);

    k_buildA<<<dim3(NV, 2), dim3(128), 0, stream>>>(H, C, Amat, A0m);
    k_invert<<<dim3(2), dim3(256), 0, stream>>>(Amat, A0m, Qinv, Qinv0);
    k_s0<<<dim3(1), dim3(256), 0, stream>>>(Qinv0, g, C, c, s0v);
    k_init<<<dim3(NB/8), dim3(256), 0, stream>>>(s0v, lamda_init, h0, sbuf, lam, hA);

    float* hcur = hA;
    float* hnxt = hB;
    for (int it = 0; it < NITER; ++it) {
        k_xi<<<dim3(NB/16), dim3(256), 0, stream>>>(sbuf, lam, C, c, g, Qinv, H, xib, Yb, wb);
        k_proj<<<dim3(NB/16), dim3(256), 0, stream>>>(xib, sbuf, lam, C, c, snew, lamn, rbuf, primal + (size_t)it*NB);
        k_qp_part<<<dim3(NPART), dim3(256), 0, stream>>>(xib, wb, Gpart, vpart, Spart);
        k_qp_red<<<dim3((NV*NV + 255)/256), dim3(256), 0, stream>>>(Gpart, vpart, Spart, Gfin, vfin, Sfin);
        k_qp_norm<<<dim3(NB/16), dim3(256), 0, stream>>>(Yb, Gfin, vfin, Sfin, qpres + (size_t)it*NB);
        k_gru<<<dim3(NB/GBM, HIDD/GBN), dim3(256), 0, stream>>>(rbuf, hcur, W_ih, W_hh, b_ih, b_hh, hnxt);
        k_outg<<<dim3(NB/GBM, (NOUTD + GBN - 1)/GBN), dim3(256), 0, stream>>>(hnxt, W_out, b_out, outb);
        k_fin<<<dim3(NB/16), dim3(256), 0, stream>>>(snew, lamn, outb, sbuf, lam, fixedo + (size_t)it*NB);
        float* tmp = hcur; hcur = hnxt; hnxt = tmp;
    }
    hipMemcpyAsync(xi_out, xib, (size_t)NB*NV*sizeof(float), hipMemcpyDeviceToDevice, stream);
}

// Round 3
// 5140.149 us; speedup vs baseline: 2.8891x; 2.8891x over previous
//
#include <hip/hip_runtime.h>
#include <hip/hip_bf16.h>
#include <math.h>

// Problem constants (match reference)
#define NB    4096   // batch
#define NV    120    // NVAR
#define NCN   240    // num constraints
#define HIDD  1024   // GRU hidden
#define RINN  1080   // GRU input dim
#define NOUTD 360    // NC+NVAR
#define NOUTP 384    // padded out cols
#define NITER 8
#define REGEPS 1e-4f
#define NPART 64     // partial blocks for G reduction

#define KP1 3264     // 3 * 1088 (r packed, padded)
#define KP2 3072     // 3 * 1024 (h packed)

typedef unsigned short u16;
typedef __attribute__((ext_vector_type(8))) short short8v;
typedef __attribute__((ext_vector_type(4))) float f32x4;

__device__ inline u16 f2b(float x) {
    __hip_bfloat16 h = __float2bfloat16(x);
    return __builtin_bit_cast(u16, h);
}
__device__ inline float b2f(u16 u) {
    __hip_bfloat16 h = __builtin_bit_cast(__hip_bfloat16, u);
    return __bfloat162float(h);
}

// ---------------------------------------------------------------------------
// Build A = H + C^T C + REG*I (which==0) and A0 = H + REG*I (which==1)
__global__ void k_buildA(const float* __restrict__ H, const float* __restrict__ C,
                         float* __restrict__ A, float* __restrict__ A0) {
    int i = blockIdx.x;
    int which = blockIdx.y;
    for (int j = threadIdx.x; j < NV; j += blockDim.x) {
        float v = H[i*NV + j] + (i == j ? REGEPS : 0.f);
        if (which == 0) {
            float acc = 0.f;
            for (int k = 0; k < NCN; ++k) acc += C[k*NV + i] * C[k*NV + j];
            A[i*NV + j] = v + acc;   // RHO = 1
        } else {
            A0[i*NV + j] = v;
        }
    }
}

// In-place Gauss-Jordan inverse of a 120x120 SPD matrix (one block per matrix).
__global__ __launch_bounds__(256) void k_invert(const float* __restrict__ Ain,
                                                const float* __restrict__ A0in,
                                                float* __restrict__ Qi,
                                                float* __restrict__ Qi0) {
    __shared__ float M[NV][NV + 1];
    __shared__ float fac[NV];
    const float* src = (blockIdx.x == 0) ? Ain : A0in;
    float* dst = (blockIdx.x == 0) ? Qi : Qi0;
    int t = threadIdx.x;
    for (int idx = t; idx < NV*NV; idx += 256) M[idx/NV][idx%NV] = src[idx];
    __syncthreads();
    for (int k = 0; k < NV; ++k) {
        for (int i = t; i < NV; i += 256) fac[i] = M[i][k];
        __syncthreads();
        float p = 1.0f / fac[k];
        for (int j = t; j < NV; j += 256) M[k][j] = (j == k) ? p : M[k][j] * p;
        __syncthreads();
        for (int idx = t; idx < NV*NV; idx += 256) {
            int i = idx / NV, j = idx % NV;
            if (i != k) {
                M[i][j] = (j == k) ? (-fac[i] * p) : (M[i][j] - fac[i] * M[k][j]);
            }
        }
        __syncthreads();
    }
    for (int idx = t; idx < NV*NV; idx += 256) dst[idx] = M[idx/NV][idx%NV];
}

// xi0 = (-g) @ Qinv0^T ; s0 = max(0, c - C xi0)   (batch-constant vectors)
__global__ void k_s0(const float* __restrict__ Qi0, const float* __restrict__ g,
                     const float* __restrict__ C, const float* __restrict__ c,
                     float* __restrict__ s0v) {
    __shared__ float xi0[NV];
    int t = threadIdx.x;
    if (t < NV) {
        float a = 0.f;
        for (int j = 0; j < NV; ++j) a += Qi0[t*NV + j] * g[j];
        xi0[t] = -a;
    }
    __syncthreads();
    if (t < NCN) {
        float a = 0.f;
        for (int j = 0; j < NV; ++j) a += C[t*NV + j] * xi0[j];
        s0v[t] = fmaxf(0.f, c[t] - a);
    }
}

// Initialize state: s = broadcast(s0), lam = lamda_init
__global__ void k_init(const float* __restrict__ s0v, const float* __restrict__ lam0,
                       float* __restrict__ s, float* __restrict__ lam) {
    int b0 = blockIdx.x * 8;
    int t = threadIdx.x;
    for (int idx = t; idx < 8*NCN; idx += 256) {
        int m = idx / NCN, k = idx % NCN;
        s[(size_t)(b0 + m)*NCN + k] = s0v[k];
    }
    for (int idx = t; idx < 8*NV; idx += 256) lam[(size_t)b0*NV + idx] = lam0[(size_t)b0*NV + idx];
}

// Pack ACTIVATION f32 [nsrc x Ks] into split-bf16 [rows x 3*Kp] = [hi | hi | lo]
__global__ void k_packA(const float* __restrict__ src, u16* __restrict__ dst,
                        int nsrc, int Ks, int Kp) {
    int n = blockIdx.x;
    size_t row = (size_t)n * 3 * Kp;
    for (int k = threadIdx.x; k < Kp; k += 256) {
        float x = (n < nsrc && k < Ks) ? src[(size_t)n * Ks + k] : 0.f;
        u16 hi = f2b(x);
        u16 lo = f2b(x - b2f(hi));
        dst[row + k] = hi;
        dst[row + Kp + k] = hi;
        dst[row + 2 * Kp + k] = lo;
    }
}

// Pack WEIGHT f32 [nsrc x Ks] into split-bf16 [rows x 3*Kp] = [hi | lo | hi]
// Paired with activation layout [hi|hi|lo]:
//   dot = a_hi.w_hi + a_hi.w_lo + a_lo.w_hi  ~=  a.w  (error ~ a_lo.w_lo)
__global__ void k_packW(const float* __restrict__ src, u16* __restrict__ dst,
                        int nsrc, int Ks, int Kp) {
    int n = blockIdx.x;
    size_t row = (size_t)n * 3 * Kp;
    for (int k = threadIdx.x; k < Kp; k += 256) {
        float x = (n < nsrc && k < Ks) ? src[(size_t)n * Ks + k] : 0.f;
        u16 hi = f2b(x);
        u16 lo = f2b(x - b2f(hi));
        dst[row + k] = hi;
        dst[row + Kp + k] = lo;
        dst[row + 2 * Kp + k] = hi;
    }
}

// xi = (lam - g + (c-s)@C) @ Qinv ; also Y = xi@H, w = xi@g   (16 batches/block)
__global__ __launch_bounds__(256) void k_xi(const float* __restrict__ s, const float* __restrict__ lam,
                    const float* __restrict__ C, const float* __restrict__ c,
                    const float* __restrict__ g, const float* __restrict__ Qi,
                    const float* __restrict__ H,
                    float* __restrict__ xi, float* __restrict__ Y, float* __restrict__ wv) {
    __shared__ float bd[16][NCN];
    __shared__ float ul[16][NV];
    __shared__ float xl[16][NV];
    int b0 = blockIdx.x * 16;
    int t = threadIdx.x;
    for (int idx = t; idx < 16*NCN; idx += 256) {
        int m = idx / NCN, k = idx % NCN;
        bd[m][k] = c[k] - s[(size_t)(b0 + m)*NCN + k];
    }
    __syncthreads();
    for (int idx = t; idx < 16*NV; idx += 256) {
        int m = idx / NV, j = idx % NV;
        float a = lam[(size_t)(b0 + m)*NV + j] - g[j];
        for (int k = 0; k < NCN; ++k) a += bd[m][k] * C[k*NV + j];
        ul[m][j] = a;
    }
    __syncthreads();
    for (int idx = t; idx < 16*NV; idx += 256) {
        int m = idx / NV, i = idx % NV;
        float a = 0.f;
        for (int j = 0; j < NV; ++j) a += Qi[j*NV + i] * ul[m][j];  // Qinv symmetric
        xl[m][i] = a;
        xi[(size_t)(b0 + m)*NV + i] = a;
    }
    __syncthreads();
    for (int idx = t; idx < 16*NV; idx += 256) {
        int m = idx / NV, i = idx % NV;
        float a = 0.f;
        for (int j = 0; j < NV; ++j) a += xl[m][j] * H[j*NV + i];
        Y[(size_t)(b0 + m)*NV + i] = a;
    }
    if (t < 16) {
        float a = 0.f;
        for (int j = 0; j < NV; ++j) a += xl[t][j] * g[j];
        wv[b0 + t] = a;
    }
}

__device__ inline void write3(u16* __restrict__ rpk, size_t base, int pos, float x) {
    u16 hi = f2b(x);
    u16 lo = f2b(x - b2f(hi));
    rpk[base + pos] = hi;
    rpk[base + 1088 + pos] = hi;
    rpk[base + 2176 + pos] = lo;
}

// Axi, s_new, res_norm, lam_new ; builds packed GRU input r (split bf16)
__global__ __launch_bounds__(256) void k_proj(const float* __restrict__ xi, const float* __restrict__ s,
                      const float* __restrict__ lam, const float* __restrict__ C,
                      const float* __restrict__ c,
                      float* __restrict__ snew, float* __restrict__ lamn,
                      u16* __restrict__ rpk, float* __restrict__ primal) {
    __shared__ float xl[16][NV];
    __shared__ float resl[16][NCN];
    int b0 = blockIdx.x * 16;
    int t = threadIdx.x;
    for (int idx = t; idx < 16*NV; idx += 256) xl[idx/NV][idx%NV] = xi[(size_t)b0*NV + idx];
    __syncthreads();
    for (int idx = t; idx < 16*NCN; idx += 256) {
        int m = idx / NCN, k = idx % NCN;
        float a = 0.f;
        for (int j = 0; j < NV; ++j) a += C[k*NV + j] * xl[m][j];
        float sn = fmaxf(0.f, c[k] - a);
        float rv = a - c[k] + sn;
        resl[m][k] = rv;
        int b = b0 + m;
        snew[(size_t)b*NCN + k] = sn;
        float so = s[(size_t)b*NCN + k];
        size_t base = (size_t)b * KP1;
        write3(rpk, base, k, so);
        write3(rpk, base, 360 + k, sn);
        write3(rpk, base, 720 + k, sn - so);
    }
    __syncthreads();
    if (t < 16) {
        float a = 0.f;
        for (int k = 0; k < NCN; ++k) a += resl[t][k] * resl[t][k];
        primal[b0 + t] = sqrtf(a);
    }
    for (int idx = t; idx < 16*NV; idx += 256) {
        int m = idx / NV, i = idx % NV;
        float a = 0.f;
        for (int k = 0; k < NCN; ++k) a += resl[m][k] * C[k*NV + i];
        int b = b0 + m;
        float lo = lam[(size_t)b*NV + i];
        float ln = lo - a;
        lamn[(size_t)b*NV + i] = ln;
        size_t base = (size_t)b * KP1;
        write3(rpk, base, 240 + i, lo);
        write3(rpk, base, 600 + i, ln);
        write3(rpk, base, 960 + i, ln - lo);
    }
    // zero the K pads (1080..1087 of each section)
    for (int idx = t; idx < 16*8; idx += 256) {
        int m = idx >> 3, k = 1080 + (idx & 7);
        size_t base = (size_t)(b0 + m) * KP1;
        rpk[base + k] = 0;
        rpk[base + 1088 + k] = 0;
        rpk[base + 2176 + k] = 0;
    }
}

// Partial Gram: G_p = sum_m xi_m xi_m^T, v_p = sum_m w_m xi_m, S_p = sum w^2
__global__ __launch_bounds__(256) void k_qp_part(const float* __restrict__ xi, const float* __restrict__ wv,
                         double* __restrict__ Gp, double* __restrict__ vp, double* __restrict__ Sp) {
    __shared__ float xl[64][NV];
    __shared__ float wl[64];
    int p = blockIdx.x;
    int b0 = p * 64;
    int t = threadIdx.x;
    for (int idx = t; idx < 64*NV; idx += 256) xl[idx/NV][idx%NV] = xi[(size_t)b0*NV + idx];
    if (t < 64) wl[t] = wv[b0 + t];
    __syncthreads();
    for (int idx = t; idx < NV*NV; idx += 256) {
        int i = idx / NV, j = idx % NV;
        double a = 0.0;
        for (int m = 0; m < 64; ++m) a += (double)xl[m][i] * (double)xl[m][j];
        Gp[(size_t)p*NV*NV + idx] = a;
    }
    if (t < NV) {
        double a = 0.0;
        for (int m = 0; m < 64; ++m) a += (double)wl[m] * (double)xl[m][t];
        vp[(size_t)p*NV + t] = a;
    }
    if (t == 0) {
        double a = 0.0;
        for (int m = 0; m < 64; ++m) a += (double)wl[m] * (double)wl[m];
        Sp[p] = a;
    }
}

__global__ void k_qp_red(const double* __restrict__ Gp, const double* __restrict__ vp,
                         const double* __restrict__ Sp,
                         double* __restrict__ G, double* __restrict__ v, double* __restrict__ S) {
    int idx = blockIdx.x * 256 + threadIdx.x;
    if (idx < NV*NV) {
        double a = 0.0;
        for (int p = 0; p < NPART; ++p) a += Gp[(size_t)p*NV*NV + idx];
        G[idx] = a;
    }
    if (idx < NV) {
        double a = 0.0;
        for (int p = 0; p < NPART; ++p) a += vp[(size_t)p*NV + idx];
        v[idx] = a;
    }
    if (idx == 0) {
        double a = 0.0;
        for (int p = 0; p < NPART; ++p) a += Sp[p];
        S[0] = a;
    }
}

// qp_norm[b] = sqrt(0.25*Y^T G Y + Y.v + S)
__global__ __launch_bounds__(256) void k_qp_norm(const float* __restrict__ Y, const double* __restrict__ G,
                         const double* __restrict__ v, const double* __restrict__ S,
                         float* __restrict__ qp) {
    __shared__ float Yl[16][NV];
    __shared__ double tl[16][NV];
    int b0 = blockIdx.x * 16;
    int t = threadIdx.x;
    for (int idx = t; idx < 16*NV; idx += 256) Yl[idx/NV][idx%NV] = Y[(size_t)b0*NV + idx];
    __syncthreads();
    for (int idx = t; idx < 16*NV; idx += 256) {
        int m = idx / NV, i = idx % NV;
        double a = 0.0;
        for (int j = 0; j < NV; ++j) a += G[j*NV + i] * (double)Yl[m][j];  // G symmetric
        tl[m][i] = a;
    }
    __syncthreads();
    if (t < 16) {
        double a = 0.0, bv = 0.0;
        for (int i = 0; i < NV; ++i) { a += (double)Yl[t][i] * tl[t][i]; bv += (double)Yl[t][i] * v[i]; }
        double q = 0.25 * a + bv + S[0];
        qp[b0 + t] = (float)sqrt(q > 0.0 ? q : 0.0);
    }
}

// ---------------------------------------------------------------------------
// Fused GRU cell via bf16 MFMA (split precision), tile 128 batch x 32 hid-cols.
__global__ __launch_bounds__(256, 2) void k_gruf(
        const u16* __restrict__ rpk, const u16* __restrict__ hpk,
        const u16* __restrict__ Wih, const u16* __restrict__ Whh,
        const float* __restrict__ bih, const float* __restrict__ bhh,
        u16* __restrict__ hnpk) {
    __shared__ char lds[28672];          // A tile 16KB + 3 B tiles 4KB each
    char* As = lds;
    char* Bs = lds + 16384;
    const int t = threadIdx.x;
    const int lane = t & 63;
    const int wid = t >> 6;
    const int wm = wid >> 1, wn = wid & 1;
    const int m0 = blockIdx.x * 128;
    const int n0 = blockIdx.y * 32;

    f32x4 acc[6][4];
    #pragma unroll
    for (int i = 0; i < 6; ++i) {
        #pragma unroll
        for (int j = 0; j < 4; ++j) {
            f32x4 z = {0.f, 0.f, 0.f, 0.f};
            acc[i][j] = z;
        }
    }

    #pragma unroll
    for (int ph = 0; ph < 2; ++ph) {
        const u16* Ag = ph ? hpk : rpk;
        const u16* Bg = ph ? Whh : Wih;
        const int ldk = ph ? KP2 : KP1;
        const int nk  = ldk >> 6;        // 48 or 51
        const int ab  = ph ? 3 : 0;
        for (int kt = 0; kt < nk; ++kt) {
            const int k0 = kt << 6;
            short8v ar[4], br[3];
            #pragma unroll
            for (int q = 0; q < 4; ++q) {
                int cc = t + (q << 8);
                int rr = cc >> 3, l = cc & 7;
                ar[q] = *(const short8v*)(Ag + (size_t)(m0 + rr) * ldk + k0 + l * 8);
            }
            #pragma unroll
            for (int q = 0; q < 3; ++q) {
                br[q] = *(const short8v*)(Bg + (size_t)(q * 1024 + n0 + (t >> 3)) * ldk + k0 + (t & 7) * 8);
            }
            __syncthreads();             // prior compute done reading LDS
            #pragma unroll
            for (int q = 0; q < 4; ++q) {
                int cc = t + (q << 8);
                int rr = cc >> 3, l = cc & 7;
                *(short8v*)(As + rr * 128 + ((l ^ (rr & 7)) << 4)) = ar[q];
            }
            #pragma unroll
            for (int q = 0; q < 3; ++q) {
                int rb = t >> 3, l = t & 7;
                *(short8v*)(Bs + q * 4096 + rb * 128 + ((l ^ (rb & 7)) << 4)) = br[q];
            }
            __syncthreads();
            #pragma unroll
            for (int s = 0; s < 2; ++s) {
                const int srow = lane & 15;
                const int slot = s * 4 + (lane >> 4);
                short8v af[4];
                #pragma unroll
                for (int fm = 0; fm < 4; ++fm) {
                    int rr = wm * 64 + fm * 16 + srow;
                    af[fm] = *(const short8v*)(As + rr * 128 + (((slot ^ (rr & 7)) & 7) << 4));
                }
                #pragma unroll
                for (int g = 0; g < 3; ++g) {
                    int rb = wn * 16 + srow;
                    short8v bf = *(const short8v*)(Bs + g * 4096 + rb * 128 + (((slot ^ (rb & 7)) & 7) << 4));
                    #pragma unroll
                    for (int fm = 0; fm < 4; ++fm)
                        acc[ab + g][fm] = __builtin_amdgcn_mfma_f32_16x16x32_bf16(af[fm], bf, acc[ab + g][fm], 0, 0, 0);
                }
            }
            __syncthreads();
        }
    }

    const int jj = n0 + wn * 16 + (lane & 15);
    const float bir = bih[jj],        bhr = bhh[jj];
    const float biz = bih[1024 + jj], bhz = bhh[1024 + jj];
    const float bin = bih[2048 + jj], bhn = bhh[2048 + jj];
    #pragma unroll
    for (int fm = 0; fm < 4; ++fm) {
        #pragma unroll
        for (int rg = 0; rg < 4; ++rg) {
            int m = m0 + wm * 64 + fm * 16 + (lane >> 4) * 4 + rg;
            float ir = acc[0][fm][rg], iz = acc[1][fm][rg], inn = acc[2][fm][rg];
            float hr = acc[3][fm][rg], hz = acc[4][fm][rg], hnn = acc[5][fm][rg];
            float rgate = 1.f / (1.f + expf(-(ir + bir + hr + bhr)));
            float zgate = 1.f / (1.f + expf(-(iz + biz + hz + bhz)));
            float ngate = tanhf(inn + bin + rgate * (hnn + bhn));
            size_t base = (size_t)m * KP2;
            float hv = b2f(hpk[base + jj]) + b2f(hpk[base + 2048 + jj]);
            float hnew = (1.f - zgate) * ngate + zgate * hv;
            u16 nh = f2b(hnew);
            u16 nl = f2b(hnew - b2f(nh));
            hnpk[base + jj] = nh;
            hnpk[base + 1024 + jj] = nh;
            hnpk[base + 2048 + jj] = nl;
        }
    }
}

// out = h_new @ W_out^T + b_out via bf16 MFMA; M=4096, N=384(360), K'=3072
__global__ __launch_bounds__(256) void k_outp(
        const u16* __restrict__ hpk, const u16* __restrict__ Wo,
        const float* __restrict__ bo, float* __restrict__ outb) {
    __shared__ char lds[24576];          // A 16KB + B 8KB
    char* As = lds;
    char* Bs = lds + 16384;
    const int t = threadIdx.x, lane = t & 63, wid = t >> 6;
    const int wm = wid >> 1, wn = wid & 1;
    const int m0 = blockIdx.x * 128, n0 = blockIdx.y * 64;
    f32x4 acc[4][2];
    #pragma unroll
    for (int i = 0; i < 4; ++i) {
        #pragma unroll
        for (int j = 0; j < 2; ++j) {
            f32x4 z = {0.f, 0.f, 0.f, 0.f};
            acc[i][j] = z;
        }
    }
    for (int kt = 0; kt < 48; ++kt) {
        const int k0 = kt << 6;
        short8v ar[4], br[2];
        #pragma unroll
        for (int q = 0; q < 4; ++q) {
            int cc = t + (q << 8);
            int rr = cc >> 3, l = cc & 7;
            ar[q] = *(const short8v*)(hpk + (size_t)(m0 + rr) * KP2 + k0 + l * 8);
        }
        #pragma unroll
        for (int q = 0; q < 2; ++q) {
            int cc = t + (q << 8);
            int rb = cc >> 3, l = cc & 7;
            br[q] = *(const short8v*)(Wo + (size_t)(n0 + rb) * KP2 + k0 + l * 8);
        }
        __syncthreads();
        #pragma unroll
        for (int q = 0; q < 4; ++q) {
            int cc = t + (q << 8);
            int rr = cc >> 3, l = cc & 7;
            *(short8v*)(As + rr * 128 + ((l ^ (rr & 7)) << 4)) = ar[q];
        }
        #pragma unroll
        for (int q = 0; q < 2; ++q) {
            int cc = t + (q << 8);
            int rb = cc >> 3, l = cc & 7;
            *(short8v*)(Bs + rb * 128 + ((l ^ (rb & 7)) << 4)) = br[q];
        }
        __syncthreads();
        #pragma unroll
        for (int s = 0; s < 2; ++s) {
            const int srow = lane & 15;
            const int slot = s * 4 + (lane >> 4);
            short8v af[4];
            #pragma unroll
            for (int fm = 0; fm < 4; ++fm) {
                int rr = wm * 64 + fm * 16 + srow;
                af[fm] = *(const short8v*)(As + rr * 128 + (((slot ^ (rr & 7)) & 7) << 4));
            }
            #pragma unroll
            for (int fn = 0; fn < 2; ++fn) {
                int rb = wn * 32 + fn * 16 + srow;
                short8v bf = *(const short8v*)(Bs + rb * 128 + (((slot ^ (rb & 7)) & 7) << 4));
                #pragma unroll
                for (int fm = 0; fm < 4; ++fm)
                    acc[fm][fn] = __builtin_amdgcn_mfma_f32_16x16x32_bf16(af[fm], bf, acc[fm][fn], 0, 0, 0);
            }
        }
        __syncthreads();
    }
    #pragma unroll
    for (int fm = 0; fm < 4; ++fm) {
        #pragma unroll
        for (int fn = 0; fn < 2; ++fn) {
            int n = n0 + wn * 32 + fn * 16 + (lane & 15);
            if (n < NOUTD) {
                float bb = bo[n];
                #pragma unroll
                for (int rg = 0; rg < 4; ++rg) {
                    int m = m0 + wm * 64 + fm * 16 + (lane >> 4) * 4 + rg;
                    outb[(size_t)m * NOUTP + n] = acc[fm][fn][rg] + bb;
                }
            }
        }
    }
}

// s_fin/lam_fin (+ in-place state update) and fixed-point residual norm
__global__ __launch_bounds__(256) void k_fin(const float* __restrict__ snew, const float* __restrict__ lamn,
                     const float* __restrict__ outb,
                     float* __restrict__ s, float* __restrict__ lam,
                     float* __restrict__ fx) {
    __shared__ float redS[16][17];
    __shared__ float redL[16][17];
    int b0 = blockIdx.x * 16;
    int tm = threadIdx.x / 16;
    int tk = threadIdx.x % 16;
    int b = b0 + tm;
    float ds2 = 0.f, dl2 = 0.f;
    for (int k = tk; k < NCN; k += 16) {
        float o = outb[(size_t)b*NOUTP + k];
        float sf = fmaxf(0.f, snew[(size_t)b*NCN + k] + o);
        float so = s[(size_t)b*NCN + k];
        s[(size_t)b*NCN + k] = sf;
        float d = so - sf;
        ds2 += d * d;
    }
    for (int i = tk; i < NV; i += 16) {
        float o = outb[(size_t)b*NOUTP + NCN + i];
        float lf = lamn[(size_t)b*NV + i] + o;
        float lo = lam[(size_t)b*NV + i];
        lam[(size_t)b*NV + i] = lf;
        float d = lo - lf;
        dl2 += d * d;
    }
    redS[tm][tk] = ds2;
    redL[tm][tk] = dl2;
    __syncthreads();
    if (tk == 0) {
        float a = 0.f, l = 0.f;
        for (int q = 0; q < 16; ++q) { a += redS[tm][q]; l += redL[tm][q]; }
        fx[b] = sqrtf(l) + sqrtf(a);
    }
}

// ---------------------------------------------------------------------------
extern "C" void kernel_launch(void* const* d_in, const int* in_sizes, int n_in,
                              void* d_out, int out_size, void* d_ws, size_t ws_size,
                              hipStream_t stream) {
    const float* lamda_init = (const float*)d_in[0];
    // d_in[1] = s_init (unused: multiplied by 0 in reference)
    const float* h0    = (const float*)d_in[2];
    const float* H     = (const float*)d_in[3];
    const float* g     = (const float*)d_in[4];
    const float* C     = (const float*)d_in[5];
    const float* c     = (const float*)d_in[6];
    const float* W_ih  = (const float*)d_in[7];
    const float* b_ih  = (const float*)d_in[8];
    const float* W_hh  = (const float*)d_in[9];
    const float* b_hh  = (const float*)d_in[10];
    const float* W_out = (const float*)d_in[11];
    const float* b_out = (const float*)d_in[12];

    float* out    = (float*)d_out;
    float* xi_out = out;                       // [B,120]
    float* primal = out + (size_t)NB*NV;       // [8,B]
    float* fixedo = primal + (size_t)NITER*NB; // [8,B]
    float* qpres  = fixedo + (size_t)NITER*NB; // [8,B]

    // workspace carve-out (~150 MB total)
    char* wp = (char*)d_ws;
    auto alloc = [&](size_t bytes) {
        void* p = (void*)wp;
        wp += (bytes + 255) & ~(size_t)255;
        return p;
    };
    float* Amat  = (float*)alloc(NV*NV*4);
    float* A0m   = (float*)alloc(NV*NV*4);
    float* Qinv  = (float*)alloc(NV*NV*4);
    float* Qinv0 = (float*)alloc(NV*NV*4);
    float* s0v   = (float*)alloc(NCN*4);
    float* sbuf  = (float*)alloc((size_t)NB*NCN*4);
    float* snew  = (float*)alloc((size_t)NB*NCN*4);
    float* lam   = (float*)alloc((size_t)NB*NV*4);
    float* lamn  = (float*)alloc((size_t)NB*NV*4);
    float* xib   = (float*)alloc((size_t)NB*NV*4);
    float* Yb    = (float*)alloc((size_t)NB*NV*4);
    float* wb    = (float*)alloc(NB*4);
    float* outb  = (float*)alloc((size_t)NB*NOUTP*4);
    u16* rpk     = (u16*)alloc((size_t)NB*KP1*2);
    u16* hpkA    = (u16*)alloc((size_t)NB*KP2*2);
    u16* hpkB    = (u16*)alloc((size_t)NB*KP2*2);
    u16* Wihpk   = (u16*)alloc((size_t)3072*KP1*2);
    u16* Whhpk   = (u16*)alloc((size_t)3072*KP2*2);
    u16* Wopk    = (u16*)alloc((size_t)NOUTP*KP2*2);
    double* Gpart = (double*)alloc((size_t)NPART*NV*NV*8);
    double* vpart = (double*)alloc((size_t)NPART*NV*8);
    double* Spart = (double*)alloc(NPART*8);
    double* Gfin  = (double*)alloc(NV*NV*8);
    double* vfin  = (double*)alloc(NV*8);
    double* Sfin  = (double*)alloc(8);

    k_buildA<<<dim3(NV, 2), dim3(128), 0, stream>>>(H, C, Amat, A0m);
    k_invert<<<dim3(2), dim3(256), 0, stream>>>(Amat, A0m, Qinv, Qinv0);
    k_s0<<<dim3(1), dim3(256), 0, stream>>>(Qinv0, g, C, c, s0v);
    k_init<<<dim3(NB/8), dim3(256), 0, stream>>>(s0v, lamda_init, sbuf, lam);
    k_packW<<<dim3(3072), dim3(256), 0, stream>>>(W_ih, Wihpk, 3072, RINN, 1088);
    k_packW<<<dim3(3072), dim3(256), 0, stream>>>(W_hh, Whhpk, 3072, HIDD, 1024);
    k_packW<<<dim3(NOUTP), dim3(256), 0, stream>>>(W_out, Wopk, NOUTD, HIDD, 1024);
    k_packA<<<dim3(NB), dim3(256), 0, stream>>>(h0, hpkA, NB, HIDD, 1024);

    u16* hc = hpkA;
    u16* hn2 = hpkB;
    for (int it = 0; it < NITER; ++it) {
        k_xi<<<dim3(NB/16), dim3(256), 0, stream>>>(sbuf, lam, C, c, g, Qinv, H, xib, Yb, wb);
        k_proj<<<dim3(NB/16), dim3(256), 0, stream>>>(xib, sbuf, lam, C, c, snew, lamn, rpk, primal + (size_t)it*NB);
        k_qp_part<<<dim3(NPART), dim3(256), 0, stream>>>(xib, wb, Gpart, vpart, Spart);
        k_qp_red<<<dim3((NV*NV + 255)/256), dim3(256), 0, stream>>>(Gpart, vpart, Spart, Gfin, vfin, Sfin);
        k_qp_norm<<<dim3(NB/16), dim3(256), 0, stream>>>(Yb, Gfin, vfin, Sfin, qpres + (size_t)it*NB);
        k_gruf<<<dim3(NB/128, HIDD/32), dim3(256), 0, stream>>>(rpk, hc, Wihpk, Whhpk, b_ih, b_hh, hn2);
        k_outp<<<dim3(NB/128, NOUTP/64), dim3(256), 0, stream>>>(hn2, Wopk, b_out, outb);
        k_fin<<<dim3(NB/16), dim3(256), 0, stream>>>(snew, lamn, outb, sbuf, lam, fixedo + (size_t)it*NB);
        u16* tmp = hc; hc = hn2; hn2 = tmp;
    }
    hipMemcpyAsync(xi_out, xib, (size_t)NB*NV*sizeof(float), hipMemcpyDeviceToDevice, stream);
}

// Round 4
// 4224.868 us; speedup vs baseline: 3.5150x; 1.2166x over previous
//
#include <hip/hip_runtime.h>
#include <hip/hip_bf16.h>
#include <math.h>

// Problem constants (match reference)
#define NB    4096   // batch
#define NV    120    // NVAR
#define NCN   240    // num constraints
#define HIDD  1024   // GRU hidden
#define RINN  1080   // GRU input dim
#define NOUTD 360    // NC+NVAR
#define NOUTP 384    // padded out cols
#define NITER 8
#define REGEPS 1e-4f
#define NPART 64     // partial blocks for G reduction

#define KP1 3264     // 3 * 1088 (r packed, padded)
#define KP2 3072     // 3 * 1024 (h packed)

typedef unsigned short u16;
typedef __attribute__((ext_vector_type(8))) short short8v;
typedef __attribute__((ext_vector_type(4))) float f32x4;

__device__ inline u16 f2b(float x) {
    __hip_bfloat16 h = __float2bfloat16(x);
    return __builtin_bit_cast(u16, h);
}
__device__ inline float b2f(u16 u) {
    __hip_bfloat16 h = __builtin_bit_cast(__hip_bfloat16, u);
    return __bfloat162float(h);
}

// ---------------------------------------------------------------------------
// Build A = H + C^T C + REG*I (which==0) and A0 = H + REG*I (which==1)
__global__ void k_buildA(const float* __restrict__ H, const float* __restrict__ C,
                         float* __restrict__ A, float* __restrict__ A0) {
    int i = blockIdx.x;
    int which = blockIdx.y;
    for (int j = threadIdx.x; j < NV; j += blockDim.x) {
        float v = H[i*NV + j] + (i == j ? REGEPS : 0.f);
        if (which == 0) {
            float acc = 0.f;
            for (int k = 0; k < NCN; ++k) acc += C[k*NV + i] * C[k*NV + j];
            A[i*NV + j] = v + acc;   // RHO = 1
        } else {
            A0[i*NV + j] = v;
        }
    }
}

// Gauss-Jordan inverse of 120x120 SPD matrix, one block per matrix.
// Fused scale+eliminate: 2 barriers/pivot, float4 LDS ops, reg-cached pivot row.
// Row stride 132 floats: 16B-aligned and (i*132)%32 = 4i%32 -> the 4 rows a
// wave touches land on distinct banks (conflict-free b128).
__global__ __launch_bounds__(256) void k_invert(const float* __restrict__ Ain,
                                                const float* __restrict__ A0in,
                                                float* __restrict__ Qi,
                                                float* __restrict__ Qi0) {
    __shared__ float M[NV][132];
    const float* src = (blockIdx.x == 0) ? Ain : A0in;
    float* dst = (blockIdx.x == 0) ? Qi : Qi0;
    const int t = threadIdx.x;
    for (int idx = t; idx < NV*132; idx += 256) {
        int i = idx / 132, j = idx - i*132;
        M[i][j] = (j < NV) ? src[i*NV + j] : 0.f;
    }
    __syncthreads();
    const int ty = t >> 4, tx = t & 15;
    for (int k = 0; k < NV; ++k) {
        float p = 1.0f / M[k][k];
        float facp[8];
        #pragma unroll
        for (int q = 0; q < 8; ++q) {
            int i = ty + 16*q;
            facp[q] = (i < NV) ? M[i][k] * p : 0.f;
        }
        float4 rowk[2];
        #pragma unroll
        for (int r = 0; r < 2; ++r)
            rowk[r] = *(const float4*)&M[k][4*tx + 64*r];
        __syncthreads();
        #pragma unroll
        for (int q = 0; q < 8; ++q) {
            int i = ty + 16*q;
            if (i < NV) {
                #pragma unroll
                for (int r = 0; r < 2; ++r) {
                    int g4 = 4*tx + 64*r;
                    float4 v = *(const float4*)&M[i][g4];
                    if (i == k) {
                        v.x = rowk[r].x * p; v.y = rowk[r].y * p;
                        v.z = rowk[r].z * p; v.w = rowk[r].w * p;
                    } else {
                        v.x -= facp[q]*rowk[r].x; v.y -= facp[q]*rowk[r].y;
                        v.z -= facp[q]*rowk[r].z; v.w -= facp[q]*rowk[r].w;
                    }
                    int kc = k - g4;   // column-k fixup if k in this group
                    if (kc >= 0 && kc < 4) {
                        float nk = (i == k) ? p : -facp[q];
                        if (kc == 0) v.x = nk;
                        else if (kc == 1) v.y = nk;
                        else if (kc == 2) v.z = nk;
                        else v.w = nk;
                    }
                    *(float4*)&M[i][g4] = v;
                }
            }
        }
        __syncthreads();
    }
    for (int idx = t; idx < NV*NV; idx += 256) {
        int i = idx / NV, j = idx - i*NV;
        dst[idx] = M[i][j];
    }
}

// xi0 = (-g) @ Qinv0^T ; s0 = max(0, c - C xi0)   (batch-constant vectors)
__global__ void k_s0(const float* __restrict__ Qi0, const float* __restrict__ g,
                     const float* __restrict__ C, const float* __restrict__ c,
                     float* __restrict__ s0v) {
    __shared__ float xi0[NV];
    int t = threadIdx.x;
    if (t < NV) {
        float a = 0.f;
        for (int j = 0; j < NV; ++j) a += Qi0[t*NV + j] * g[j];
        xi0[t] = -a;
    }
    __syncthreads();
    if (t < NCN) {
        float a = 0.f;
        for (int j = 0; j < NV; ++j) a += C[t*NV + j] * xi0[j];
        s0v[t] = fmaxf(0.f, c[t] - a);
    }
}

// Initialize state: s = broadcast(s0), lam = lamda_init
__global__ void k_init(const float* __restrict__ s0v, const float* __restrict__ lam0,
                       float* __restrict__ s, float* __restrict__ lam) {
    int b0 = blockIdx.x * 8;
    int t = threadIdx.x;
    for (int idx = t; idx < 8*NCN; idx += 256) {
        int m = idx / NCN, k = idx % NCN;
        s[(size_t)(b0 + m)*NCN + k] = s0v[k];
    }
    for (int idx = t; idx < 8*NV; idx += 256) lam[(size_t)b0*NV + idx] = lam0[(size_t)b0*NV + idx];
}

// Pack ACTIVATION f32 [nsrc x Ks] into split-bf16 [rows x 3*Kp] = [hi | hi | lo]
__global__ void k_packA(const float* __restrict__ src, u16* __restrict__ dst,
                        int nsrc, int Ks, int Kp) {
    int n = blockIdx.x;
    size_t row = (size_t)n * 3 * Kp;
    for (int k = threadIdx.x; k < Kp; k += 256) {
        float x = (n < nsrc && k < Ks) ? src[(size_t)n * Ks + k] : 0.f;
        u16 hi = f2b(x);
        u16 lo = f2b(x - b2f(hi));
        dst[row + k] = hi;
        dst[row + Kp + k] = hi;
        dst[row + 2 * Kp + k] = lo;
    }
}

// Pack WEIGHT f32 [nsrc x Ks] into split-bf16 [rows x 3*Kp] = [hi | lo | hi]
// Paired with activation layout [hi|hi|lo]:
//   dot = a_hi.w_hi + a_hi.w_lo + a_lo.w_hi  ~=  a.w  (error ~ a_lo.w_lo)
__global__ void k_packW(const float* __restrict__ src, u16* __restrict__ dst,
                        int nsrc, int Ks, int Kp) {
    int n = blockIdx.x;
    size_t row = (size_t)n * 3 * Kp;
    for (int k = threadIdx.x; k < Kp; k += 256) {
        float x = (n < nsrc && k < Ks) ? src[(size_t)n * Ks + k] : 0.f;
        u16 hi = f2b(x);
        u16 lo = f2b(x - b2f(hi));
        dst[row + k] = hi;
        dst[row + Kp + k] = lo;
        dst[row + 2 * Kp + k] = hi;
    }
}

__device__ inline void write3(u16* __restrict__ rpk, size_t base, int pos, float x) {
    u16 hi = f2b(x);
    u16 lo = f2b(x - b2f(hi));
    rpk[base + pos] = hi;
    rpk[base + 1088 + pos] = hi;
    rpk[base + 2176 + pos] = lo;
}

// Fused: xi solve + projection + GRU-input pack (16 batches/block).
//   xi = (lam - g + (c-s)@C) @ Qinv ; Y = xi@H ; w = xi.g
//   Axi -> s_new, res, primal-norm, lam_new ; rpk = packed GRU input
__global__ __launch_bounds__(256) void k_xiproj(
        const float* __restrict__ s, const float* __restrict__ lam,
        const float* __restrict__ C, const float* __restrict__ c,
        const float* __restrict__ g, const float* __restrict__ Qi,
        const float* __restrict__ H,
        float* __restrict__ xi, float* __restrict__ Y, float* __restrict__ wv,
        float* __restrict__ snew, float* __restrict__ lamn,
        u16* __restrict__ rpk, float* __restrict__ primal) {
    __shared__ float bd[16][NCN];
    __shared__ float ul[16][NV];
    __shared__ float xl[16][NV];
    __shared__ float resl[16][NCN];
    int b0 = blockIdx.x * 16;
    int t = threadIdx.x;
    for (int idx = t; idx < 16*NCN; idx += 256) {
        int m = idx / NCN, k = idx % NCN;
        bd[m][k] = c[k] - s[(size_t)(b0 + m)*NCN + k];
    }
    __syncthreads();
    for (int idx = t; idx < 16*NV; idx += 256) {
        int m = idx / NV, j = idx % NV;
        float a = lam[(size_t)(b0 + m)*NV + j] - g[j];
        for (int k = 0; k < NCN; ++k) a += bd[m][k] * C[k*NV + j];
        ul[m][j] = a;
    }
    __syncthreads();
    for (int idx = t; idx < 16*NV; idx += 256) {
        int m = idx / NV, i = idx % NV;
        float a = 0.f;
        for (int j = 0; j < NV; ++j) a += Qi[j*NV + i] * ul[m][j];  // Qinv symmetric
        xl[m][i] = a;
        xi[(size_t)(b0 + m)*NV + i] = a;
    }
    __syncthreads();
    for (int idx = t; idx < 16*NV; idx += 256) {
        int m = idx / NV, i = idx % NV;
        float a = 0.f;
        for (int j = 0; j < NV; ++j) a += xl[m][j] * H[j*NV + i];
        Y[(size_t)(b0 + m)*NV + i] = a;
    }
    if (t < 16) {
        float a = 0.f;
        for (int j = 0; j < NV; ++j) a += xl[t][j] * g[j];
        wv[b0 + t] = a;
    }
    // projection: Axi, s_new, res; pack s-related GRU inputs
    for (int idx = t; idx < 16*NCN; idx += 256) {
        int m = idx / NCN, k = idx % NCN;
        float a = 0.f;
        for (int j = 0; j < NV; ++j) a += C[k*NV + j] * xl[m][j];
        float sn = fmaxf(0.f, c[k] - a);
        float rv = a - c[k] + sn;
        resl[m][k] = rv;
        int b = b0 + m;
        snew[(size_t)b*NCN + k] = sn;
        float so = s[(size_t)b*NCN + k];
        size_t base = (size_t)b * KP1;
        write3(rpk, base, k, so);
        write3(rpk, base, 360 + k, sn);
        write3(rpk, base, 720 + k, sn - so);
    }
    __syncthreads();
    if (t < 16) {
        float a = 0.f;
        for (int k = 0; k < NCN; ++k) a += resl[t][k] * resl[t][k];
        primal[b0 + t] = sqrtf(a);
    }
    for (int idx = t; idx < 16*NV; idx += 256) {
        int m = idx / NV, i = idx % NV;
        float a = 0.f;
        for (int k = 0; k < NCN; ++k) a += resl[m][k] * C[k*NV + i];
        int b = b0 + m;
        float lo = lam[(size_t)b*NV + i];
        float ln = lo - a;
        lamn[(size_t)b*NV + i] = ln;
        size_t base = (size_t)b * KP1;
        write3(rpk, base, 240 + i, lo);
        write3(rpk, base, 600 + i, ln);
        write3(rpk, base, 960 + i, ln - lo);
    }
    // zero the K pads (1080..1087 of each section)
    for (int idx = t; idx < 16*8; idx += 256) {
        int m = idx >> 3, k = 1080 + (idx & 7);
        size_t base = (size_t)(b0 + m) * KP1;
        rpk[base + k] = 0;
        rpk[base + 1088 + k] = 0;
        rpk[base + 2176 + k] = 0;
    }
}

// Partial Gram: G_p = sum_m xi_m xi_m^T, v_p = sum_m w_m xi_m, S_p = sum w^2
__global__ __launch_bounds__(256) void k_qp_part(const float* __restrict__ xi, const float* __restrict__ wv,
                         double* __restrict__ Gp, double* __restrict__ vp, double* __restrict__ Sp) {
    __shared__ float xl[64][NV];
    __shared__ float wl[64];
    int p = blockIdx.x;
    int b0 = p * 64;
    int t = threadIdx.x;
    for (int idx = t; idx < 64*NV; idx += 256) xl[idx/NV][idx%NV] = xi[(size_t)b0*NV + idx];
    if (t < 64) wl[t] = wv[b0 + t];
    __syncthreads();
    for (int idx = t; idx < NV*NV; idx += 256) {
        int i = idx / NV, j = idx % NV;
        double a = 0.0;
        for (int m = 0; m < 64; ++m) a += (double)xl[m][i] * (double)xl[m][j];
        Gp[(size_t)p*NV*NV + idx] = a;
    }
    if (t < NV) {
        double a = 0.0;
        for (int m = 0; m < 64; ++m) a += (double)wl[m] * (double)xl[m][t];
        vp[(size_t)p*NV + t] = a;
    }
    if (t == 0) {
        double a = 0.0;
        for (int m = 0; m < 64; ++m) a += (double)wl[m] * (double)wl[m];
        Sp[p] = a;
    }
}

__global__ void k_qp_red(const double* __restrict__ Gp, const double* __restrict__ vp,
                         const double* __restrict__ Sp,
                         double* __restrict__ G, double* __restrict__ v, double* __restrict__ S) {
    int idx = blockIdx.x * 256 + threadIdx.x;
    if (idx < NV*NV) {
        double a = 0.0;
        for (int p = 0; p < NPART; ++p) a += Gp[(size_t)p*NV*NV + idx];
        G[idx] = a;
    }
    if (idx < NV) {
        double a = 0.0;
        for (int p = 0; p < NPART; ++p) a += vp[(size_t)p*NV + idx];
        v[idx] = a;
    }
    if (idx == 0) {
        double a = 0.0;
        for (int p = 0; p < NPART; ++p) a += Sp[p];
        S[0] = a;
    }
}

// qp_norm[b] = sqrt(0.25*Y^T G Y + Y.v + S)
__global__ __launch_bounds__(256) void k_qp_norm(const float* __restrict__ Y, const double* __restrict__ G,
                         const double* __restrict__ v, const double* __restrict__ S,
                         float* __restrict__ qp) {
    __shared__ float Yl[16][NV];
    __shared__ double tl[16][NV];
    int b0 = blockIdx.x * 16;
    int t = threadIdx.x;
    for (int idx = t; idx < 16*NV; idx += 256) Yl[idx/NV][idx%NV] = Y[(size_t)b0*NV + idx];
    __syncthreads();
    for (int idx = t; idx < 16*NV; idx += 256) {
        int m = idx / NV, i = idx % NV;
        double a = 0.0;
        for (int j = 0; j < NV; ++j) a += G[j*NV + i] * (double)Yl[m][j];  // G symmetric
        tl[m][i] = a;
    }
    __syncthreads();
    if (t < 16) {
        double a = 0.0, bv = 0.0;
        for (int i = 0; i < NV; ++i) { a += (double)Yl[t][i] * tl[t][i]; bv += (double)Yl[t][i] * v[i]; }
        double q = 0.25 * a + bv + S[0];
        qp[b0 + t] = (float)sqrt(q > 0.0 ? q : 0.0);
    }
}

// ---------------------------------------------------------------------------
// Fused GRU cell via bf16 MFMA (split precision), tile 128 batch x 32 hid-cols.
__global__ __launch_bounds__(256, 2) void k_gruf(
        const u16* __restrict__ rpk, const u16* __restrict__ hpk,
        const u16* __restrict__ Wih, const u16* __restrict__ Whh,
        const float* __restrict__ bih, const float* __restrict__ bhh,
        u16* __restrict__ hnpk) {
    __shared__ char lds[28672];          // A tile 16KB + 3 B tiles 4KB each
    char* As = lds;
    char* Bs = lds + 16384;
    const int t = threadIdx.x;
    const int lane = t & 63;
    const int wid = t >> 6;
    const int wm = wid >> 1, wn = wid & 1;
    const int m0 = blockIdx.x * 128;
    const int n0 = blockIdx.y * 32;

    f32x4 acc[6][4];
    #pragma unroll
    for (int i = 0; i < 6; ++i) {
        #pragma unroll
        for (int j = 0; j < 4; ++j) {
            f32x4 z = {0.f, 0.f, 0.f, 0.f};
            acc[i][j] = z;
        }
    }

    #pragma unroll
    for (int ph = 0; ph < 2; ++ph) {
        const u16* Ag = ph ? hpk : rpk;
        const u16* Bg = ph ? Whh : Wih;
        const int ldk = ph ? KP2 : KP1;
        const int nk  = ldk >> 6;        // 48 or 51
        const int ab  = ph ? 3 : 0;
        for (int kt = 0; kt < nk; ++kt) {
            const int k0 = kt << 6;
            short8v ar[4], br[3];
            #pragma unroll
            for (int q = 0; q < 4; ++q) {
                int cc = t + (q << 8);
                int rr = cc >> 3, l = cc & 7;
                ar[q] = *(const short8v*)(Ag + (size_t)(m0 + rr) * ldk + k0 + l * 8);
            }
            #pragma unroll
            for (int q = 0; q < 3; ++q) {
                br[q] = *(const short8v*)(Bg + (size_t)(q * 1024 + n0 + (t >> 3)) * ldk + k0 + (t & 7) * 8);
            }
            __syncthreads();             // prior MFMA reads done before overwrite
            #pragma unroll
            for (int q = 0; q < 4; ++q) {
                int cc = t + (q << 8);
                int rr = cc >> 3, l = cc & 7;
                *(short8v*)(As + rr * 128 + ((l ^ (rr & 7)) << 4)) = ar[q];
            }
            #pragma unroll
            for (int q = 0; q < 3; ++q) {
                int rb = t >> 3, l = t & 7;
                *(short8v*)(Bs + q * 4096 + rb * 128 + ((l ^ (rb & 7)) << 4)) = br[q];
            }
            __syncthreads();
            #pragma unroll
            for (int s = 0; s < 2; ++s) {
                const int srow = lane & 15;
                const int slot = s * 4 + (lane >> 4);
                short8v af[4];
                #pragma unroll
                for (int fm = 0; fm < 4; ++fm) {
                    int rr = wm * 64 + fm * 16 + srow;
                    af[fm] = *(const short8v*)(As + rr * 128 + (((slot ^ (rr & 7)) & 7) << 4));
                }
                #pragma unroll
                for (int g = 0; g < 3; ++g) {
                    int rb = wn * 16 + srow;
                    short8v bf = *(const short8v*)(Bs + g * 4096 + rb * 128 + (((slot ^ (rb & 7)) & 7) << 4));
                    #pragma unroll
                    for (int fm = 0; fm < 4; ++fm)
                        acc[ab + g][fm] = __builtin_amdgcn_mfma_f32_16x16x32_bf16(af[fm], bf, acc[ab + g][fm], 0, 0, 0);
                }
            }
            // no trailing barrier: next iteration's pre-write barrier orders
        }
    }

    const int jj = n0 + wn * 16 + (lane & 15);
    const float bir = bih[jj],        bhr = bhh[jj];
    const float biz = bih[1024 + jj], bhz = bhh[1024 + jj];
    const float bin = bih[2048 + jj], bhn = bhh[2048 + jj];
    #pragma unroll
    for (int fm = 0; fm < 4; ++fm) {
        #pragma unroll
        for (int rg = 0; rg < 4; ++rg) {
            int m = m0 + wm * 64 + fm * 16 + (lane >> 4) * 4 + rg;
            float ir = acc[0][fm][rg], iz = acc[1][fm][rg], inn = acc[2][fm][rg];
            float hr = acc[3][fm][rg], hz = acc[4][fm][rg], hnn = acc[5][fm][rg];
            float rgate = 1.f / (1.f + expf(-(ir + bir + hr + bhr)));
            float zgate = 1.f / (1.f + expf(-(iz + biz + hz + bhz)));
            float ngate = tanhf(inn + bin + rgate * (hnn + bhn));
            size_t base = (size_t)m * KP2;
            float hv = b2f(hpk[base + jj]) + b2f(hpk[base + 2048 + jj]);
            float hnew = (1.f - zgate) * ngate + zgate * hv;
            u16 nh = f2b(hnew);
            u16 nl = f2b(hnew - b2f(nh));
            hnpk[base + jj] = nh;
            hnpk[base + 1024 + jj] = nh;
            hnpk[base + 2048 + jj] = nl;
        }
    }
}

// out = h_new @ W_out^T + b_out via bf16 MFMA; M=4096, N=384(360), K'=3072
__global__ __launch_bounds__(256) void k_outp(
        const u16* __restrict__ hpk, const u16* __restrict__ Wo,
        const float* __restrict__ bo, float* __restrict__ outb) {
    __shared__ char lds[24576];          // A 16KB + B 8KB
    char* As = lds;
    char* Bs = lds + 16384;
    const int t = threadIdx.x, lane = t & 63, wid = t >> 6;
    const int wm = wid >> 1, wn = wid & 1;
    const int m0 = blockIdx.x * 128, n0 = blockIdx.y * 64;
    f32x4 acc[4][2];
    #pragma unroll
    for (int i = 0; i < 4; ++i) {
        #pragma unroll
        for (int j = 0; j < 2; ++j) {
            f32x4 z = {0.f, 0.f, 0.f, 0.f};
            acc[i][j] = z;
        }
    }
    for (int kt = 0; kt < 48; ++kt) {
        const int k0 = kt << 6;
        short8v ar[4], br[2];
        #pragma unroll
        for (int q = 0; q < 4; ++q) {
            int cc = t + (q << 8);
            int rr = cc >> 3, l = cc & 7;
            ar[q] = *(const short8v*)(hpk + (size_t)(m0 + rr) * KP2 + k0 + l * 8);
        }
        #pragma unroll
        for (int q = 0; q < 2; ++q) {
            int cc = t + (q << 8);
            int rb = cc >> 3, l = cc & 7;
            br[q] = *(const short8v*)(Wo + (size_t)(n0 + rb) * KP2 + k0 + l * 8);
        }
        __syncthreads();
        #pragma unroll
        for (int q = 0; q < 4; ++q) {
            int cc = t + (q << 8);
            int rr = cc >> 3, l = cc & 7;
            *(short8v*)(As + rr * 128 + ((l ^ (rr & 7)) << 4)) = ar[q];
        }
        #pragma unroll
        for (int q = 0; q < 2; ++q) {
            int cc = t + (q << 8);
            int rb = cc >> 3, l = cc & 7;
            *(short8v*)(Bs + rb * 128 + ((l ^ (rb & 7)) << 4)) = br[q];
        }
        __syncthreads();
        #pragma unroll
        for (int s = 0; s < 2; ++s) {
            const int srow = lane & 15;
            const int slot = s * 4 + (lane >> 4);
            short8v af[4];
            #pragma unroll
            for (int fm = 0; fm < 4; ++fm) {
                int rr = wm * 64 + fm * 16 + srow;
                af[fm] = *(const short8v*)(As + rr * 128 + (((slot ^ (rr & 7)) & 7) << 4));
            }
            #pragma unroll
            for (int fn = 0; fn < 2; ++fn) {
                int rb = wn * 32 + fn * 16 + srow;
                short8v bf = *(const short8v*)(Bs + rb * 128 + (((slot ^ (rb & 7)) & 7) << 4));
                #pragma unroll
                for (int fm = 0; fm < 4; ++fm)
                    acc[fm][fn] = __builtin_amdgcn_mfma_f32_16x16x32_bf16(af[fm], bf, acc[fm][fn], 0, 0, 0);
            }
        }
        // no trailing barrier: next iteration's pre-write barrier orders
    }
    #pragma unroll
    for (int fm = 0; fm < 4; ++fm) {
        #pragma unroll
        for (int fn = 0; fn < 2; ++fn) {
            int n = n0 + wn * 32 + fn * 16 + (lane & 15);
            if (n < NOUTD) {
                float bb = bo[n];
                #pragma unroll
                for (int rg = 0; rg < 4; ++rg) {
                    int m = m0 + wm * 64 + fm * 16 + (lane >> 4) * 4 + rg;
                    outb[(size_t)m * NOUTP + n] = acc[fm][fn][rg] + bb;
                }
            }
        }
    }
}

// s_fin/lam_fin (+ in-place state update) and fixed-point residual norm
__global__ __launch_bounds__(256) void k_fin(const float* __restrict__ snew, const float* __restrict__ lamn,
                     const float* __restrict__ outb,
                     float* __restrict__ s, float* __restrict__ lam,
                     float* __restrict__ fx) {
    __shared__ float redS[16][17];
    __shared__ float redL[16][17];
    int b0 = blockIdx.x * 16;
    int tm = threadIdx.x / 16;
    int tk = threadIdx.x % 16;
    int b = b0 + tm;
    float ds2 = 0.f, dl2 = 0.f;
    for (int k = tk; k < NCN; k += 16) {
        float o = outb[(size_t)b*NOUTP + k];
        float sf = fmaxf(0.f, snew[(size_t)b*NCN + k] + o);
        float so = s[(size_t)b*NCN + k];
        s[(size_t)b*NCN + k] = sf;
        float d = so - sf;
        ds2 += d * d;
    }
    for (int i = tk; i < NV; i += 16) {
        float o = outb[(size_t)b*NOUTP + NCN + i];
        float lf = lamn[(size_t)b*NV + i] + o;
        float lo = lam[(size_t)b*NV + i];
        lam[(size_t)b*NV + i] = lf;
        float d = lo - lf;
        dl2 += d * d;
    }
    redS[tm][tk] = ds2;
    redL[tm][tk] = dl2;
    __syncthreads();
    if (tk == 0) {
        float a = 0.f, l = 0.f;
        for (int q = 0; q < 16; ++q) { a += redS[tm][q]; l += redL[tm][q]; }
        fx[b] = sqrtf(l) + sqrtf(a);
    }
}

// ---------------------------------------------------------------------------
extern "C" void kernel_launch(void* const* d_in, const int* in_sizes, int n_in,
                              void* d_out, int out_size, void* d_ws, size_t ws_size,
                              hipStream_t stream) {
    const float* lamda_init = (const float*)d_in[0];
    // d_in[1] = s_init (unused: multiplied by 0 in reference)
    const float* h0    = (const float*)d_in[2];
    const float* H     = (const float*)d_in[3];
    const float* g     = (const float*)d_in[4];
    const float* C     = (const float*)d_in[5];
    const float* c     = (const float*)d_in[6];
    const float* W_ih  = (const float*)d_in[7];
    const float* b_ih  = (const float*)d_in[8];
    const float* W_hh  = (const float*)d_in[9];
    const float* b_hh  = (const float*)d_in[10];
    const float* W_out = (const float*)d_in[11];
    const float* b_out = (const float*)d_in[12];

    float* out    = (float*)d_out;
    float* xi_out = out;                       // [B,120]
    float* primal = out + (size_t)NB*NV;       // [8,B]
    float* fixedo = primal + (size_t)NITER*NB; // [8,B]
    float* qpres  = fixedo + (size_t)NITER*NB; // [8,B]

    // workspace carve-out (~150 MB total)
    char* wp = (char*)d_ws;
    auto alloc = [&](size_t bytes) {
        void* p = (void*)wp;
        wp += (bytes + 255) & ~(size_t)255;
        return p;
    };
    float* Amat  = (float*)alloc(NV*NV*4);
    float* A0m   = (float*)alloc(NV*NV*4);
    float* Qinv  = (float*)alloc(NV*NV*4);
    float* Qinv0 = (float*)alloc(NV*NV*4);
    float* s0v   = (float*)alloc(NCN*4);
    float* sbuf  = (float*)alloc((size_t)NB*NCN*4);
    float* snew  = (float*)alloc((size_t)NB*NCN*4);
    float* lam   = (float*)alloc((size_t)NB*NV*4);
    float* lamn  = (float*)alloc((size_t)NB*NV*4);
    float* xib   = (float*)alloc((size_t)NB*NV*4);
    float* Yb    = (float*)alloc((size_t)NB*NV*4);
    float* wb    = (float*)alloc(NB*4);
    float* outb  = (float*)alloc((size_t)NB*NOUTP*4);
    u16* rpk     = (u16*)alloc((size_t)NB*KP1*2);
    u16* hpkA    = (u16*)alloc((size_t)NB*KP2*2);
    u16* hpkB    = (u16*)alloc((size_t)NB*KP2*2);
    u16* Wihpk   = (u16*)alloc((size_t)3072*KP1*2);
    u16* Whhpk   = (u16*)alloc((size_t)3072*KP2*2);
    u16* Wopk    = (u16*)alloc((size_t)NOUTP*KP2*2);
    double* Gpart = (double*)alloc((size_t)NPART*NV*NV*8);
    double* vpart = (double*)alloc((size_t)NPART*NV*8);
    double* Spart = (double*)alloc(NPART*8);
    double* Gfin  = (double*)alloc(NV*NV*8);
    double* vfin  = (double*)alloc(NV*8);
    double* Sfin  = (double*)alloc(8);

    k_buildA<<<dim3(NV, 2), dim3(128), 0, stream>>>(H, C, Amat, A0m);
    k_invert<<<dim3(2), dim3(256), 0, stream>>>(Amat, A0m, Qinv, Qinv0);
    k_s0<<<dim3(1), dim3(256), 0, stream>>>(Qinv0, g, C, c, s0v);
    k_init<<<dim3(NB/8), dim3(256), 0, stream>>>(s0v, lamda_init, sbuf, lam);
    k_packW<<<dim3(3072), dim3(256), 0, stream>>>(W_ih, Wihpk, 3072, RINN, 1088);
    k_packW<<<dim3(3072), dim3(256), 0, stream>>>(W_hh, Whhpk, 3072, HIDD, 1024);
    k_packW<<<dim3(NOUTP), dim3(256), 0, stream>>>(W_out, Wopk, NOUTD, HIDD, 1024);
    k_packA<<<dim3(NB), dim3(256), 0, stream>>>(h0, hpkA, NB, HIDD, 1024);

    u16* hc = hpkA;
    u16* hn2 = hpkB;
    for (int it = 0; it < NITER; ++it) {
        k_xiproj<<<dim3(NB/16), dim3(256), 0, stream>>>(sbuf, lam, C, c, g, Qinv, H,
                                                        xib, Yb, wb, snew, lamn, rpk,
                                                        primal + (size_t)it*NB);
        k_qp_part<<<dim3(NPART), dim3(256), 0, stream>>>(xib, wb, Gpart, vpart, Spart);
        k_qp_red<<<dim3((NV*NV + 255)/256), dim3(256), 0, stream>>>(Gpart, vpart, Spart, Gfin, vfin, Sfin);
        k_qp_norm<<<dim3(NB/16), dim3(256), 0, stream>>>(Yb, Gfin, vfin, Sfin, qpres + (size_t)it*NB);
        k_gruf<<<dim3(NB/128, HIDD/32), dim3(256), 0, stream>>>(rpk, hc, Wihpk, Whhpk, b_ih, b_hh, hn2);
        k_outp<<<dim3(NB/128, NOUTP/64), dim3(256), 0, stream>>>(hn2, Wopk, b_out, outb);
        k_fin<<<dim3(NB/16), dim3(256), 0, stream>>>(snew, lamn, outb, sbuf, lam, fixedo + (size_t)it*NB);
        u16* tmp = hc; hc = hn2; hn2 = tmp;
    }
    hipMemcpyAsync(xi_out, xib, (size_t)NB*NV*sizeof(float), hipMemcpyDeviceToDevice, stream);
}

// Round 5
// 3997.960 us; speedup vs baseline: 3.7145x; 1.0568x over previous
//
#include <hip/hip_runtime.h>
#include <hip/hip_bf16.h>
#include <math.h>

// Problem constants (match reference)
#define NB    4096   // batch
#define NV    120    // NVAR
#define NCN   240    // num constraints
#define HIDD  1024   // GRU hidden
#define RINN  1080   // GRU input dim
#define NOUTD 360    // NC+NVAR
#define NOUTP 384    // padded out cols
#define NITER 8
#define REGEPS 1e-4f
#define NPART 64     // partial blocks for G reduction

#define KP1 3264     // 3 * 1088 (r packed, padded)
#define KP2 3072     // 3 * 1024 (h packed)

typedef unsigned short u16;
typedef __attribute__((ext_vector_type(8))) short short8v;
typedef __attribute__((ext_vector_type(4))) float f32x4;

__device__ inline u16 f2b(float x) {
    __hip_bfloat16 h = __float2bfloat16(x);
    return __builtin_bit_cast(u16, h);
}
__device__ inline float b2f(u16 u) {
    __hip_bfloat16 h = __builtin_bit_cast(__hip_bfloat16, u);
    return __bfloat162float(h);
}

// ---------------------------------------------------------------------------
// Build A = H + C^T C + REG*I (which==0) and A0 = H + REG*I (which==1)
__global__ void k_buildA(const float* __restrict__ H, const float* __restrict__ C,
                         float* __restrict__ A, float* __restrict__ A0) {
    int i = blockIdx.x;
    int which = blockIdx.y;
    for (int j = threadIdx.x; j < NV; j += blockDim.x) {
        float v = H[i*NV + j] + (i == j ? REGEPS : 0.f);
        if (which == 0) {
            float acc = 0.f;
            for (int k = 0; k < NCN; ++k) acc += C[k*NV + i] * C[k*NV + j];
            A[i*NV + j] = v + acc;   // RHO = 1
        } else {
            A0[i*NV + j] = v;
        }
    }
}

// Row-major 4x4 inverse via 2x2-subdeterminant adjugate (ILP-friendly).
__device__ inline void inv4x4(const float* m, float* inv) {
    float s0 = m[0]*m[5] - m[1]*m[4];
    float s1 = m[0]*m[6] - m[2]*m[4];
    float s2 = m[0]*m[7] - m[3]*m[4];
    float s3 = m[1]*m[6] - m[2]*m[5];
    float s4 = m[1]*m[7] - m[3]*m[5];
    float s5 = m[2]*m[7] - m[3]*m[6];
    float c5 = m[10]*m[15] - m[11]*m[14];
    float c4 = m[9]*m[15] - m[11]*m[13];
    float c3 = m[9]*m[14] - m[10]*m[13];
    float c2 = m[8]*m[15] - m[11]*m[12];
    float c1 = m[8]*m[14] - m[10]*m[12];
    float c0 = m[8]*m[13] - m[9]*m[12];
    float det = s0*c5 - s1*c4 + s2*c3 + s3*c2 - s4*c1 + s5*c0;
    float id = 1.0f / det;
    inv[0]  = ( m[5]*c5 - m[6]*c4 + m[7]*c3) * id;
    inv[1]  = (-m[1]*c5 + m[2]*c4 - m[3]*c3) * id;
    inv[2]  = ( m[13]*s5 - m[14]*s4 + m[15]*s3) * id;
    inv[3]  = (-m[9]*s5 + m[10]*s4 - m[11]*s3) * id;
    inv[4]  = (-m[4]*c5 + m[6]*c2 - m[7]*c1) * id;
    inv[5]  = ( m[0]*c5 - m[2]*c2 + m[3]*c1) * id;
    inv[6]  = (-m[12]*s5 + m[14]*s2 - m[15]*s1) * id;
    inv[7]  = ( m[8]*s5 - m[10]*s2 + m[11]*s1) * id;
    inv[8]  = ( m[4]*c4 - m[5]*c2 + m[7]*c0) * id;
    inv[9]  = (-m[0]*c4 + m[1]*c2 - m[3]*c0) * id;
    inv[10] = ( m[12]*s4 - m[13]*s2 + m[15]*s0) * id;
    inv[11] = (-m[8]*s4 + m[9]*s2 - m[11]*s0) * id;
    inv[12] = (-m[4]*c3 + m[5]*c1 - m[6]*c0) * id;
    inv[13] = ( m[0]*c3 - m[1]*c1 + m[2]*c0) * id;
    inv[14] = (-m[12]*s3 + m[13]*s1 - m[14]*s0) * id;
    inv[15] = ( m[8]*s3 - m[9]*s1 + m[10]*s0) * id;
}

// Blocked (rank-4) Gauss-Jordan inverse of 120x120 SPD matrix; one block per
// matrix. 30 chunks x 2 barriers (vs 120 x 2 scalar pivots). Every thread
// redundantly inverts the 4x4 pivot block (broadcast LDS reads, ~100 ILP
// FLOPs) -> no extra barrier to share B. Rows ty+16q owned by one thread;
// col-groups 4*tx+64r owned by one thread -> each cell read+written by its
// unique owner after the mid-chunk barrier.
__global__ __launch_bounds__(256) void k_invert(const float* __restrict__ Ain,
                                                const float* __restrict__ A0in,
                                                float* __restrict__ Qi,
                                                float* __restrict__ Qi0) {
    __shared__ float M[NV][132];
    const float* src = (blockIdx.x == 0) ? Ain : A0in;
    float* dst = (blockIdx.x == 0) ? Qi : Qi0;
    const int t = threadIdx.x;
    for (int idx = t; idx < NV*132; idx += 256) {
        int i = idx / 132, j = idx - i*132;
        M[i][j] = (j < NV) ? src[i*NV + j] : 0.f;
    }
    __syncthreads();
    const int ty = t >> 4, tx = t & 15;
    for (int kk = 0; kk < NV; kk += 4) {
        // 1. all threads: read A11 (broadcast) and invert it in registers
        float a[16], b[16];
        #pragma unroll
        for (int p = 0; p < 4; ++p) {
            float4 v = *(const float4*)&M[kk + p][kk];
            a[p*4+0] = v.x; a[p*4+1] = v.y; a[p*4+2] = v.z; a[p*4+3] = v.w;
        }
        inv4x4(a, b);
        // 2. stash F = M[i, kk:kk+4] for my 8 rows
        float4 F[8];
        #pragma unroll
        for (int q = 0; q < 8; ++q) {
            int i = ty + 16*q;
            F[q] = (i < NV) ? *(const float4*)&M[i][kk] : float4{0.f,0.f,0.f,0.f};
        }
        // 3. R' = B @ pivot-rows for my 2 col-groups (original values)
        float4 R[2][4];
        #pragma unroll
        for (int r = 0; r < 2; ++r) {
            int g4 = 4*tx + 64*r;
            float4 m0 = *(const float4*)&M[kk+0][g4];
            float4 m1 = *(const float4*)&M[kk+1][g4];
            float4 m2 = *(const float4*)&M[kk+2][g4];
            float4 m3 = *(const float4*)&M[kk+3][g4];
            #pragma unroll
            for (int p = 0; p < 4; ++p) {
                R[r][p].x = b[p*4+0]*m0.x + b[p*4+1]*m1.x + b[p*4+2]*m2.x + b[p*4+3]*m3.x;
                R[r][p].y = b[p*4+0]*m0.y + b[p*4+1]*m1.y + b[p*4+2]*m2.y + b[p*4+3]*m3.y;
                R[r][p].z = b[p*4+0]*m0.z + b[p*4+1]*m1.z + b[p*4+2]*m2.z + b[p*4+3]*m3.z;
                R[r][p].w = b[p*4+0]*m0.w + b[p*4+1]*m1.w + b[p*4+2]*m2.w + b[p*4+3]*m3.w;
            }
        }
        __syncthreads();   // all reads of original M complete
        // 4. write: pivot rows get R' (pivot block -> B);
        //    others: M -= F @ R' (pivot block -> -F @ B)
        #pragma unroll
        for (int q = 0; q < 8; ++q) {
            int i = ty + 16*q;
            if (i < NV) {
                int dp = i - kk;
                bool ispiv = (dp >= 0) && (dp < 4);
                #pragma unroll
                for (int r = 0; r < 2; ++r) {
                    int g4 = 4*tx + 64*r;
                    float4 v;
                    if (ispiv) {
                        v = R[r][dp];
                    } else {
                        v = *(const float4*)&M[i][g4];
                        v.x -= F[q].x*R[r][0].x + F[q].y*R[r][1].x + F[q].z*R[r][2].x + F[q].w*R[r][3].x;
                        v.y -= F[q].x*R[r][0].y + F[q].y*R[r][1].y + F[q].z*R[r][2].y + F[q].w*R[r][3].y;
                        v.z -= F[q].x*R[r][0].z + F[q].y*R[r][1].z + F[q].z*R[r][2].z + F[q].w*R[r][3].z;
                        v.w -= F[q].x*R[r][0].w + F[q].y*R[r][1].w + F[q].z*R[r][2].w + F[q].w*R[r][3].w;
                    }
                    if (g4 == kk) {
                        if (ispiv) {
                            v = float4{b[dp*4+0], b[dp*4+1], b[dp*4+2], b[dp*4+3]};
                        } else {
                            v.x = -(F[q].x*b[0] + F[q].y*b[4] + F[q].z*b[8]  + F[q].w*b[12]);
                            v.y = -(F[q].x*b[1] + F[q].y*b[5] + F[q].z*b[9]  + F[q].w*b[13]);
                            v.z = -(F[q].x*b[2] + F[q].y*b[6] + F[q].z*b[10] + F[q].w*b[14]);
                            v.w = -(F[q].x*b[3] + F[q].y*b[7] + F[q].z*b[11] + F[q].w*b[15]);
                        }
                    }
                    *(float4*)&M[i][g4] = v;
                }
            }
        }
        __syncthreads();
    }
    for (int idx = t; idx < NV*NV; idx += 256) {
        int i = idx / NV, j = idx - i*NV;
        dst[idx] = M[i][j];
    }
}

// xi0 = (-g) @ Qinv0^T ; s0 = max(0, c - C xi0)   (batch-constant vectors)
__global__ void k_s0(const float* __restrict__ Qi0, const float* __restrict__ g,
                     const float* __restrict__ C, const float* __restrict__ c,
                     float* __restrict__ s0v) {
    __shared__ float xi0[NV];
    int t = threadIdx.x;
    if (t < NV) {
        float a = 0.f;
        for (int j = 0; j < NV; ++j) a += Qi0[t*NV + j] * g[j];
        xi0[t] = -a;
    }
    __syncthreads();
    if (t < NCN) {
        float a = 0.f;
        for (int j = 0; j < NV; ++j) a += C[t*NV + j] * xi0[j];
        s0v[t] = fmaxf(0.f, c[t] - a);
    }
}

// Initialize state: s = broadcast(s0), lam = lamda_init
__global__ void k_init(const float* __restrict__ s0v, const float* __restrict__ lam0,
                       float* __restrict__ s, float* __restrict__ lam) {
    int b0 = blockIdx.x * 8;
    int t = threadIdx.x;
    for (int idx = t; idx < 8*NCN; idx += 256) {
        int m = idx / NCN, k = idx % NCN;
        s[(size_t)(b0 + m)*NCN + k] = s0v[k];
    }
    for (int idx = t; idx < 8*NV; idx += 256) lam[(size_t)b0*NV + idx] = lam0[(size_t)b0*NV + idx];
}

// Pack ACTIVATION f32 [nsrc x Ks] into split-bf16 [rows x 3*Kp] = [hi | hi | lo]
__global__ void k_packA(const float* __restrict__ src, u16* __restrict__ dst,
                        int nsrc, int Ks, int Kp) {
    int n = blockIdx.x;
    size_t row = (size_t)n * 3 * Kp;
    for (int k = threadIdx.x; k < Kp; k += 256) {
        float x = (n < nsrc && k < Ks) ? src[(size_t)n * Ks + k] : 0.f;
        u16 hi = f2b(x);
        u16 lo = f2b(x - b2f(hi));
        dst[row + k] = hi;
        dst[row + Kp + k] = hi;
        dst[row + 2 * Kp + k] = lo;
    }
}

// Pack WEIGHT f32 [nsrc x Ks] into split-bf16 [rows x 3*Kp] = [hi | lo | hi]
// Paired with activation layout [hi|hi|lo]:
//   dot = a_hi.w_hi + a_hi.w_lo + a_lo.w_hi  ~=  a.w  (error ~ a_lo.w_lo)
__global__ void k_packW(const float* __restrict__ src, u16* __restrict__ dst,
                        int nsrc, int Ks, int Kp) {
    int n = blockIdx.x;
    size_t row = (size_t)n * 3 * Kp;
    for (int k = threadIdx.x; k < Kp; k += 256) {
        float x = (n < nsrc && k < Ks) ? src[(size_t)n * Ks + k] : 0.f;
        u16 hi = f2b(x);
        u16 lo = f2b(x - b2f(hi));
        dst[row + k] = hi;
        dst[row + Kp + k] = lo;
        dst[row + 2 * Kp + k] = hi;
    }
}

__device__ inline void write3(u16* __restrict__ rpk, size_t base, int pos, float x) {
    u16 hi = f2b(x);
    u16 lo = f2b(x - b2f(hi));
    rpk[base + pos] = hi;
    rpk[base + 1088 + pos] = hi;
    rpk[base + 2176 + pos] = lo;
}

// Fused: xi solve + projection + GRU-input pack (16 batches/block).
__global__ __launch_bounds__(256) void k_xiproj(
        const float* __restrict__ s, const float* __restrict__ lam,
        const float* __restrict__ C, const float* __restrict__ c,
        const float* __restrict__ g, const float* __restrict__ Qi,
        const float* __restrict__ H,
        float* __restrict__ xi, float* __restrict__ Y, float* __restrict__ wv,
        float* __restrict__ snew, float* __restrict__ lamn,
        u16* __restrict__ rpk, float* __restrict__ primal) {
    __shared__ float bd[16][NCN];
    __shared__ float ul[16][NV];
    __shared__ float xl[16][NV];
    __shared__ float resl[16][NCN];
    int b0 = blockIdx.x * 16;
    int t = threadIdx.x;
    for (int idx = t; idx < 16*NCN; idx += 256) {
        int m = idx / NCN, k = idx % NCN;
        bd[m][k] = c[k] - s[(size_t)(b0 + m)*NCN + k];
    }
    __syncthreads();
    for (int idx = t; idx < 16*NV; idx += 256) {
        int m = idx / NV, j = idx % NV;
        float a = lam[(size_t)(b0 + m)*NV + j] - g[j];
        for (int k = 0; k < NCN; ++k) a += bd[m][k] * C[k*NV + j];
        ul[m][j] = a;
    }
    __syncthreads();
    for (int idx = t; idx < 16*NV; idx += 256) {
        int m = idx / NV, i = idx % NV;
        float a = 0.f;
        for (int j = 0; j < NV; ++j) a += Qi[j*NV + i] * ul[m][j];  // Qinv symmetric
        xl[m][i] = a;
        xi[(size_t)(b0 + m)*NV + i] = a;
    }
    __syncthreads();
    for (int idx = t; idx < 16*NV; idx += 256) {
        int m = idx / NV, i = idx % NV;
        float a = 0.f;
        for (int j = 0; j < NV; ++j) a += xl[m][j] * H[j*NV + i];
        Y[(size_t)(b0 + m)*NV + i] = a;
    }
    if (t < 16) {
        float a = 0.f;
        for (int j = 0; j < NV; ++j) a += xl[t][j] * g[j];
        wv[b0 + t] = a;
    }
    for (int idx = t; idx < 16*NCN; idx += 256) {
        int m = idx / NCN, k = idx % NCN;
        float a = 0.f;
        for (int j = 0; j < NV; ++j) a += C[k*NV + j] * xl[m][j];
        float sn = fmaxf(0.f, c[k] - a);
        float rv = a - c[k] + sn;
        resl[m][k] = rv;
        int b = b0 + m;
        snew[(size_t)b*NCN + k] = sn;
        float so = s[(size_t)b*NCN + k];
        size_t base = (size_t)b * KP1;
        write3(rpk, base, k, so);
        write3(rpk, base, 360 + k, sn);
        write3(rpk, base, 720 + k, sn - so);
    }
    __syncthreads();
    if (t < 16) {
        float a = 0.f;
        for (int k = 0; k < NCN; ++k) a += resl[t][k] * resl[t][k];
        primal[b0 + t] = sqrtf(a);
    }
    for (int idx = t; idx < 16*NV; idx += 256) {
        int m = idx / NV, i = idx % NV;
        float a = 0.f;
        for (int k = 0; k < NCN; ++k) a += resl[m][k] * C[k*NV + i];
        int b = b0 + m;
        float lo = lam[(size_t)b*NV + i];
        float ln = lo - a;
        lamn[(size_t)b*NV + i] = ln;
        size_t base = (size_t)b * KP1;
        write3(rpk, base, 240 + i, lo);
        write3(rpk, base, 600 + i, ln);
        write3(rpk, base, 960 + i, ln - lo);
    }
    for (int idx = t; idx < 16*8; idx += 256) {
        int m = idx >> 3, k = 1080 + (idx & 7);
        size_t base = (size_t)(b0 + m) * KP1;
        rpk[base + k] = 0;
        rpk[base + 1088 + k] = 0;
        rpk[base + 2176 + k] = 0;
    }
}

// Partial Gram: G_p = sum_m xi_m xi_m^T, v_p = sum_m w_m xi_m, S_p = sum w^2
__global__ __launch_bounds__(256) void k_qp_part(const float* __restrict__ xi, const float* __restrict__ wv,
                         double* __restrict__ Gp, double* __restrict__ vp, double* __restrict__ Sp) {
    __shared__ float xl[64][NV];
    __shared__ float wl[64];
    int p = blockIdx.x;
    int b0 = p * 64;
    int t = threadIdx.x;
    for (int idx = t; idx < 64*NV; idx += 256) xl[idx/NV][idx%NV] = xi[(size_t)b0*NV + idx];
    if (t < 64) wl[t] = wv[b0 + t];
    __syncthreads();
    for (int idx = t; idx < NV*NV; idx += 256) {
        int i = idx / NV, j = idx % NV;
        double a = 0.0;
        for (int m = 0; m < 64; ++m) a += (double)xl[m][i] * (double)xl[m][j];
        Gp[(size_t)p*NV*NV + idx] = a;
    }
    if (t < NV) {
        double a = 0.0;
        for (int m = 0; m < 64; ++m) a += (double)wl[m] * (double)xl[m][t];
        vp[(size_t)p*NV + t] = a;
    }
    if (t == 0) {
        double a = 0.0;
        for (int m = 0; m < 64; ++m) a += (double)wl[m] * (double)wl[m];
        Sp[p] = a;
    }
}

__global__ void k_qp_red(const double* __restrict__ Gp, const double* __restrict__ vp,
                         const double* __restrict__ Sp,
                         double* __restrict__ G, double* __restrict__ v, double* __restrict__ S) {
    int idx = blockIdx.x * 256 + threadIdx.x;
    if (idx < NV*NV) {
        double a = 0.0;
        for (int p = 0; p < NPART; ++p) a += Gp[(size_t)p*NV*NV + idx];
        G[idx] = a;
    }
    if (idx < NV) {
        double a = 0.0;
        for (int p = 0; p < NPART; ++p) a += vp[(size_t)p*NV + idx];
        v[idx] = a;
    }
    if (idx == 0) {
        double a = 0.0;
        for (int p = 0; p < NPART; ++p) a += Sp[p];
        S[0] = a;
    }
}

// qp_norm[b] = sqrt(0.25*Y^T G Y + Y.v + S)
__global__ __launch_bounds__(256) void k_qp_norm(const float* __restrict__ Y, const double* __restrict__ G,
                         const double* __restrict__ v, const double* __restrict__ S,
                         float* __restrict__ qp) {
    __shared__ float Yl[16][NV];
    __shared__ double tl[16][NV];
    int b0 = blockIdx.x * 16;
    int t = threadIdx.x;
    for (int idx = t; idx < 16*NV; idx += 256) Yl[idx/NV][idx%NV] = Y[(size_t)b0*NV + idx];
    __syncthreads();
    for (int idx = t; idx < 16*NV; idx += 256) {
        int m = idx / NV, i = idx % NV;
        double a = 0.0;
        for (int j = 0; j < NV; ++j) a += G[j*NV + i] * (double)Yl[m][j];  // G symmetric
        tl[m][i] = a;
    }
    __syncthreads();
    if (t < 16) {
        double a = 0.0, bv = 0.0;
        for (int i = 0; i < NV; ++i) { a += (double)Yl[t][i] * tl[t][i]; bv += (double)Yl[t][i] * v[i]; }
        double q = 0.25 * a + bv + S[0];
        qp[b0 + t] = (float)sqrt(q > 0.0 ? q : 0.0);
    }
}

// ---------------------------------------------------------------------------
// Fused GRU cell via bf16 MFMA (split precision).
// Tile 128 batch x 64 hid-cols, 512 threads (8 waves = 2m x 4n), K-step 64.
// Double-buffered LDS (2 x 40KB), ONE barrier per K-step (T3-minimum):
// stage regs loaded a full iteration ahead; ds_write to buf^1 overlaps MFMA
// on buf. XCD-aware swizzle: 2 n-strips per XCD -> weight slice L2-resident.
#define GRUF_MFMA(AB) do {                                                       \
    char* As_ = lds + cur * 40960;                                               \
    char* Bs_ = As_ + 16384;                                                     \
    _Pragma("unroll")                                                            \
    for (int ss = 0; ss < 2; ++ss) {                                             \
        const int srow = lane & 15;                                              \
        const int slot = ss * 4 + (lane >> 4);                                   \
        short8v af[4];                                                           \
        _Pragma("unroll")                                                        \
        for (int fm = 0; fm < 4; ++fm) {                                         \
            int rr = wm * 64 + fm * 16 + srow;                                   \
            af[fm] = *(const short8v*)(As_ + rr * 128 + (((slot ^ (rr & 7)) & 7) << 4)); \
        }                                                                        \
        _Pragma("unroll")                                                        \
        for (int gg = 0; gg < 3; ++gg) {                                         \
            int rb = wn * 16 + srow;                                             \
            short8v bf = *(const short8v*)(Bs_ + gg * 8192 + rb * 128 + (((slot ^ (rb & 7)) & 7) << 4)); \
            _Pragma("unroll")                                                    \
            for (int fm = 0; fm < 4; ++fm)                                       \
                acc[(AB) + gg][fm] = __builtin_amdgcn_mfma_f32_16x16x32_bf16(af[fm], bf, acc[(AB) + gg][fm], 0, 0, 0); \
        }                                                                        \
    }                                                                            \
} while (0)

__global__ __launch_bounds__(512, 2) void k_gruf(
        const u16* __restrict__ rpk, const u16* __restrict__ hpk,
        const u16* __restrict__ Wih, const u16* __restrict__ Whh,
        const float* __restrict__ bih, const float* __restrict__ bhh,
        u16* __restrict__ hnpk) {
    __shared__ char lds[81920];          // 2 x (A 16KB + 3 B-tiles 8KB)
    const int t = threadIdx.x;
    const int lane = t & 63;
    const int wid = t >> 6;              // 0..7
    const int wm = wid >> 2;             // 0..1: 64-row half
    const int wn = wid & 3;              // 0..3: 16-col quarter
    // XCD swizzle: grid 512 = 32 m-blocks x 16 n-strips; 2 n-strips per XCD
    const int wg = blockIdx.x;
    const int xcd = wg & 7, slot_ = wg >> 3;
    const int m0 = (slot_ & 31) * 128;
    const int n0 = (xcd * 2 + (slot_ >> 5)) * 64;

    f32x4 acc[6][4];
    #pragma unroll
    for (int i = 0; i < 6; ++i)
        #pragma unroll
        for (int j = 0; j < 4; ++j) {
            f32x4 z = {0.f, 0.f, 0.f, 0.f};
            acc[i][j] = z;
        }

    short8v arS[2], brS[3];
    const int rl = t & 7;
    const int rb0 = t >> 3;              // 0..63

    auto gload = [&](int step) {
        const u16* Ag; const u16* Bg; int ldk, k0;
        if (step < 51) { Ag = rpk; Bg = Wih; ldk = KP1; k0 = step << 6; }
        else           { Ag = hpk; Bg = Whh; ldk = KP2; k0 = (step - 51) << 6; }
        #pragma unroll
        for (int q = 0; q < 2; ++q) {
            int rr = rb0 + (q << 6);
            arS[q] = *(const short8v*)(Ag + (size_t)(m0 + rr) * ldk + k0 + rl * 8);
        }
        #pragma unroll
        for (int q = 0; q < 3; ++q)
            brS[q] = *(const short8v*)(Bg + (size_t)(q * 1024 + n0 + rb0) * ldk + k0 + rl * 8);
    };
    auto lwrite = [&](int buf) {
        char* As_ = lds + buf * 40960;
        char* Bs_ = As_ + 16384;
        #pragma unroll
        for (int q = 0; q < 2; ++q) {
            int rr = rb0 + (q << 6);
            *(short8v*)(As_ + rr * 128 + ((rl ^ (rr & 7)) << 4)) = arS[q];
        }
        #pragma unroll
        for (int q = 0; q < 3; ++q)
            *(short8v*)(Bs_ + q * 8192 + rb0 * 128 + ((rl ^ (rb0 & 7)) << 4)) = brS[q];
    };

    // prologue: buf0 <- step 0; regs <- step 1
    gload(0);
    lwrite(0);
    gload(1);
    __syncthreads();
    int cur = 0;
    for (int step = 0; step < 51; ++step) {       // phase 0: gi (ab=0)
        if (step < 98) lwrite(cur ^ 1);           // write step+1 (waits its vmcnt)
        if (step < 97) gload(step + 2);           // issue step+2
        GRUF_MFMA(0);
        __syncthreads();
        cur ^= 1;
    }
    for (int step = 51; step < 99; ++step) {      // phase 1: gh (ab=3)
        if (step < 98) lwrite(cur ^ 1);
        if (step < 97) gload(step + 2);
        GRUF_MFMA(3);
        __syncthreads();
        cur ^= 1;
    }

    const int jj = n0 + wn * 16 + (lane & 15);
    const float bir = bih[jj],        bhr = bhh[jj];
    const float biz = bih[1024 + jj], bhz = bhh[1024 + jj];
    const float bin = bih[2048 + jj], bhn = bhh[2048 + jj];
    #pragma unroll
    for (int fm = 0; fm < 4; ++fm) {
        #pragma unroll
        for (int rg = 0; rg < 4; ++rg) {
            int m = m0 + wm * 64 + fm * 16 + (lane >> 4) * 4 + rg;
            float ir = acc[0][fm][rg], iz = acc[1][fm][rg], inn = acc[2][fm][rg];
            float hr = acc[3][fm][rg], hz = acc[4][fm][rg], hnn = acc[5][fm][rg];
            float rgate = 1.f / (1.f + expf(-(ir + bir + hr + bhr)));
            float zgate = 1.f / (1.f + expf(-(iz + biz + hz + bhz)));
            float ngate = tanhf(inn + bin + rgate * (hnn + bhn));
            size_t base = (size_t)m * KP2;
            float hv = b2f(hpk[base + jj]) + b2f(hpk[base + 2048 + jj]);
            float hnew = (1.f - zgate) * ngate + zgate * hv;
            u16 nh = f2b(hnew);
            u16 nl = f2b(hnew - b2f(nh));
            hnpk[base + jj] = nh;
            hnpk[base + 1024 + jj] = nh;
            hnpk[base + 2048 + jj] = nl;
        }
    }
}

// out = h_new @ W_out^T + b_out via bf16 MFMA; M=4096, N=384(360), K'=3072
__global__ __launch_bounds__(256) void k_outp(
        const u16* __restrict__ hpk, const u16* __restrict__ Wo,
        const float* __restrict__ bo, float* __restrict__ outb) {
    __shared__ char lds[24576];          // A 16KB + B 8KB
    char* As = lds;
    char* Bs = lds + 16384;
    const int t = threadIdx.x, lane = t & 63, wid = t >> 6;
    const int wm = wid >> 1, wn = wid & 1;
    const int m0 = blockIdx.x * 128, n0 = blockIdx.y * 64;
    f32x4 acc[4][2];
    #pragma unroll
    for (int i = 0; i < 4; ++i)
        #pragma unroll
        for (int j = 0; j < 2; ++j) {
            f32x4 z = {0.f, 0.f, 0.f, 0.f};
            acc[i][j] = z;
        }
    for (int kt = 0; kt < 48; ++kt) {
        const int k0 = kt << 6;
        short8v ar[4], br[2];
        #pragma unroll
        for (int q = 0; q < 4; ++q) {
            int cc = t + (q << 8);
            int rr = cc >> 3, l = cc & 7;
            ar[q] = *(const short8v*)(hpk + (size_t)(m0 + rr) * KP2 + k0 + l * 8);
        }
        #pragma unroll
        for (int q = 0; q < 2; ++q) {
            int cc = t + (q << 8);
            int rb = cc >> 3, l = cc & 7;
            br[q] = *(const short8v*)(Wo + (size_t)(n0 + rb) * KP2 + k0 + l * 8);
        }
        __syncthreads();
        #pragma unroll
        for (int q = 0; q < 4; ++q) {
            int cc = t + (q << 8);
            int rr = cc >> 3, l = cc & 7;
            *(short8v*)(As + rr * 128 + ((l ^ (rr & 7)) << 4)) = ar[q];
        }
        #pragma unroll
        for (int q = 0; q < 2; ++q) {
            int cc = t + (q << 8);
            int rb = cc >> 3, l = cc & 7;
            *(short8v*)(Bs + rb * 128 + ((l ^ (rb & 7)) << 4)) = br[q];
        }
        __syncthreads();
        #pragma unroll
        for (int s = 0; s < 2; ++s) {
            const int srow = lane & 15;
            const int slot = s * 4 + (lane >> 4);
            short8v af[4];
            #pragma unroll
            for (int fm = 0; fm < 4; ++fm) {
                int rr = wm * 64 + fm * 16 + srow;
                af[fm] = *(const short8v*)(As + rr * 128 + (((slot ^ (rr & 7)) & 7) << 4));
            }
            #pragma unroll
            for (int fn = 0; fn < 2; ++fn) {
                int rb = wn * 32 + fn * 16 + srow;
                short8v bf = *(const short8v*)(Bs + rb * 128 + (((slot ^ (rb & 7)) & 7) << 4));
                #pragma unroll
                for (int fm = 0; fm < 4; ++fm)
                    acc[fm][fn] = __builtin_amdgcn_mfma_f32_16x16x32_bf16(af[fm], bf, acc[fm][fn], 0, 0, 0);
            }
        }
    }
    #pragma unroll
    for (int fm = 0; fm < 4; ++fm) {
        #pragma unroll
        for (int fn = 0; fn < 2; ++fn) {
            int n = n0 + wn * 32 + fn * 16 + (lane & 15);
            if (n < NOUTD) {
                float bb = bo[n];
                #pragma unroll
                for (int rg = 0; rg < 4; ++rg) {
                    int m = m0 + wm * 64 + fm * 16 + (lane >> 4) * 4 + rg;
                    outb[(size_t)m * NOUTP + n] = acc[fm][fn][rg] + bb;
                }
            }
        }
    }
}

// s_fin/lam_fin (+ in-place state update) and fixed-point residual norm
__global__ __launch_bounds__(256) void k_fin(const float* __restrict__ snew, const float* __restrict__ lamn,
                     const float* __restrict__ outb,
                     float* __restrict__ s, float* __restrict__ lam,
                     float* __restrict__ fx) {
    __shared__ float redS[16][17];
    __shared__ float redL[16][17];
    int b0 = blockIdx.x * 16;
    int tm = threadIdx.x / 16;
    int tk = threadIdx.x % 16;
    int b = b0 + tm;
    float ds2 = 0.f, dl2 = 0.f;
    for (int k = tk; k < NCN; k += 16) {
        float o = outb[(size_t)b*NOUTP + k];
        float sf = fmaxf(0.f, snew[(size_t)b*NCN + k] + o);
        float so = s[(size_t)b*NCN + k];
        s[(size_t)b*NCN + k] = sf;
        float d = so - sf;
        ds2 += d * d;
    }
    for (int i = tk; i < NV; i += 16) {
        float o = outb[(size_t)b*NOUTP + NCN + i];
        float lf = lamn[(size_t)b*NV + i] + o;
        float lo = lam[(size_t)b*NV + i];
        lam[(size_t)b*NV + i] = lf;
        float d = lo - lf;
        dl2 += d * d;
    }
    redS[tm][tk] = ds2;
    redL[tm][tk] = dl2;
    __syncthreads();
    if (tk == 0) {
        float a = 0.f, l = 0.f;
        for (int q = 0; q < 16; ++q) { a += redS[tm][q]; l += redL[tm][q]; }
        fx[b] = sqrtf(l) + sqrtf(a);
    }
}

// ---------------------------------------------------------------------------
extern "C" void kernel_launch(void* const* d_in, const int* in_sizes, int n_in,
                              void* d_out, int out_size, void* d_ws, size_t ws_size,
                              hipStream_t stream) {
    const float* lamda_init = (const float*)d_in[0];
    // d_in[1] = s_init (unused: multiplied by 0 in reference)
    const float* h0    = (const float*)d_in[2];
    const float* H     = (const float*)d_in[3];
    const float* g     = (const float*)d_in[4];
    const float* C     = (const float*)d_in[5];
    const float* c     = (const float*)d_in[6];
    const float* W_ih  = (const float*)d_in[7];
    const float* b_ih  = (const float*)d_in[8];
    const float* W_hh  = (const float*)d_in[9];
    const float* b_hh  = (const float*)d_in[10];
    const float* W_out = (const float*)d_in[11];
    const float* b_out = (const float*)d_in[12];

    float* out    = (float*)d_out;
    float* xi_out = out;                       // [B,120]
    float* primal = out + (size_t)NB*NV;       // [8,B]
    float* fixedo = primal + (size_t)NITER*NB; // [8,B]
    float* qpres  = fixedo + (size_t)NITER*NB; // [8,B]

    // workspace carve-out (~150 MB total)
    char* wp = (char*)d_ws;
    auto alloc = [&](size_t bytes) {
        void* p = (void*)wp;
        wp += (bytes + 255) & ~(size_t)255;
        return p;
    };
    float* Amat  = (float*)alloc(NV*NV*4);
    float* A0m   = (float*)alloc(NV*NV*4);
    float* Qinv  = (float*)alloc(NV*NV*4);
    float* Qinv0 = (float*)alloc(NV*NV*4);
    float* s0v   = (float*)alloc(NCN*4);
    float* sbuf  = (float*)alloc((size_t)NB*NCN*4);
    float* snew  = (float*)alloc((size_t)NB*NCN*4);
    float* lam   = (float*)alloc((size_t)NB*NV*4);
    float* lamn  = (float*)alloc((size_t)NB*NV*4);
    float* xib   = (float*)alloc((size_t)NB*NV*4);
    float* Yb    = (float*)alloc((size_t)NB*NV*4);
    float* wb    = (float*)alloc(NB*4);
    float* outb  = (float*)alloc((size_t)NB*NOUTP*4);
    u16* rpk     = (u16*)alloc((size_t)NB*KP1*2);
    u16* hpkA    = (u16*)alloc((size_t)NB*KP2*2);
    u16* hpkB    = (u16*)alloc((size_t)NB*KP2*2);
    u16* Wihpk   = (u16*)alloc((size_t)3072*KP1*2);
    u16* Whhpk   = (u16*)alloc((size_t)3072*KP2*2);
    u16* Wopk    = (u16*)alloc((size_t)NOUTP*KP2*2);
    double* Gpart = (double*)alloc((size_t)NPART*NV*NV*8);
    double* vpart = (double*)alloc((size_t)NPART*NV*8);
    double* Spart = (double*)alloc(NPART*8);
    double* Gfin  = (double*)alloc(NV*NV*8);
    double* vfin  = (double*)alloc(NV*8);
    double* Sfin  = (double*)alloc(8);

    k_buildA<<<dim3(NV, 2), dim3(128), 0, stream>>>(H, C, Amat, A0m);
    k_invert<<<dim3(2), dim3(256), 0, stream>>>(Amat, A0m, Qinv, Qinv0);
    k_s0<<<dim3(1), dim3(256), 0, stream>>>(Qinv0, g, C, c, s0v);
    k_init<<<dim3(NB/8), dim3(256), 0, stream>>>(s0v, lamda_init, sbuf, lam);
    k_packW<<<dim3(3072), dim3(256), 0, stream>>>(W_ih, Wihpk, 3072, RINN, 1088);
    k_packW<<<dim3(3072), dim3(256), 0, stream>>>(W_hh, Whhpk, 3072, HIDD, 1024);
    k_packW<<<dim3(NOUTP), dim3(256), 0, stream>>>(W_out, Wopk, NOUTD, HIDD, 1024);
    k_packA<<<dim3(NB), dim3(256), 0, stream>>>(h0, hpkA, NB, HIDD, 1024);

    u16* hc = hpkA;
    u16* hn2 = hpkB;
    for (int it = 0; it < NITER; ++it) {
        k_xiproj<<<dim3(NB/16), dim3(256), 0, stream>>>(sbuf, lam, C, c, g, Qinv, H,
                                                        xib, Yb, wb, snew, lamn, rpk,
                                                        primal + (size_t)it*NB);
        k_qp_part<<<dim3(NPART), dim3(256), 0, stream>>>(xib, wb, Gpart, vpart, Spart);
        k_qp_red<<<dim3((NV*NV + 255)/256), dim3(256), 0, stream>>>(Gpart, vpart, Spart, Gfin, vfin, Sfin);
        k_qp_norm<<<dim3(NB/16), dim3(256), 0, stream>>>(Yb, Gfin, vfin, Sfin, qpres + (size_t)it*NB);
        k_gruf<<<dim3(512), dim3(512), 0, stream>>>(rpk, hc, Wihpk, Whhpk, b_ih, b_hh, hn2);
        k_outp<<<dim3(NB/128, NOUTP/64), dim3(256), 0, stream>>>(hn2, Wopk, b_out, outb);
        k_fin<<<dim3(NB/16), dim3(256), 0, stream>>>(snew, lamn, outb, sbuf, lam, fixedo + (size_t)it*NB);
        u16* tmp = hc; hc = hn2; hn2 = tmp;
    }
    hipMemcpyAsync(xi_out, xib, (size_t)NB*NV*sizeof(float), hipMemcpyDeviceToDevice, stream);
}

// Round 6
// 2983.952 us; speedup vs baseline: 4.9767x; 1.3398x over previous
//
#include <hip/hip_runtime.h>
#include <hip/hip_bf16.h>
#include <math.h>

// Problem constants (match reference)
#define NB    4096   // batch
#define NV    120    // NVAR
#define NCN   240    // num constraints
#define HIDD  1024   // GRU hidden
#define RINN  1080   // GRU input dim
#define NOUTD 360    // NC+NVAR
#define NOUTP 384    // padded out cols
#define NITER 8
#define REGEPS 1e-4f
#define NPART 128    // partial blocks for G reduction

// 2-term split packing: activations [hi|lo] (exact), weights [hi|hi].
// dot = a_hi.w_hi + a_lo.w_hi = a.w_hi  (systematic ~0.2% weight quant error)
#define KP1 2176     // 2 * 1088 (r packed, padded)
#define KP2 2048     // 2 * 1024 (h packed)

typedef unsigned short u16;
typedef __attribute__((ext_vector_type(8))) short short8v;
typedef __attribute__((ext_vector_type(4))) float f32x4;

__device__ inline u16 f2b(float x) {
    __hip_bfloat16 h = __float2bfloat16(x);
    return __builtin_bit_cast(u16, h);
}
__device__ inline float b2f(u16 u) {
    __hip_bfloat16 h = __builtin_bit_cast(__hip_bfloat16, u);
    return __bfloat162float(h);
}

// ---------------------------------------------------------------------------
// Build A = H + C^T C + REG*I (which==0) and A0 = H + REG*I (which==1)
__global__ void k_buildA(const float* __restrict__ H, const float* __restrict__ C,
                         float* __restrict__ A, float* __restrict__ A0) {
    int i = blockIdx.x;
    int which = blockIdx.y;
    for (int j = threadIdx.x; j < NV; j += blockDim.x) {
        float v = H[i*NV + j] + (i == j ? REGEPS : 0.f);
        if (which == 0) {
            float acc = 0.f;
            for (int k = 0; k < NCN; ++k) acc += C[k*NV + i] * C[k*NV + j];
            A[i*NV + j] = v + acc;   // RHO = 1
        } else {
            A0[i*NV + j] = v;
        }
    }
}

// Row-major 4x4 inverse via 2x2-subdeterminant adjugate (ILP-friendly).
__device__ inline void inv4x4(const float* m, float* inv) {
    float s0 = m[0]*m[5] - m[1]*m[4];
    float s1 = m[0]*m[6] - m[2]*m[4];
    float s2 = m[0]*m[7] - m[3]*m[4];
    float s3 = m[1]*m[6] - m[2]*m[5];
    float s4 = m[1]*m[7] - m[3]*m[5];
    float s5 = m[2]*m[7] - m[3]*m[6];
    float c5 = m[10]*m[15] - m[11]*m[14];
    float c4 = m[9]*m[15] - m[11]*m[13];
    float c3 = m[9]*m[14] - m[10]*m[13];
    float c2 = m[8]*m[15] - m[11]*m[12];
    float c1 = m[8]*m[14] - m[10]*m[12];
    float c0 = m[8]*m[13] - m[9]*m[12];
    float det = s0*c5 - s1*c4 + s2*c3 + s3*c2 - s4*c1 + s5*c0;
    float id = 1.0f / det;
    inv[0]  = ( m[5]*c5 - m[6]*c4 + m[7]*c3) * id;
    inv[1]  = (-m[1]*c5 + m[2]*c4 - m[3]*c3) * id;
    inv[2]  = ( m[13]*s5 - m[14]*s4 + m[15]*s3) * id;
    inv[3]  = (-m[9]*s5 + m[10]*s4 - m[11]*s3) * id;
    inv[4]  = (-m[4]*c5 + m[6]*c2 - m[7]*c1) * id;
    inv[5]  = ( m[0]*c5 - m[2]*c2 + m[3]*c1) * id;
    inv[6]  = (-m[12]*s5 + m[14]*s2 - m[15]*s1) * id;
    inv[7]  = ( m[8]*s5 - m[10]*s2 + m[11]*s1) * id;
    inv[8]  = ( m[4]*c4 - m[5]*c2 + m[7]*c0) * id;
    inv[9]  = (-m[0]*c4 + m[1]*c2 - m[3]*c0) * id;
    inv[10] = ( m[12]*s4 - m[13]*s2 + m[15]*s0) * id;
    inv[11] = (-m[8]*s4 + m[9]*s2 - m[11]*s0) * id;
    inv[12] = (-m[4]*c3 + m[5]*c1 - m[6]*c0) * id;
    inv[13] = ( m[0]*c3 - m[1]*c1 + m[2]*c0) * id;
    inv[14] = (-m[12]*s3 + m[13]*s1 - m[14]*s0) * id;
    inv[15] = ( m[8]*s3 - m[9]*s1 + m[10]*s0) * id;
}

// Blocked (rank-4) Gauss-Jordan inverse of 120x120 SPD matrix; one block per
// matrix. 512 threads (2 waves/SIMD for latency hiding), 4 rows/thread
// (F[4]=16 VGPR live across barrier; round-5's 8-rows/thread spilled to
// scratch: WRITE_SIZE 176KB vs 115KB real). 30 chunks x 2 barriers.
__global__ __launch_bounds__(512) void k_invert(const float* __restrict__ Ain,
                                                const float* __restrict__ A0in,
                                                float* __restrict__ Qi,
                                                float* __restrict__ Qi0) {
    __shared__ float M[NV][132];
    const float* src = (blockIdx.x == 0) ? Ain : A0in;
    float* dst = (blockIdx.x == 0) ? Qi : Qi0;
    const int t = threadIdx.x;
    for (int idx = t; idx < NV*132; idx += 512) {
        int i = idx / 132, j = idx - i*132;
        M[i][j] = (j < NV) ? src[i*NV + j] : 0.f;
    }
    __syncthreads();
    const int ty = t >> 4;       // 0..31 row owner
    const int tx = t & 15;       // col-group owner
    for (int kk = 0; kk < NV; kk += 4) {
        // 1. all threads: read A11 (broadcast) and invert in registers
        float a[16], b[16];
        #pragma unroll
        for (int p = 0; p < 4; ++p) {
            float4 v = *(const float4*)&M[kk + p][kk];
            a[p*4+0] = v.x; a[p*4+1] = v.y; a[p*4+2] = v.z; a[p*4+3] = v.w;
        }
        inv4x4(a, b);
        // 2. stash F = M[i, kk:kk+4] for my 4 rows
        float4 F[4];
        #pragma unroll
        for (int q = 0; q < 4; ++q) {
            int i = ty + 32*q;
            F[q] = (i < NV) ? *(const float4*)&M[i][kk] : float4{0.f,0.f,0.f,0.f};
        }
        // 3. R' = B @ pivot-rows for my 2 col-groups (original values)
        float4 R[2][4];
        #pragma unroll
        for (int r = 0; r < 2; ++r) {
            int g4 = 4*tx + 64*r;
            float4 m0 = *(const float4*)&M[kk+0][g4];
            float4 m1 = *(const float4*)&M[kk+1][g4];
            float4 m2 = *(const float4*)&M[kk+2][g4];
            float4 m3 = *(const float4*)&M[kk+3][g4];
            #pragma unroll
            for (int p = 0; p < 4; ++p) {
                R[r][p].x = b[p*4+0]*m0.x + b[p*4+1]*m1.x + b[p*4+2]*m2.x + b[p*4+3]*m3.x;
                R[r][p].y = b[p*4+0]*m0.y + b[p*4+1]*m1.y + b[p*4+2]*m2.y + b[p*4+3]*m3.y;
                R[r][p].z = b[p*4+0]*m0.z + b[p*4+1]*m1.z + b[p*4+2]*m2.z + b[p*4+3]*m3.z;
                R[r][p].w = b[p*4+0]*m0.w + b[p*4+1]*m1.w + b[p*4+2]*m2.w + b[p*4+3]*m3.w;
            }
        }
        __syncthreads();   // all reads of original M complete
        // 4. write: pivot rows <- R'; others: M -= F @ R'; col-k block special
        #pragma unroll
        for (int q = 0; q < 4; ++q) {
            int i = ty + 32*q;
            if (i < NV) {
                int dp = i - kk;
                bool ispiv = (dp >= 0) && (dp < 4);
                #pragma unroll
                for (int r = 0; r < 2; ++r) {
                    int g4 = 4*tx + 64*r;
                    float4 v;
                    if (ispiv) {
                        v = R[r][dp];
                    } else {
                        v = *(const float4*)&M[i][g4];
                        v.x -= F[q].x*R[r][0].x + F[q].y*R[r][1].x + F[q].z*R[r][2].x + F[q].w*R[r][3].x;
                        v.y -= F[q].x*R[r][0].y + F[q].y*R[r][1].y + F[q].z*R[r][2].y + F[q].w*R[r][3].y;
                        v.z -= F[q].x*R[r][0].z + F[q].y*R[r][1].z + F[q].z*R[r][2].z + F[q].w*R[r][3].z;
                        v.w -= F[q].x*R[r][0].w + F[q].y*R[r][1].w + F[q].z*R[r][2].w + F[q].w*R[r][3].w;
                    }
                    if (g4 == kk) {
                        if (ispiv) {
                            v = float4{b[dp*4+0], b[dp*4+1], b[dp*4+2], b[dp*4+3]};
                        } else {
                            v.x = -(F[q].x*b[0] + F[q].y*b[4] + F[q].z*b[8]  + F[q].w*b[12]);
                            v.y = -(F[q].x*b[1] + F[q].y*b[5] + F[q].z*b[9]  + F[q].w*b[13]);
                            v.z = -(F[q].x*b[2] + F[q].y*b[6] + F[q].z*b[10] + F[q].w*b[14]);
                            v.w = -(F[q].x*b[3] + F[q].y*b[7] + F[q].z*b[11] + F[q].w*b[15]);
                        }
                    }
                    *(float4*)&M[i][g4] = v;
                }
            }
        }
        __syncthreads();
    }
    for (int idx = t; idx < NV*NV; idx += 512) {
        int i = idx / NV, j = idx - i*NV;
        dst[idx] = M[i][j];
    }
}

// xi0 = (-g) @ Qinv0^T ; s0 = max(0, c - C xi0)   (batch-constant vectors)
__global__ void k_s0(const float* __restrict__ Qi0, const float* __restrict__ g,
                     const float* __restrict__ C, const float* __restrict__ c,
                     float* __restrict__ s0v) {
    __shared__ float xi0[NV];
    int t = threadIdx.x;
    if (t < NV) {
        float a = 0.f;
        for (int j = 0; j < NV; ++j) a += Qi0[t*NV + j] * g[j];
        xi0[t] = -a;
    }
    __syncthreads();
    if (t < NCN) {
        float a = 0.f;
        for (int j = 0; j < NV; ++j) a += C[t*NV + j] * xi0[j];
        s0v[t] = fmaxf(0.f, c[t] - a);
    }
}

// Initialize state: s = broadcast(s0), lam = lamda_init
__global__ void k_init(const float* __restrict__ s0v, const float* __restrict__ lam0,
                       float* __restrict__ s, float* __restrict__ lam) {
    int b0 = blockIdx.x * 8;
    int t = threadIdx.x;
    for (int idx = t; idx < 8*NCN; idx += 256) {
        int m = idx / NCN, k = idx % NCN;
        s[(size_t)(b0 + m)*NCN + k] = s0v[k];
    }
    for (int idx = t; idx < 8*NV; idx += 256) lam[(size_t)b0*NV + idx] = lam0[(size_t)b0*NV + idx];
}

// Pack ACTIVATION f32 [nsrc x Ks] into split-bf16 [rows x 2*Kp] = [hi | lo]
__global__ void k_packA(const float* __restrict__ src, u16* __restrict__ dst,
                        int nsrc, int Ks, int Kp) {
    int n = blockIdx.x;
    size_t row = (size_t)n * 2 * Kp;
    for (int k = threadIdx.x; k < Kp; k += 256) {
        float x = (n < nsrc && k < Ks) ? src[(size_t)n * Ks + k] : 0.f;
        u16 hi = f2b(x);
        u16 lo = f2b(x - b2f(hi));
        dst[row + k] = hi;
        dst[row + Kp + k] = lo;
    }
}

// Pack WEIGHT f32 [nsrc x Ks] into split-bf16 [rows x 2*Kp] = [hi | hi]
__global__ void k_packW(const float* __restrict__ src, u16* __restrict__ dst,
                        int nsrc, int Ks, int Kp) {
    int n = blockIdx.x;
    size_t row = (size_t)n * 2 * Kp;
    for (int k = threadIdx.x; k < Kp; k += 256) {
        float x = (n < nsrc && k < Ks) ? src[(size_t)n * Ks + k] : 0.f;
        u16 hi = f2b(x);
        dst[row + k] = hi;
        dst[row + Kp + k] = hi;
    }
}

__device__ inline void write2(u16* __restrict__ rpk, size_t base, int pos, float x) {
    u16 hi = f2b(x);
    u16 lo = f2b(x - b2f(hi));
    rpk[base + pos] = hi;
    rpk[base + 1088 + pos] = lo;
}

// Fused: xi solve + projection + GRU-input pack (16 batches/block, 512 thr).
__global__ __launch_bounds__(512) void k_xiproj(
        const float* __restrict__ s, const float* __restrict__ lam,
        const float* __restrict__ C, const float* __restrict__ c,
        const float* __restrict__ g, const float* __restrict__ Qi,
        const float* __restrict__ H,
        float* __restrict__ xi, float* __restrict__ Y, float* __restrict__ wv,
        float* __restrict__ snew, float* __restrict__ lamn,
        u16* __restrict__ rpk, float* __restrict__ primal) {
    __shared__ float bd[16][NCN];
    __shared__ float ul[16][NV];
    __shared__ float xl[16][NV];
    __shared__ float resl[16][NCN];
    int b0 = blockIdx.x * 16;
    int t = threadIdx.x;
    for (int idx = t; idx < 16*NCN; idx += 512) {
        int m = idx / NCN, k = idx % NCN;
        bd[m][k] = c[k] - s[(size_t)(b0 + m)*NCN + k];
    }
    __syncthreads();
    for (int idx = t; idx < 16*NV; idx += 512) {
        int m = idx / NV, j = idx % NV;
        float a = lam[(size_t)(b0 + m)*NV + j] - g[j];
        for (int k = 0; k < NCN; ++k) a += bd[m][k] * C[k*NV + j];
        ul[m][j] = a;
    }
    __syncthreads();
    for (int idx = t; idx < 16*NV; idx += 512) {
        int m = idx / NV, i = idx % NV;
        float a = 0.f;
        for (int j = 0; j < NV; ++j) a += Qi[j*NV + i] * ul[m][j];  // Qinv symmetric
        xl[m][i] = a;
        xi[(size_t)(b0 + m)*NV + i] = a;
    }
    __syncthreads();
    for (int idx = t; idx < 16*NV; idx += 512) {
        int m = idx / NV, i = idx % NV;
        float a = 0.f;
        for (int j = 0; j < NV; ++j) a += xl[m][j] * H[j*NV + i];
        Y[(size_t)(b0 + m)*NV + i] = a;
    }
    if (t < 16) {
        float a = 0.f;
        for (int j = 0; j < NV; ++j) a += xl[t][j] * g[j];
        wv[b0 + t] = a;
    }
    for (int idx = t; idx < 16*NCN; idx += 512) {
        int m = idx / NCN, k = idx % NCN;
        float a = 0.f;
        for (int j = 0; j < NV; ++j) a += C[k*NV + j] * xl[m][j];
        float sn = fmaxf(0.f, c[k] - a);
        float rv = a - c[k] + sn;
        resl[m][k] = rv;
        int b = b0 + m;
        snew[(size_t)b*NCN + k] = sn;
        float so = s[(size_t)b*NCN + k];
        size_t base = (size_t)b * KP1;
        write2(rpk, base, k, so);
        write2(rpk, base, 360 + k, sn);
        write2(rpk, base, 720 + k, sn - so);
    }
    __syncthreads();
    if (t < 16) {
        float a = 0.f;
        for (int k = 0; k < NCN; ++k) a += resl[t][k] * resl[t][k];
        primal[b0 + t] = sqrtf(a);
    }
    for (int idx = t; idx < 16*NV; idx += 512) {
        int m = idx / NV, i = idx % NV;
        float a = 0.f;
        for (int k = 0; k < NCN; ++k) a += resl[m][k] * C[k*NV + i];
        int b = b0 + m;
        float lo = lam[(size_t)b*NV + i];
        float ln = lo - a;
        lamn[(size_t)b*NV + i] = ln;
        size_t base = (size_t)b * KP1;
        write2(rpk, base, 240 + i, lo);
        write2(rpk, base, 600 + i, ln);
        write2(rpk, base, 960 + i, ln - lo);
    }
    for (int idx = t; idx < 16*8; idx += 512) {
        int m = idx >> 3, k = 1080 + (idx & 7);
        size_t base = (size_t)(b0 + m) * KP1;
        rpk[base + k] = 0;
        rpk[base + 1088 + k] = 0;
    }
}

// Partial Gram: G_p = sum_m xi_m xi_m^T, v_p = sum_m w_m xi_m, S_p = sum w^2
__global__ __launch_bounds__(256) void k_qp_part(const float* __restrict__ xi, const float* __restrict__ wv,
                         double* __restrict__ Gp, double* __restrict__ vp, double* __restrict__ Sp) {
    __shared__ float xl[32][NV];
    __shared__ float wl[32];
    int p = blockIdx.x;
    int b0 = p * 32;
    int t = threadIdx.x;
    for (int idx = t; idx < 32*NV; idx += 256) xl[idx/NV][idx%NV] = xi[(size_t)b0*NV + idx];
    if (t < 32) wl[t] = wv[b0 + t];
    __syncthreads();
    for (int idx = t; idx < NV*NV; idx += 256) {
        int i = idx / NV, j = idx % NV;
        double a = 0.0;
        for (int m = 0; m < 32; ++m) a += (double)xl[m][i] * (double)xl[m][j];
        Gp[(size_t)p*NV*NV + idx] = a;
    }
    if (t < NV) {
        double a = 0.0;
        for (int m = 0; m < 32; ++m) a += (double)wl[m] * (double)xl[m][t];
        vp[(size_t)p*NV + t] = a;
    }
    if (t == 0) {
        double a = 0.0;
        for (int m = 0; m < 32; ++m) a += (double)wl[m] * (double)wl[m];
        Sp[p] = a;
    }
}

__global__ void k_qp_red(const double* __restrict__ Gp, const double* __restrict__ vp,
                         const double* __restrict__ Sp,
                         double* __restrict__ G, double* __restrict__ v, double* __restrict__ S) {
    int idx = blockIdx.x * 256 + threadIdx.x;
    if (idx < NV*NV) {
        double a = 0.0;
        for (int p = 0; p < NPART; ++p) a += Gp[(size_t)p*NV*NV + idx];
        G[idx] = a;
    }
    if (idx < NV) {
        double a = 0.0;
        for (int p = 0; p < NPART; ++p) a += vp[(size_t)p*NV + idx];
        v[idx] = a;
    }
    if (idx == 0) {
        double a = 0.0;
        for (int p = 0; p < NPART; ++p) a += Sp[p];
        S[0] = a;
    }
}

// qp_norm[b] = sqrt(0.25*Y^T G Y + Y.v + S)
__global__ __launch_bounds__(256) void k_qp_norm(const float* __restrict__ Y, const double* __restrict__ G,
                         const double* __restrict__ v, const double* __restrict__ S,
                         float* __restrict__ qp) {
    __shared__ float Yl[16][NV];
    __shared__ double tl[16][NV];
    int b0 = blockIdx.x * 16;
    int t = threadIdx.x;
    for (int idx = t; idx < 16*NV; idx += 256) Yl[idx/NV][idx%NV] = Y[(size_t)b0*NV + idx];
    __syncthreads();
    for (int idx = t; idx < 16*NV; idx += 256) {
        int m = idx / NV, i = idx % NV;
        double a = 0.0;
        for (int j = 0; j < NV; ++j) a += G[j*NV + i] * (double)Yl[m][j];  // G symmetric
        tl[m][i] = a;
    }
    __syncthreads();
    if (t < 16) {
        double a = 0.0, bv = 0.0;
        for (int i = 0; i < NV; ++i) { a += (double)Yl[t][i] * tl[t][i]; bv += (double)Yl[t][i] * v[i]; }
        double q = 0.25 * a + bv + S[0];
        qp[b0 + t] = (float)sqrt(q > 0.0 ? q : 0.0);
    }
}

// ---------------------------------------------------------------------------
// Fused GRU cell via bf16 MFMA (2-term split precision).
// Tile 128 batch x 64 hid-cols, 512 threads (8 waves = 2m x 4n), K-step 64.
// Double-buffered LDS (2 x 40KB), one barrier per K-step; stage regs loaded
// a full step ahead. XCD-aware swizzle for weight L2 residency.
#define GRUF_MFMA(AB) do {                                                       \
    char* As_ = lds + cur * 40960;                                               \
    char* Bs_ = As_ + 16384;                                                     \
    _Pragma("unroll")                                                            \
    for (int ss = 0; ss < 2; ++ss) {                                             \
        const int srow = lane & 15;                                              \
        const int slot = ss * 4 + (lane >> 4);                                   \
        short8v af[4];                                                           \
        _Pragma("unroll")                                                        \
        for (int fm = 0; fm < 4; ++fm) {                                         \
            int rr = wm * 64 + fm * 16 + srow;                                   \
            af[fm] = *(const short8v*)(As_ + rr * 128 + (((slot ^ (rr & 7)) & 7) << 4)); \
        }                                                                        \
        _Pragma("unroll")                                                        \
        for (int gg = 0; gg < 3; ++gg) {                                         \
            int rb = wn * 16 + srow;                                             \
            short8v bf = *(const short8v*)(Bs_ + gg * 8192 + rb * 128 + (((slot ^ (rb & 7)) & 7) << 4)); \
            _Pragma("unroll")                                                    \
            for (int fm = 0; fm < 4; ++fm)                                       \
                acc[(AB) + gg][fm] = __builtin_amdgcn_mfma_f32_16x16x32_bf16(af[fm], bf, acc[(AB) + gg][fm], 0, 0, 0); \
        }                                                                        \
    }                                                                            \
} while (0)

#define NSTEP1 34   // KP1/64
#define NSTEPT 66   // + KP2/64

__global__ __launch_bounds__(512, 2) void k_gruf(
        const u16* __restrict__ rpk, const u16* __restrict__ hpk,
        const u16* __restrict__ Wih, const u16* __restrict__ Whh,
        const float* __restrict__ bih, const float* __restrict__ bhh,
        u16* __restrict__ hnpk) {
    __shared__ char lds[81920];          // 2 x (A 16KB + 3 B-tiles 8KB)
    const int t = threadIdx.x;
    const int lane = t & 63;
    const int wid = t >> 6;              // 0..7
    const int wm = wid >> 2;             // 0..1: 64-row half
    const int wn = wid & 3;              // 0..3: 16-col quarter
    const int wg = blockIdx.x;
    const int xcd = wg & 7, slot_ = wg >> 3;
    const int m0 = (slot_ & 31) * 128;
    const int n0 = (xcd * 2 + (slot_ >> 5)) * 64;

    f32x4 acc[6][4];
    #pragma unroll
    for (int i = 0; i < 6; ++i)
        #pragma unroll
        for (int j = 0; j < 4; ++j) {
            f32x4 z = {0.f, 0.f, 0.f, 0.f};
            acc[i][j] = z;
        }

    short8v arS[2], brS[3];
    const int rl = t & 7;
    const int rb0 = t >> 3;              // 0..63

    auto gload = [&](int step) {
        const u16* Ag; const u16* Bg; int ldk, k0;
        if (step < NSTEP1) { Ag = rpk; Bg = Wih; ldk = KP1; k0 = step << 6; }
        else               { Ag = hpk; Bg = Whh; ldk = KP2; k0 = (step - NSTEP1) << 6; }
        #pragma unroll
        for (int q = 0; q < 2; ++q) {
            int rr = rb0 + (q << 6);
            arS[q] = *(const short8v*)(Ag + (size_t)(m0 + rr) * ldk + k0 + rl * 8);
        }
        #pragma unroll
        for (int q = 0; q < 3; ++q)
            brS[q] = *(const short8v*)(Bg + (size_t)(q * 1024 + n0 + rb0) * ldk + k0 + rl * 8);
    };
    auto lwrite = [&](int buf) {
        char* As_ = lds + buf * 40960;
        char* Bs_ = As_ + 16384;
        #pragma unroll
        for (int q = 0; q < 2; ++q) {
            int rr = rb0 + (q << 6);
            *(short8v*)(As_ + rr * 128 + ((rl ^ (rr & 7)) << 4)) = arS[q];
        }
        #pragma unroll
        for (int q = 0; q < 3; ++q)
            *(short8v*)(Bs_ + q * 8192 + rb0 * 128 + ((rl ^ (rb0 & 7)) << 4)) = brS[q];
    };

    gload(0);
    lwrite(0);
    gload(1);
    __syncthreads();
    int cur = 0;
    for (int step = 0; step < NSTEP1; ++step) {       // phase 0: gi (ab=0)
        if (step < NSTEPT - 1) lwrite(cur ^ 1);
        if (step < NSTEPT - 2) gload(step + 2);
        GRUF_MFMA(0);
        __syncthreads();
        cur ^= 1;
    }
    for (int step = NSTEP1; step < NSTEPT; ++step) {  // phase 1: gh (ab=3)
        if (step < NSTEPT - 1) lwrite(cur ^ 1);
        if (step < NSTEPT - 2) gload(step + 2);
        GRUF_MFMA(3);
        __syncthreads();
        cur ^= 1;
    }

    const int jj = n0 + wn * 16 + (lane & 15);
    const float bir = bih[jj],        bhr = bhh[jj];
    const float biz = bih[1024 + jj], bhz = bhh[1024 + jj];
    const float bin = bih[2048 + jj], bhn = bhh[2048 + jj];
    #pragma unroll
    for (int fm = 0; fm < 4; ++fm) {
        #pragma unroll
        for (int rg = 0; rg < 4; ++rg) {
            int m = m0 + wm * 64 + fm * 16 + (lane >> 4) * 4 + rg;
            float ir = acc[0][fm][rg], iz = acc[1][fm][rg], inn = acc[2][fm][rg];
            float hr = acc[3][fm][rg], hz = acc[4][fm][rg], hnn = acc[5][fm][rg];
            float rgate = 1.f / (1.f + expf(-(ir + bir + hr + bhr)));
            float zgate = 1.f / (1.f + expf(-(iz + biz + hz + bhz)));
            float ngate = tanhf(inn + bin + rgate * (hnn + bhn));
            size_t base = (size_t)m * KP2;
            float hv = b2f(hpk[base + jj]) + b2f(hpk[base + 1024 + jj]);
            float hnew = (1.f - zgate) * ngate + zgate * hv;
            u16 nh = f2b(hnew);
            u16 nl = f2b(hnew - b2f(nh));
            hnpk[base + jj] = nh;
            hnpk[base + 1024 + jj] = nl;
        }
    }
}

// out = h_new @ W_out^T + b_out via bf16 MFMA; M=4096, N=384(360), K'=2048
__global__ __launch_bounds__(256) void k_outp(
        const u16* __restrict__ hpk, const u16* __restrict__ Wo,
        const float* __restrict__ bo, float* __restrict__ outb) {
    __shared__ char lds[24576];          // A 16KB + B 8KB
    char* As = lds;
    char* Bs = lds + 16384;
    const int t = threadIdx.x, lane = t & 63, wid = t >> 6;
    const int wm = wid >> 1, wn = wid & 1;
    const int m0 = blockIdx.x * 128, n0 = blockIdx.y * 64;
    f32x4 acc[4][2];
    #pragma unroll
    for (int i = 0; i < 4; ++i)
        #pragma unroll
        for (int j = 0; j < 2; ++j) {
            f32x4 z = {0.f, 0.f, 0.f, 0.f};
            acc[i][j] = z;
        }
    for (int kt = 0; kt < 32; ++kt) {
        const int k0 = kt << 6;
        short8v ar[4], br[2];
        #pragma unroll
        for (int q = 0; q < 4; ++q) {
            int cc = t + (q << 8);
            int rr = cc >> 3, l = cc & 7;
            ar[q] = *(const short8v*)(hpk + (size_t)(m0 + rr) * KP2 + k0 + l * 8);
        }
        #pragma unroll
        for (int q = 0; q < 2; ++q) {
            int cc = t + (q << 8);
            int rb = cc >> 3, l = cc & 7;
            br[q] = *(const short8v*)(Wo + (size_t)(n0 + rb) * KP2 + k0 + l * 8);
        }
        __syncthreads();
        #pragma unroll
        for (int q = 0; q < 4; ++q) {
            int cc = t + (q << 8);
            int rr = cc >> 3, l = cc & 7;
            *(short8v*)(As + rr * 128 + ((l ^ (rr & 7)) << 4)) = ar[q];
        }
        #pragma unroll
        for (int q = 0; q < 2; ++q) {
            int cc = t + (q << 8);
            int rb = cc >> 3, l = cc & 7;
            *(short8v*)(Bs + rb * 128 + ((l ^ (rb & 7)) << 4)) = br[q];
        }
        __syncthreads();
        #pragma unroll
        for (int s = 0; s < 2; ++s) {
            const int srow = lane & 15;
            const int slot = s * 4 + (lane >> 4);
            short8v af[4];
            #pragma unroll
            for (int fm = 0; fm < 4; ++fm) {
                int rr = wm * 64 + fm * 16 + srow;
                af[fm] = *(const short8v*)(As + rr * 128 + (((slot ^ (rr & 7)) & 7) << 4));
            }
            #pragma unroll
            for (int fn = 0; fn < 2; ++fn) {
                int rb = wn * 32 + fn * 16 + srow;
                short8v bf = *(const short8v*)(Bs + rb * 128 + (((slot ^ (rb & 7)) & 7) << 4));
                #pragma unroll
                for (int fm = 0; fm < 4; ++fm)
                    acc[fm][fn] = __builtin_amdgcn_mfma_f32_16x16x32_bf16(af[fm], bf, acc[fm][fn], 0, 0, 0);
            }
        }
    }
    #pragma unroll
    for (int fm = 0; fm < 4; ++fm) {
        #pragma unroll
        for (int fn = 0; fn < 2; ++fn) {
            int n = n0 + wn * 32 + fn * 16 + (lane & 15);
            if (n < NOUTD) {
                float bb = bo[n];
                #pragma unroll
                for (int rg = 0; rg < 4; ++rg) {
                    int m = m0 + wm * 64 + fm * 16 + (lane >> 4) * 4 + rg;
                    outb[(size_t)m * NOUTP + n] = acc[fm][fn][rg] + bb;
                }
            }
        }
    }
}

// s_fin/lam_fin (+ in-place state update) and fixed-point residual norm
__global__ __launch_bounds__(256) void k_fin(const float* __restrict__ snew, const float* __restrict__ lamn,
                     const float* __restrict__ outb,
                     float* __restrict__ s, float* __restrict__ lam,
                     float* __restrict__ fx) {
    __shared__ float redS[16][17];
    __shared__ float redL[16][17];
    int b0 = blockIdx.x * 16;
    int tm = threadIdx.x / 16;
    int tk = threadIdx.x % 16;
    int b = b0 + tm;
    float ds2 = 0.f, dl2 = 0.f;
    for (int k = tk; k < NCN; k += 16) {
        float o = outb[(size_t)b*NOUTP + k];
        float sf = fmaxf(0.f, snew[(size_t)b*NCN + k] + o);
        float so = s[(size_t)b*NCN + k];
        s[(size_t)b*NCN + k] = sf;
        float d = so - sf;
        ds2 += d * d;
    }
    for (int i = tk; i < NV; i += 16) {
        float o = outb[(size_t)b*NOUTP + NCN + i];
        float lf = lamn[(size_t)b*NV + i] + o;
        float lo = lam[(size_t)b*NV + i];
        lam[(size_t)b*NV + i] = lf;
        float d = lo - lf;
        dl2 += d * d;
    }
    redS[tm][tk] = ds2;
    redL[tm][tk] = dl2;
    __syncthreads();
    if (tk == 0) {
        float a = 0.f, l = 0.f;
        for (int q = 0; q < 16; ++q) { a += redS[tm][q]; l += redL[tm][q]; }
        fx[b] = sqrtf(l) + sqrtf(a);
    }
}

// ---------------------------------------------------------------------------
extern "C" void kernel_launch(void* const* d_in, const int* in_sizes, int n_in,
                              void* d_out, int out_size, void* d_ws, size_t ws_size,
                              hipStream_t stream) {
    const float* lamda_init = (const float*)d_in[0];
    // d_in[1] = s_init (unused: multiplied by 0 in reference)
    const float* h0    = (const float*)d_in[2];
    const float* H     = (const float*)d_in[3];
    const float* g     = (const float*)d_in[4];
    const float* C     = (const float*)d_in[5];
    const float* c     = (const float*)d_in[6];
    const float* W_ih  = (const float*)d_in[7];
    const float* b_ih  = (const float*)d_in[8];
    const float* W_hh  = (const float*)d_in[9];
    const float* b_hh  = (const float*)d_in[10];
    const float* W_out = (const float*)d_in[11];
    const float* b_out = (const float*)d_in[12];

    float* out    = (float*)d_out;
    float* xi_out = out;                       // [B,120]
    float* primal = out + (size_t)NB*NV;       // [8,B]
    float* fixedo = primal + (size_t)NITER*NB; // [8,B]
    float* qpres  = fixedo + (size_t)NITER*NB; // [8,B]

    char* wp = (char*)d_ws;
    auto alloc = [&](size_t bytes) {
        void* p = (void*)wp;
        wp += (bytes + 255) & ~(size_t)255;
        return p;
    };
    float* Amat  = (float*)alloc(NV*NV*4);
    float* A0m   = (float*)alloc(NV*NV*4);
    float* Qinv  = (float*)alloc(NV*NV*4);
    float* Qinv0 = (float*)alloc(NV*NV*4);
    float* s0v   = (float*)alloc(NCN*4);
    float* sbuf  = (float*)alloc((size_t)NB*NCN*4);
    float* snew  = (float*)alloc((size_t)NB*NCN*4);
    float* lam   = (float*)alloc((size_t)NB*NV*4);
    float* lamn  = (float*)alloc((size_t)NB*NV*4);
    float* xib   = (float*)alloc((size_t)NB*NV*4);
    float* Yb    = (float*)alloc((size_t)NB*NV*4);
    float* wb    = (float*)alloc(NB*4);
    float* outb  = (float*)alloc((size_t)NB*NOUTP*4);
    u16* rpk     = (u16*)alloc((size_t)NB*KP1*2);
    u16* hpkA    = (u16*)alloc((size_t)NB*KP2*2);
    u16* hpkB    = (u16*)alloc((size_t)NB*KP2*2);
    u16* Wihpk   = (u16*)alloc((size_t)3072*KP1*2);
    u16* Whhpk   = (u16*)alloc((size_t)3072*KP2*2);
    u16* Wopk    = (u16*)alloc((size_t)NOUTP*KP2*2);
    double* Gpart = (double*)alloc((size_t)NPART*NV*NV*8);
    double* vpart = (double*)alloc((size_t)NPART*NV*8);
    double* Spart = (double*)alloc(NPART*8);
    double* Gfin  = (double*)alloc(NV*NV*8);
    double* vfin  = (double*)alloc(NV*8);
    double* Sfin  = (double*)alloc(8);

    k_buildA<<<dim3(NV, 2), dim3(128), 0, stream>>>(H, C, Amat, A0m);
    k_invert<<<dim3(2), dim3(512), 0, stream>>>(Amat, A0m, Qinv, Qinv0);
    k_s0<<<dim3(1), dim3(256), 0, stream>>>(Qinv0, g, C, c, s0v);
    k_init<<<dim3(NB/8), dim3(256), 0, stream>>>(s0v, lamda_init, sbuf, lam);
    k_packW<<<dim3(3072), dim3(256), 0, stream>>>(W_ih, Wihpk, 3072, RINN, 1088);
    k_packW<<<dim3(3072), dim3(256), 0, stream>>>(W_hh, Whhpk, 3072, HIDD, 1024);
    k_packW<<<dim3(NOUTP), dim3(256), 0, stream>>>(W_out, Wopk, NOUTD, HIDD, 1024);
    k_packA<<<dim3(NB), dim3(256), 0, stream>>>(h0, hpkA, NB, HIDD, 1024);

    u16* hc = hpkA;
    u16* hn2 = hpkB;
    for (int it = 0; it < NITER; ++it) {
        k_xiproj<<<dim3(NB/16), dim3(512), 0, stream>>>(sbuf, lam, C, c, g, Qinv, H,
                                                        xib, Yb, wb, snew, lamn, rpk,
                                                        primal + (size_t)it*NB);
        k_qp_part<<<dim3(NPART), dim3(256), 0, stream>>>(xib, wb, Gpart, vpart, Spart);
        k_qp_red<<<dim3((NV*NV + 255)/256), dim3(256), 0, stream>>>(Gpart, vpart, Spart, Gfin, vfin, Sfin);
        k_qp_norm<<<dim3(NB/16), dim3(256), 0, stream>>>(Yb, Gfin, vfin, Sfin, qpres + (size_t)it*NB);
        k_gruf<<<dim3(512), dim3(512), 0, stream>>>(rpk, hc, Wihpk, Whhpk, b_ih, b_hh, hn2);
        k_outp<<<dim3(NB/128, NOUTP/64), dim3(256), 0, stream>>>(hn2, Wopk, b_out, outb);
        k_fin<<<dim3(NB/16), dim3(256), 0, stream>>>(snew, lamn, outb, sbuf, lam, fixedo + (size_t)it*NB);
        u16* tmp = hc; hc = hn2; hn2 = tmp;
    }
    hipMemcpyAsync(xi_out, xib, (size_t)NB*NV*sizeof(float), hipMemcpyDeviceToDevice, stream);
}

// Round 7
// 2803.643 us; speedup vs baseline: 5.2968x; 1.0643x over previous
//
#include <hip/hip_runtime.h>
#include <hip/hip_bf16.h>
#include <math.h>

// Problem constants (match reference)
#define NB    4096   // batch
#define NV    120    // NVAR
#define NCN   240    // num constraints
#define HIDD  1024   // GRU hidden
#define RINN  1080   // GRU input dim
#define NOUTD 360    // NC+NVAR
#define NOUTP 384    // padded out cols
#define NITER 8
#define REGEPS 1e-4f
#define NPART 128    // partial blocks for G reduction

// 2-term split: activations [hi|lo] (exact), weights [hi|hi].
// Concatenated activation row: [r_hi 1088 | r_lo 1088 | h_hi 1024 | h_lo 1024]
#define KCAT 4224
#define HOFF 2176    // h section start within a row
#define KP2  2048    // W_out packed K
#define NSTEP_R 34   // r-section K-steps (2176/64)
#define NSTEPS  66   // total K-steps (4224/64)

typedef unsigned short u16;
typedef __attribute__((ext_vector_type(8))) short short8v;
typedef __attribute__((ext_vector_type(4))) float f32x4;

__device__ inline u16 f2b(float x) {
    __hip_bfloat16 h = __float2bfloat16(x);
    return __builtin_bit_cast(u16, h);
}
__device__ inline float b2f(u16 u) {
    __hip_bfloat16 h = __builtin_bit_cast(__hip_bfloat16, u);
    return __bfloat162float(h);
}

// async global -> LDS, 16B per lane (wave-uniform LDS base + lane*16)
__device__ inline void gl16(const void* g, void* l) {
    __builtin_amdgcn_global_load_lds(
        (__attribute__((address_space(1))) void*)(void*)g,
        (__attribute__((address_space(3))) void*)l, 16, 0, 0);
}

// ---------------------------------------------------------------------------
// Build A = H + C^T C + REG*I (which==0) and A0 = H + REG*I (which==1)
__global__ void k_buildA(const float* __restrict__ H, const float* __restrict__ C,
                         float* __restrict__ A, float* __restrict__ A0) {
    int i = blockIdx.x;
    int which = blockIdx.y;
    for (int j = threadIdx.x; j < NV; j += blockDim.x) {
        float v = H[i*NV + j] + (i == j ? REGEPS : 0.f);
        if (which == 0) {
            float acc = 0.f;
            for (int k = 0; k < NCN; ++k) acc += C[k*NV + i] * C[k*NV + j];
            A[i*NV + j] = v + acc;   // RHO = 1
        } else {
            A0[i*NV + j] = v;
        }
    }
}

// Row-major 4x4 inverse via 2x2-subdeterminant adjugate (ILP-friendly).
__device__ inline void inv4x4(const float* m, float* inv) {
    float s0 = m[0]*m[5] - m[1]*m[4];
    float s1 = m[0]*m[6] - m[2]*m[4];
    float s2 = m[0]*m[7] - m[3]*m[4];
    float s3 = m[1]*m[6] - m[2]*m[5];
    float s4 = m[1]*m[7] - m[3]*m[5];
    float s5 = m[2]*m[7] - m[3]*m[6];
    float c5 = m[10]*m[15] - m[11]*m[14];
    float c4 = m[9]*m[15] - m[11]*m[13];
    float c3 = m[9]*m[14] - m[10]*m[13];
    float c2 = m[8]*m[15] - m[11]*m[12];
    float c1 = m[8]*m[14] - m[10]*m[12];
    float c0 = m[8]*m[13] - m[9]*m[12];
    float det = s0*c5 - s1*c4 + s2*c3 + s3*c2 - s4*c1 + s5*c0;
    float id = 1.0f / det;
    inv[0]  = ( m[5]*c5 - m[6]*c4 + m[7]*c3) * id;
    inv[1]  = (-m[1]*c5 + m[2]*c4 - m[3]*c3) * id;
    inv[2]  = ( m[13]*s5 - m[14]*s4 + m[15]*s3) * id;
    inv[3]  = (-m[9]*s5 + m[10]*s4 - m[11]*s3) * id;
    inv[4]  = (-m[4]*c5 + m[6]*c2 - m[7]*c1) * id;
    inv[5]  = ( m[0]*c5 - m[2]*c2 + m[3]*c1) * id;
    inv[6]  = (-m[12]*s5 + m[14]*s2 - m[15]*s1) * id;
    inv[7]  = ( m[8]*s5 - m[10]*s2 + m[11]*s1) * id;
    inv[8]  = ( m[4]*c4 - m[5]*c2 + m[7]*c0) * id;
    inv[9]  = (-m[0]*c4 + m[1]*c2 - m[3]*c0) * id;
    inv[10] = ( m[12]*s4 - m[13]*s2 + m[15]*s0) * id;
    inv[11] = (-m[8]*s4 + m[9]*s2 - m[11]*s0) * id;
    inv[12] = (-m[4]*c3 + m[5]*c1 - m[6]*c0) * id;
    inv[13] = ( m[0]*c3 - m[1]*c1 + m[2]*c0) * id;
    inv[14] = (-m[12]*s3 + m[13]*s1 - m[14]*s0) * id;
    inv[15] = ( m[8]*s3 - m[9]*s1 + m[10]*s0) * id;
}

// Blocked rank-4 Gauss-Jordan inverse, 1024 threads (4 waves/SIMD), 4 rows +
// 1 col-group of 4 per thread. NO dynamic register-array indexing (rule #20:
// round-6's R[r][dp] with runtime dp spilled the array to scratch -> 125KB
// extra WRITE_SIZE). Pivot-row select is a cndmask chain instead.
__global__ __launch_bounds__(1024) void k_invert(const float* __restrict__ Ain,
                                                 const float* __restrict__ A0in,
                                                 float* __restrict__ Qi,
                                                 float* __restrict__ Qi0) {
    __shared__ float M[NV][132];
    const float* src = (blockIdx.x == 0) ? Ain : A0in;
    float* dst = (blockIdx.x == 0) ? Qi : Qi0;
    const int t = threadIdx.x;
    for (int idx = t; idx < NV*132; idx += 1024) {
        int i = idx / 132, j = idx - i*132;
        M[i][j] = (j < NV) ? src[i*NV + j] : 0.f;
    }
    __syncthreads();
    const int ty = t >> 5;        // 0..31 row owner
    const int g4 = (t & 31) * 4;  // col group 0..124 (cols padded to 132)
    for (int kk = 0; kk < NV; kk += 4) {
        float a[16], b[16];
        #pragma unroll
        for (int p = 0; p < 4; ++p) {
            float4 v = *(const float4*)&M[kk + p][kk];
            a[p*4+0] = v.x; a[p*4+1] = v.y; a[p*4+2] = v.z; a[p*4+3] = v.w;
        }
        inv4x4(a, b);
        float4 F[4];
        #pragma unroll
        for (int q = 0; q < 4; ++q) {
            int i = ty + 32*q;
            F[q] = (i < NV) ? *(const float4*)&M[i][kk] : float4{0.f,0.f,0.f,0.f};
        }
        float4 R[4];
        {
            float4 m0v = *(const float4*)&M[kk+0][g4];
            float4 m1v = *(const float4*)&M[kk+1][g4];
            float4 m2v = *(const float4*)&M[kk+2][g4];
            float4 m3v = *(const float4*)&M[kk+3][g4];
            #pragma unroll
            for (int p = 0; p < 4; ++p) {
                R[p].x = b[p*4+0]*m0v.x + b[p*4+1]*m1v.x + b[p*4+2]*m2v.x + b[p*4+3]*m3v.x;
                R[p].y = b[p*4+0]*m0v.y + b[p*4+1]*m1v.y + b[p*4+2]*m2v.y + b[p*4+3]*m3v.y;
                R[p].z = b[p*4+0]*m0v.z + b[p*4+1]*m1v.z + b[p*4+2]*m2v.z + b[p*4+3]*m3v.z;
                R[p].w = b[p*4+0]*m0v.w + b[p*4+1]*m1v.w + b[p*4+2]*m2v.w + b[p*4+3]*m3v.w;
            }
        }
        __syncthreads();   // all reads of original M complete
        #pragma unroll
        for (int q = 0; q < 4; ++q) {
            int i = ty + 32*q;
            if (i < NV) {
                int dp = i - kk;
                bool ispiv = (dp >= 0) && (dp < 4);
                float4 v;
                if (ispiv) {
                    v = (dp == 0) ? R[0] : (dp == 1) ? R[1] : (dp == 2) ? R[2] : R[3];
                } else {
                    v = *(const float4*)&M[i][g4];
                    v.x -= F[q].x*R[0].x + F[q].y*R[1].x + F[q].z*R[2].x + F[q].w*R[3].x;
                    v.y -= F[q].x*R[0].y + F[q].y*R[1].y + F[q].z*R[2].y + F[q].w*R[3].y;
                    v.z -= F[q].x*R[0].z + F[q].y*R[1].z + F[q].z*R[2].z + F[q].w*R[3].z;
                    v.w -= F[q].x*R[0].w + F[q].y*R[1].w + F[q].z*R[2].w + F[q].w*R[3].w;
                }
                if (g4 == kk) {
                    if (ispiv) {
                        float4 b0 = float4{b[0],  b[1],  b[2],  b[3]};
                        float4 b1 = float4{b[4],  b[5],  b[6],  b[7]};
                        float4 b2 = float4{b[8],  b[9],  b[10], b[11]};
                        float4 b3 = float4{b[12], b[13], b[14], b[15]};
                        v = (dp == 0) ? b0 : (dp == 1) ? b1 : (dp == 2) ? b2 : b3;
                    } else {
                        v.x = -(F[q].x*b[0] + F[q].y*b[4] + F[q].z*b[8]  + F[q].w*b[12]);
                        v.y = -(F[q].x*b[1] + F[q].y*b[5] + F[q].z*b[9]  + F[q].w*b[13]);
                        v.z = -(F[q].x*b[2] + F[q].y*b[6] + F[q].z*b[10] + F[q].w*b[14]);
                        v.w = -(F[q].x*b[3] + F[q].y*b[7] + F[q].z*b[11] + F[q].w*b[15]);
                    }
                }
                *(float4*)&M[i][g4] = v;
            }
        }
        __syncthreads();
    }
    for (int idx = t; idx < NV*NV; idx += 1024) {
        int i = idx / NV, j = idx - i*NV;
        dst[idx] = M[i][j];
    }
}

// xi0 = (-g) @ Qinv0^T ; s0 = max(0, c - C xi0)   (batch-constant vectors)
__global__ void k_s0(const float* __restrict__ Qi0, const float* __restrict__ g,
                     const float* __restrict__ C, const float* __restrict__ c,
                     float* __restrict__ s0v) {
    __shared__ float xi0[NV];
    int t = threadIdx.x;
    if (t < NV) {
        float a = 0.f;
        for (int j = 0; j < NV; ++j) a += Qi0[t*NV + j] * g[j];
        xi0[t] = -a;
    }
    __syncthreads();
    if (t < NCN) {
        float a = 0.f;
        for (int j = 0; j < NV; ++j) a += C[t*NV + j] * xi0[j];
        s0v[t] = fmaxf(0.f, c[t] - a);
    }
}

// Initialize state: s = broadcast(s0), lam = lamda_init
__global__ void k_init(const float* __restrict__ s0v, const float* __restrict__ lam0,
                       float* __restrict__ s, float* __restrict__ lam) {
    int b0 = blockIdx.x * 8;
    int t = threadIdx.x;
    for (int idx = t; idx < 8*NCN; idx += 256) {
        int m = idx / NCN, k = idx % NCN;
        s[(size_t)(b0 + m)*NCN + k] = s0v[k];
    }
    for (int idx = t; idx < 8*NV; idx += 256) lam[(size_t)b0*NV + idx] = lam0[(size_t)b0*NV + idx];
}

// Pack h0 into act buffer h-section: [h_hi | h_lo]
__global__ void k_packH(const float* __restrict__ h0, u16* __restrict__ act) {
    int n = blockIdx.x;
    size_t base = (size_t)n * KCAT + HOFF;
    for (int k = threadIdx.x; k < HIDD; k += 256) {
        float x = h0[(size_t)n * HIDD + k];
        u16 hi = f2b(x);
        act[base + k] = hi;
        act[base + HIDD + k] = f2b(x - b2f(hi));
    }
}

// Pack Wih+Whh into Wcat rows: [Wih_hi 1088 | Wih_hi 1088 | Whh_hi 1024 | Whh_hi 1024]
__global__ void k_packWcat(const float* __restrict__ Wih, const float* __restrict__ Whh,
                           u16* __restrict__ Wc) {
    int n = blockIdx.x;   // 0..3071
    size_t base = (size_t)n * KCAT;
    for (int k = threadIdx.x; k < 1088; k += 256) {
        u16 hi = f2b(k < RINN ? Wih[(size_t)n * RINN + k] : 0.f);
        Wc[base + k] = hi;
        Wc[base + 1088 + k] = hi;
    }
    for (int k = threadIdx.x; k < HIDD; k += 256) {
        u16 hi = f2b(Whh[(size_t)n * HIDD + k]);
        Wc[base + HOFF + k] = hi;
        Wc[base + HOFF + HIDD + k] = hi;
    }
}

// Pack WEIGHT f32 [nsrc x Ks] into [rows x 2*Kp] = [hi | hi]  (W_out)
__global__ void k_packW(const float* __restrict__ src, u16* __restrict__ dst,
                        int nsrc, int Ks, int Kp) {
    int n = blockIdx.x;
    size_t row = (size_t)n * 2 * Kp;
    for (int k = threadIdx.x; k < Kp; k += 256) {
        float x = (n < nsrc && k < Ks) ? src[(size_t)n * Ks + k] : 0.f;
        u16 hi = f2b(x);
        dst[row + k] = hi;
        dst[row + Kp + k] = hi;
    }
}

__device__ inline void write2(u16* __restrict__ act, size_t base, int pos, float x) {
    u16 hi = f2b(x);
    u16 lo = f2b(x - b2f(hi));
    act[base + pos] = hi;
    act[base + 1088 + pos] = lo;
}

// Fused: xi solve + projection + GRU-input pack into act r-section.
__global__ __launch_bounds__(512) void k_xiproj(
        const float* __restrict__ s, const float* __restrict__ lam,
        const float* __restrict__ C, const float* __restrict__ c,
        const float* __restrict__ g, const float* __restrict__ Qi,
        const float* __restrict__ H,
        float* __restrict__ xi, float* __restrict__ Y, float* __restrict__ wv,
        float* __restrict__ snew, float* __restrict__ lamn,
        u16* __restrict__ act, float* __restrict__ primal) {
    __shared__ float bd[16][NCN];
    __shared__ float ul[16][NV];
    __shared__ float xl[16][NV];
    __shared__ float resl[16][NCN];
    int b0 = blockIdx.x * 16;
    int t = threadIdx.x;
    for (int idx = t; idx < 16*NCN; idx += 512) {
        int m = idx / NCN, k = idx % NCN;
        bd[m][k] = c[k] - s[(size_t)(b0 + m)*NCN + k];
    }
    __syncthreads();
    for (int idx = t; idx < 16*NV; idx += 512) {
        int m = idx / NV, j = idx % NV;
        float a = lam[(size_t)(b0 + m)*NV + j] - g[j];
        for (int k = 0; k < NCN; ++k) a += bd[m][k] * C[k*NV + j];
        ul[m][j] = a;
    }
    __syncthreads();
    for (int idx = t; idx < 16*NV; idx += 512) {
        int m = idx / NV, i = idx % NV;
        float a = 0.f;
        for (int j = 0; j < NV; ++j) a += Qi[j*NV + i] * ul[m][j];  // Qinv symmetric
        xl[m][i] = a;
        xi[(size_t)(b0 + m)*NV + i] = a;
    }
    __syncthreads();
    for (int idx = t; idx < 16*NV; idx += 512) {
        int m = idx / NV, i = idx % NV;
        float a = 0.f;
        for (int j = 0; j < NV; ++j) a += xl[m][j] * H[j*NV + i];
        Y[(size_t)(b0 + m)*NV + i] = a;
    }
    if (t < 16) {
        float a = 0.f;
        for (int j = 0; j < NV; ++j) a += xl[t][j] * g[j];
        wv[b0 + t] = a;
    }
    for (int idx = t; idx < 16*NCN; idx += 512) {
        int m = idx / NCN, k = idx % NCN;
        float a = 0.f;
        for (int j = 0; j < NV; ++j) a += C[k*NV + j] * xl[m][j];
        float sn = fmaxf(0.f, c[k] - a);
        float rv = a - c[k] + sn;
        resl[m][k] = rv;
        int b = b0 + m;
        snew[(size_t)b*NCN + k] = sn;
        float so = s[(size_t)b*NCN + k];
        size_t base = (size_t)b * KCAT;
        write2(act, base, k, so);
        write2(act, base, 360 + k, sn);
        write2(act, base, 720 + k, sn - so);
    }
    __syncthreads();
    if (t < 16) {
        float a = 0.f;
        for (int k = 0; k < NCN; ++k) a += resl[t][k] * resl[t][k];
        primal[b0 + t] = sqrtf(a);
    }
    for (int idx = t; idx < 16*NV; idx += 512) {
        int m = idx / NV, i = idx % NV;
        float a = 0.f;
        for (int k = 0; k < NCN; ++k) a += resl[m][k] * C[k*NV + i];
        int b = b0 + m;
        float lo = lam[(size_t)b*NV + i];
        float ln = lo - a;
        lamn[(size_t)b*NV + i] = ln;
        size_t base = (size_t)b * KCAT;
        write2(act, base, 240 + i, lo);
        write2(act, base, 600 + i, ln);
        write2(act, base, 960 + i, ln - lo);
    }
    for (int idx = t; idx < 16*8; idx += 512) {
        int m = idx >> 3, k = 1080 + (idx & 7);
        size_t base = (size_t)(b0 + m) * KCAT;
        act[base + k] = 0;
        act[base + 1088 + k] = 0;
    }
}

// Partial Gram: G_p = sum_m xi_m xi_m^T, v_p = sum_m w_m xi_m, S_p = sum w^2
__global__ __launch_bounds__(256) void k_qp_part(const float* __restrict__ xi, const float* __restrict__ wv,
                         double* __restrict__ Gp, double* __restrict__ vp, double* __restrict__ Sp) {
    __shared__ float xl[32][NV];
    __shared__ float wl[32];
    int p = blockIdx.x;
    int b0 = p * 32;
    int t = threadIdx.x;
    for (int idx = t; idx < 32*NV; idx += 256) xl[idx/NV][idx%NV] = xi[(size_t)b0*NV + idx];
    if (t < 32) wl[t] = wv[b0 + t];
    __syncthreads();
    for (int idx = t; idx < NV*NV; idx += 256) {
        int i = idx / NV, j = idx % NV;
        double a = 0.0;
        for (int m = 0; m < 32; ++m) a += (double)xl[m][i] * (double)xl[m][j];
        Gp[(size_t)p*NV*NV + idx] = a;
    }
    if (t < NV) {
        double a = 0.0;
        for (int m = 0; m < 32; ++m) a += (double)wl[m] * (double)xl[m][t];
        vp[(size_t)p*NV + t] = a;
    }
    if (t == 0) {
        double a = 0.0;
        for (int m = 0; m < 32; ++m) a += (double)wl[m] * (double)wl[m];
        Sp[p] = a;
    }
}

__global__ void k_qp_red(const double* __restrict__ Gp, const double* __restrict__ vp,
                         const double* __restrict__ Sp,
                         double* __restrict__ G, double* __restrict__ v, double* __restrict__ S) {
    int idx = blockIdx.x * 256 + threadIdx.x;
    if (idx < NV*NV) {
        double a = 0.0;
        for (int p = 0; p < NPART; ++p) a += Gp[(size_t)p*NV*NV + idx];
        G[idx] = a;
    }
    if (idx < NV) {
        double a = 0.0;
        for (int p = 0; p < NPART; ++p) a += vp[(size_t)p*NV + idx];
        v[idx] = a;
    }
    if (idx == 0) {
        double a = 0.0;
        for (int p = 0; p < NPART; ++p) a += Sp[p];
        S[0] = a;
    }
}

// qp_norm[b] = sqrt(0.25*Y^T G Y + Y.v + S)
__global__ __launch_bounds__(256) void k_qp_norm(const float* __restrict__ Y, const double* __restrict__ G,
                         const double* __restrict__ v, const double* __restrict__ S,
                         float* __restrict__ qp) {
    __shared__ float Yl[16][NV];
    __shared__ double tl[16][NV];
    int b0 = blockIdx.x * 16;
    int t = threadIdx.x;
    for (int idx = t; idx < 16*NV; idx += 256) Yl[idx/NV][idx%NV] = Y[(size_t)b0*NV + idx];
    __syncthreads();
    for (int idx = t; idx < 16*NV; idx += 256) {
        int m = idx / NV, i = idx % NV;
        double a = 0.0;
        for (int j = 0; j < NV; ++j) a += G[j*NV + i] * (double)Yl[m][j];  // G symmetric
        tl[m][i] = a;
    }
    __syncthreads();
    if (t < 16) {
        double a = 0.0, bv = 0.0;
        for (int i = 0; i < NV; ++i) { a += (double)Yl[t][i] * tl[t][i]; bv += (double)Yl[t][i] * v[i]; }
        double q = 0.25 * a + bv + S[0];
        qp[b0 + t] = (float)sqrt(q > 0.0 ? q : 0.0);
    }
}

// ---------------------------------------------------------------------------
// Fused GRU cell, one concatenated-K GEMM via bf16 MFMA + global_load_lds.
// Block: 128 rows x (128 cols x 3 gates); 512 thr = 8 waves (2m x 4n).
// LDS: 2 x (A 16KB + B 48KB) = 128KB double buffer, linear rows of 128B;
// swizzle applied on the GLOBAL source (rule #21) and on the ds_read.
// acc: r/z gates sum over full K; n-gate splits i_n (slot2) / h_n (slot3)
// at the step-34 boundary (statically, two loops).
#define GRUF_STEP(NSLOT) do {                                                    \
    char* As_ = lds + cur * 65536;                                               \
    char* Bs_ = As_ + 16384;                                                     \
    _Pragma("unroll")                                                            \
    for (int ss = 0; ss < 2; ++ss) {                                             \
        const int srow = lane & 15;                                              \
        const int slot = ss * 4 + (lane >> 4);                                   \
        short8v af[4];                                                           \
        _Pragma("unroll")                                                        \
        for (int fm = 0; fm < 4; ++fm) {                                         \
            int rr = wm * 64 + fm * 16 + srow;                                   \
            af[fm] = *(const short8v*)(As_ + rr * 128 + ((slot ^ (rr & 7)) << 4)); \
        }                                                                        \
        _Pragma("unroll")                                                        \
        for (int fn = 0; fn < 2; ++fn) {                                         \
            int cb = wn * 32 + fn * 16 + srow;                                   \
            int sw = (slot ^ (cb & 7)) << 4;                                     \
            short8v bfr = *(const short8v*)(Bs_ + (size_t)cb * 128 + sw);        \
            short8v bfz = *(const short8v*)(Bs_ + (size_t)(128 + cb) * 128 + sw);\
            short8v bfn = *(const short8v*)(Bs_ + (size_t)(256 + cb) * 128 + sw);\
            _Pragma("unroll")                                                    \
            for (int fm = 0; fm < 4; ++fm) {                                     \
                acc[0][fn][fm] = __builtin_amdgcn_mfma_f32_16x16x32_bf16(af[fm], bfr, acc[0][fn][fm], 0, 0, 0); \
                acc[1][fn][fm] = __builtin_amdgcn_mfma_f32_16x16x32_bf16(af[fm], bfz, acc[1][fn][fm], 0, 0, 0); \
                acc[NSLOT][fn][fm] = __builtin_amdgcn_mfma_f32_16x16x32_bf16(af[fm], bfn, acc[NSLOT][fn][fm], 0, 0, 0); \
            }                                                                    \
        }                                                                        \
    }                                                                            \
} while (0)

__global__ __launch_bounds__(512, 2) void k_gruf(
        const u16* __restrict__ act,   // [NB][KCAT]: r filled + h_cur
        const u16* __restrict__ Wcat,  // [3*1024][KCAT]
        const float* __restrict__ bih, const float* __restrict__ bhh,
        u16* __restrict__ actn) {      // h_new -> h-section
    __shared__ char lds[131072];
    const int t = threadIdx.x;
    const int lane = t & 63;
    const int wid = t >> 6;          // 0..7
    const int wm = wid >> 2;         // 0..1
    const int wn = wid & 3;          // 0..3
    // grid 256 = 32 m-blocks x 8 n-strips; n-strip == XCD (round-robin)
    const int bid = blockIdx.x;
    const int n0 = (bid & 7) * 128;
    const int m0 = (bid >> 3) * 128;

    f32x4 acc[4][2][4];
    #pragma unroll
    for (int i = 0; i < 4; ++i)
        #pragma unroll
        for (int j = 0; j < 2; ++j)
            #pragma unroll
            for (int k = 0; k < 4; ++k) {
                f32x4 z = {0.f, 0.f, 0.f, 0.f};
                acc[i][j][k] = z;
            }

    const int lr = lane >> 3;                    // row within 8-row chunk
    const int kq = ((lane & 7) ^ lr) << 3;       // inverse-swizzled k offset (elems)

    auto stage = [&](int step, int buf) {
        const int k0 = step << 6;
        char* As_ = lds + buf * 65536;
        char* Bs_ = As_ + 16384;
        #pragma unroll
        for (int q = 0; q < 2; ++q) {
            int chunk = wid * 2 + q;             // 0..15 (8 rows each)
            const u16* gp = act + (size_t)(m0 + chunk * 8 + lr) * KCAT + k0 + kq;
            gl16(gp, As_ + chunk * 1024);
        }
        #pragma unroll
        for (int q = 0; q < 6; ++q) {
            int chunk = wid * 6 + q;             // 0..47 (8 W-rows each)
            int rbg = chunk * 8 + lr;            // 0..383: gate = rbg>>7, col = rbg&127
            const u16* gp = Wcat + (size_t)((rbg >> 7) * 1024 + n0 + (rbg & 127)) * KCAT + k0 + kq;
            gl16(gp, Bs_ + chunk * 1024);
        }
    };

    stage(0, 0);
    __syncthreads();
    int cur = 0;
    for (int step = 0; step < NSTEP_R; ++step) {       // r-part: n-gate -> i_n (slot 2)
        stage(step + 1, cur ^ 1);
        GRUF_STEP(2);
        __syncthreads();
        cur ^= 1;
    }
    for (int step = NSTEP_R; step < NSTEPS; ++step) {  // h-part: n-gate -> h_n (slot 3)
        if (step + 1 < NSTEPS) stage(step + 1, cur ^ 1);
        GRUF_STEP(3);
        __syncthreads();
        cur ^= 1;
    }

    #pragma unroll
    for (int fn = 0; fn < 2; ++fn) {
        const int jj = n0 + wn * 32 + fn * 16 + (lane & 15);
        const float bir = bih[jj],        bhr = bhh[jj];
        const float biz = bih[1024 + jj], bhz = bhh[1024 + jj];
        const float bin = bih[2048 + jj], bhn = bhh[2048 + jj];
        #pragma unroll
        for (int fm = 0; fm < 4; ++fm) {
            #pragma unroll
            for (int rg = 0; rg < 4; ++rg) {
                int m = m0 + wm * 64 + fm * 16 + (lane >> 4) * 4 + rg;
                float rz = acc[0][fn][fm][rg];
                float zz = acc[1][fn][fm][rg];
                float inn = acc[2][fn][fm][rg];
                float hnn = acc[3][fn][fm][rg];
                float rgate = 1.f / (1.f + expf(-(rz + bir + bhr)));
                float zgate = 1.f / (1.f + expf(-(zz + biz + bhz)));
                float ngate = tanhf(inn + bin + rgate * (hnn + bhn));
                size_t base = (size_t)m * KCAT + HOFF;
                float hv = b2f(act[base + jj]) + b2f(act[base + HIDD + jj]);
                float hnew = (1.f - zgate) * ngate + zgate * hv;
                u16 nh = f2b(hnew);
                actn[base + jj] = nh;
                actn[base + HIDD + jj] = f2b(hnew - b2f(nh));
            }
        }
    }
}

// out = h_new @ W_out^T + b_out via bf16 MFMA; M=4096, N=384(360), K'=2048
__global__ __launch_bounds__(256) void k_outp(
        const u16* __restrict__ act, const u16* __restrict__ Wo,
        const float* __restrict__ bo, float* __restrict__ outb) {
    __shared__ char lds[24576];          // A 16KB + B 8KB
    char* As = lds;
    char* Bs = lds + 16384;
    const int t = threadIdx.x, lane = t & 63, wid = t >> 6;
    const int wm = wid >> 1, wn = wid & 1;
    const int m0 = blockIdx.x * 128, n0 = blockIdx.y * 64;
    f32x4 acc[4][2];
    #pragma unroll
    for (int i = 0; i < 4; ++i)
        #pragma unroll
        for (int j = 0; j < 2; ++j) {
            f32x4 z = {0.f, 0.f, 0.f, 0.f};
            acc[i][j] = z;
        }
    for (int kt = 0; kt < 32; ++kt) {
        const int k0 = kt << 6;
        short8v ar[4], br[2];
        #pragma unroll
        for (int q = 0; q < 4; ++q) {
            int cc = t + (q << 8);
            int rr = cc >> 3, l = cc & 7;
            ar[q] = *(const short8v*)(act + (size_t)(m0 + rr) * KCAT + HOFF + k0 + l * 8);
        }
        #pragma unroll
        for (int q = 0; q < 2; ++q) {
            int cc = t + (q << 8);
            int rb = cc >> 3, l = cc & 7;
            br[q] = *(const short8v*)(Wo + (size_t)(n0 + rb) * KP2 + k0 + l * 8);
        }
        __syncthreads();
        #pragma unroll
        for (int q = 0; q < 4; ++q) {
            int cc = t + (q << 8);
            int rr = cc >> 3, l = cc & 7;
            *(short8v*)(As + rr * 128 + ((l ^ (rr & 7)) << 4)) = ar[q];
        }
        #pragma unroll
        for (int q = 0; q < 2; ++q) {
            int cc = t + (q << 8);
            int rb = cc >> 3, l = cc & 7;
            *(short8v*)(Bs + rb * 128 + ((l ^ (rb & 7)) << 4)) = br[q];
        }
        __syncthreads();
        #pragma unroll
        for (int s = 0; s < 2; ++s) {
            const int srow = lane & 15;
            const int slot = s * 4 + (lane >> 4);
            short8v af[4];
            #pragma unroll
            for (int fm = 0; fm < 4; ++fm) {
                int rr = wm * 64 + fm * 16 + srow;
                af[fm] = *(const short8v*)(As + rr * 128 + (((slot ^ (rr & 7)) & 7) << 4));
            }
            #pragma unroll
            for (int fn = 0; fn < 2; ++fn) {
                int rb = wn * 32 + fn * 16 + srow;
                short8v bf = *(const short8v*)(Bs + rb * 128 + (((slot ^ (rb & 7)) & 7) << 4));
                #pragma unroll
                for (int fm = 0; fm < 4; ++fm)
                    acc[fm][fn] = __builtin_amdgcn_mfma_f32_16x16x32_bf16(af[fm], bf, acc[fm][fn], 0, 0, 0);
            }
        }
    }
    #pragma unroll
    for (int fm = 0; fm < 4; ++fm) {
        #pragma unroll
        for (int fn = 0; fn < 2; ++fn) {
            int n = n0 + wn * 32 + fn * 16 + (lane & 15);
            if (n < NOUTD) {
                float bb = bo[n];
                #pragma unroll
                for (int rg = 0; rg < 4; ++rg) {
                    int m = m0 + wm * 64 + fm * 16 + (lane >> 4) * 4 + rg;
                    outb[(size_t)m * NOUTP + n] = acc[fm][fn][rg] + bb;
                }
            }
        }
    }
}

// s_fin/lam_fin (+ in-place state update) and fixed-point residual norm
__global__ __launch_bounds__(256) void k_fin(const float* __restrict__ snew, const float* __restrict__ lamn,
                     const float* __restrict__ outb,
                     float* __restrict__ s, float* __restrict__ lam,
                     float* __restrict__ fx) {
    __shared__ float redS[16][17];
    __shared__ float redL[16][17];
    int b0 = blockIdx.x * 16;
    int tm = threadIdx.x / 16;
    int tk = threadIdx.x % 16;
    int b = b0 + tm;
    float ds2 = 0.f, dl2 = 0.f;
    for (int k = tk; k < NCN; k += 16) {
        float o = outb[(size_t)b*NOUTP + k];
        float sf = fmaxf(0.f, snew[(size_t)b*NCN + k] + o);
        float so = s[(size_t)b*NCN + k];
        s[(size_t)b*NCN + k] = sf;
        float d = so - sf;
        ds2 += d * d;
    }
    for (int i = tk; i < NV; i += 16) {
        float o = outb[(size_t)b*NOUTP + NCN + i];
        float lf = lamn[(size_t)b*NV + i] + o;
        float lo = lam[(size_t)b*NV + i];
        lam[(size_t)b*NV + i] = lf;
        float d = lo - lf;
        dl2 += d * d;
    }
    redS[tm][tk] = ds2;
    redL[tm][tk] = dl2;
    __syncthreads();
    if (tk == 0) {
        float a = 0.f, l = 0.f;
        for (int q = 0; q < 16; ++q) { a += redS[tm][q]; l += redL[tm][q]; }
        fx[b] = sqrtf(l) + sqrtf(a);
    }
}

// ---------------------------------------------------------------------------
extern "C" void kernel_launch(void* const* d_in, const int* in_sizes, int n_in,
                              void* d_out, int out_size, void* d_ws, size_t ws_size,
                              hipStream_t stream) {
    const float* lamda_init = (const float*)d_in[0];
    // d_in[1] = s_init (unused: multiplied by 0 in reference)
    const float* h0    = (const float*)d_in[2];
    const float* H     = (const float*)d_in[3];
    const float* g     = (const float*)d_in[4];
    const float* C     = (const float*)d_in[5];
    const float* c     = (const float*)d_in[6];
    const float* W_ih  = (const float*)d_in[7];
    const float* b_ih  = (const float*)d_in[8];
    const float* W_hh  = (const float*)d_in[9];
    const float* b_hh  = (const float*)d_in[10];
    const float* W_out = (const float*)d_in[11];
    const float* b_out = (const float*)d_in[12];

    float* out    = (float*)d_out;
    float* xi_out = out;                       // [B,120]
    float* primal = out + (size_t)NB*NV;       // [8,B]
    float* fixedo = primal + (size_t)NITER*NB; // [8,B]
    float* qpres  = fixedo + (size_t)NITER*NB; // [8,B]

    char* wp = (char*)d_ws;
    auto alloc = [&](size_t bytes) {
        void* p = (void*)wp;
        wp += (bytes + 255) & ~(size_t)255;
        return p;
    };
    float* Amat  = (float*)alloc(NV*NV*4);
    float* A0m   = (float*)alloc(NV*NV*4);
    float* Qinv  = (float*)alloc(NV*NV*4);
    float* Qinv0 = (float*)alloc(NV*NV*4);
    float* s0v   = (float*)alloc(NCN*4);
    float* sbuf  = (float*)alloc((size_t)NB*NCN*4);
    float* snew  = (float*)alloc((size_t)NB*NCN*4);
    float* lam   = (float*)alloc((size_t)NB*NV*4);
    float* lamn  = (float*)alloc((size_t)NB*NV*4);
    float* xib   = (float*)alloc((size_t)NB*NV*4);
    float* Yb    = (float*)alloc((size_t)NB*NV*4);
    float* wb    = (float*)alloc(NB*4);
    float* outb  = (float*)alloc((size_t)NB*NOUTP*4);
    u16* actA    = (u16*)alloc((size_t)NB*KCAT*2);
    u16* actB    = (u16*)alloc((size_t)NB*KCAT*2);
    u16* Wcat    = (u16*)alloc((size_t)3072*KCAT*2);
    u16* Wopk    = (u16*)alloc((size_t)NOUTP*KP2*2);
    double* Gpart = (double*)alloc((size_t)NPART*NV*NV*8);
    double* vpart = (double*)alloc((size_t)NPART*NV*8);
    double* Spart = (double*)alloc(NPART*8);
    double* Gfin  = (double*)alloc(NV*NV*8);
    double* vfin  = (double*)alloc(NV*8);
    double* Sfin  = (double*)alloc(8);

    k_buildA<<<dim3(NV, 2), dim3(128), 0, stream>>>(H, C, Amat, A0m);
    k_invert<<<dim3(2), dim3(1024), 0, stream>>>(Amat, A0m, Qinv, Qinv0);
    k_s0<<<dim3(1), dim3(256), 0, stream>>>(Qinv0, g, C, c, s0v);
    k_init<<<dim3(NB/8), dim3(256), 0, stream>>>(s0v, lamda_init, sbuf, lam);
    k_packWcat<<<dim3(3072), dim3(256), 0, stream>>>(W_ih, W_hh, Wcat);
    k_packW<<<dim3(NOUTP), dim3(256), 0, stream>>>(W_out, Wopk, NOUTD, HIDD, 1024);
    k_packH<<<dim3(NB), dim3(256), 0, stream>>>(h0, actA);

    u16* hc = actA;
    u16* hn2 = actB;
    for (int it = 0; it < NITER; ++it) {
        k_xiproj<<<dim3(NB/16), dim3(512), 0, stream>>>(sbuf, lam, C, c, g, Qinv, H,
                                                        xib, Yb, wb, snew, lamn, hc,
                                                        primal + (size_t)it*NB);
        k_qp_part<<<dim3(NPART), dim3(256), 0, stream>>>(xib, wb, Gpart, vpart, Spart);
        k_qp_red<<<dim3((NV*NV + 255)/256), dim3(256), 0, stream>>>(Gpart, vpart, Spart, Gfin, vfin, Sfin);
        k_qp_norm<<<dim3(NB/16), dim3(256), 0, stream>>>(Yb, Gfin, vfin, Sfin, qpres + (size_t)it*NB);
        k_gruf<<<dim3(256), dim3(512), 0, stream>>>(hc, Wcat, b_ih, b_hh, hn2);
        k_outp<<<dim3(NB/128, NOUTP/64), dim3(256), 0, stream>>>(hn2, Wopk, b_out, outb);
        k_fin<<<dim3(NB/16), dim3(256), 0, stream>>>(snew, lamn, outb, sbuf, lam, fixedo + (size_t)it*NB);
        u16* tmp = hc; hc = hn2; hn2 = tmp;
    }
    hipMemcpyAsync(xi_out, xib, (size_t)NB*NV*sizeof(float), hipMemcpyDeviceToDevice, stream);
}

// Round 8
// 2668.565 us; speedup vs baseline: 5.5649x; 1.0506x over previous
//
#include <hip/hip_runtime.h>
#include <hip/hip_bf16.h>
#include <math.h>

// Problem constants (match reference)
#define NB    4096   // batch
#define NV    120    // NVAR
#define NCN   240    // num constraints
#define HIDD  1024   // GRU hidden
#define RINN  1080   // GRU input dim
#define NOUTD 360    // NC+NVAR
#define NOUTP 384    // padded out cols
#define NITER 8
#define REGEPS 1e-4f
#define NPART 128    // partial blocks for G reduction

// 2-term split: activations [hi|lo] (exact), weights stored ONCE (hi).
// act row: [r_hi 1088 | r_lo 1088 | h_hi 1024 | h_lo 1024] = 4224
// Wcat row: [Wih_hi 1088 | Whh_hi 1024] = 2112 (B-reuse pairing: each W
// block staged once, multiplied by both a_hi and a_lo into the same acc)
#define KCAT 4224
#define HOFF 2176    // h section start within an act row
#define KWC  2112    // Wcat K
#define KWO  1024    // W_out packed K
#define NSTEP_R 34   // r-section 32-wide K-steps (1088/32)
#define NSTEPS  66   // total (2112/32)

typedef unsigned short u16;
typedef __attribute__((ext_vector_type(8))) short short8v;
typedef __attribute__((ext_vector_type(4))) float f32x4;

__device__ inline u16 f2b(float x) {
    __hip_bfloat16 h = __float2bfloat16(x);
    return __builtin_bit_cast(u16, h);
}
__device__ inline float b2f(u16 u) {
    __hip_bfloat16 h = __builtin_bit_cast(__hip_bfloat16, u);
    return __bfloat162float(h);
}

// async global -> LDS, 16B per lane (wave-uniform LDS base + lane*16)
__device__ inline void gl16(const void* g, void* l) {
    __builtin_amdgcn_global_load_lds(
        (__attribute__((address_space(1))) void*)(void*)g,
        (__attribute__((address_space(3))) void*)l, 16, 0, 0);
}

// ---------------------------------------------------------------------------
// Build A = H + C^T C + REG*I (which==0) and A0 = H + REG*I (which==1)
__global__ void k_buildA(const float* __restrict__ H, const float* __restrict__ C,
                         float* __restrict__ A, float* __restrict__ A0) {
    int i = blockIdx.x;
    int which = blockIdx.y;
    for (int j = threadIdx.x; j < NV; j += blockDim.x) {
        float v = H[i*NV + j] + (i == j ? REGEPS : 0.f);
        if (which == 0) {
            float acc = 0.f;
            for (int k = 0; k < NCN; ++k) acc += C[k*NV + i] * C[k*NV + j];
            A[i*NV + j] = v + acc;   // RHO = 1
        } else {
            A0[i*NV + j] = v;
        }
    }
}

// Row-major 4x4 inverse via 2x2-subdeterminant adjugate (ILP-friendly).
__device__ inline void inv4x4(const float* m, float* inv) {
    float s0 = m[0]*m[5] - m[1]*m[4];
    float s1 = m[0]*m[6] - m[2]*m[4];
    float s2 = m[0]*m[7] - m[3]*m[4];
    float s3 = m[1]*m[6] - m[2]*m[5];
    float s4 = m[1]*m[7] - m[3]*m[5];
    float s5 = m[2]*m[7] - m[3]*m[6];
    float c5 = m[10]*m[15] - m[11]*m[14];
    float c4 = m[9]*m[15] - m[11]*m[13];
    float c3 = m[9]*m[14] - m[10]*m[13];
    float c2 = m[8]*m[15] - m[11]*m[12];
    float c1 = m[8]*m[14] - m[10]*m[12];
    float c0 = m[8]*m[13] - m[9]*m[12];
    float det = s0*c5 - s1*c4 + s2*c3 + s3*c2 - s4*c1 + s5*c0;
    float id = 1.0f / det;
    inv[0]  = ( m[5]*c5 - m[6]*c4 + m[7]*c3) * id;
    inv[1]  = (-m[1]*c5 + m[2]*c4 - m[3]*c3) * id;
    inv[2]  = ( m[13]*s5 - m[14]*s4 + m[15]*s3) * id;
    inv[3]  = (-m[9]*s5 + m[10]*s4 - m[11]*s3) * id;
    inv[4]  = (-m[4]*c5 + m[6]*c2 - m[7]*c1) * id;
    inv[5]  = ( m[0]*c5 - m[2]*c2 + m[3]*c1) * id;
    inv[6]  = (-m[12]*s5 + m[14]*s2 - m[15]*s1) * id;
    inv[7]  = ( m[8]*s5 - m[10]*s2 + m[11]*s1) * id;
    inv[8]  = ( m[4]*c4 - m[5]*c2 + m[7]*c0) * id;
    inv[9]  = (-m[0]*c4 + m[1]*c2 - m[3]*c0) * id;
    inv[10] = ( m[12]*s4 - m[13]*s2 + m[15]*s0) * id;
    inv[11] = (-m[8]*s4 + m[9]*s2 - m[11]*s0) * id;
    inv[12] = (-m[4]*c3 + m[5]*c1 - m[6]*c0) * id;
    inv[13] = ( m[0]*c3 - m[1]*c1 + m[2]*c0) * id;
    inv[14] = (-m[12]*s3 + m[13]*s1 - m[14]*s0) * id;
    inv[15] = ( m[8]*s3 - m[9]*s1 + m[10]*s0) * id;
}

// Blocked rank-4 Gauss-Jordan, phase-split: nothing long-lived crosses a
// barrier (rounds 5-7 spilled a/b/F/R arrays to scratch: WRITE_SIZE 240KB vs
// 115KB real). Phase A: ty==0 threads compute B=inv(A11) and R=B@pivotrows
// INTO LDS; all threads read F (16 VGPR only). Barrier. Phase B: update from
// LDS R/B (dynamic indexing hits LDS, not registers). 2 barriers/chunk.
__global__ __launch_bounds__(1024) void k_invert(const float* __restrict__ Ain,
                                                 const float* __restrict__ A0in,
                                                 float* __restrict__ Qi,
                                                 float* __restrict__ Qi0) {
    __shared__ float M[NV][132];
    __shared__ float Rl[4][132];
    __shared__ float Bl[16];
    const float* src = (blockIdx.x == 0) ? Ain : A0in;
    float* dst = (blockIdx.x == 0) ? Qi : Qi0;
    const int t = threadIdx.x;
    for (int idx = t; idx < NV*132; idx += 1024) {
        int i = idx / 132, j = idx - i*132;
        M[i][j] = (j < NV) ? src[i*NV + j] : 0.f;
    }
    __syncthreads();
    const int ty = t >> 5;        // 0..31 row owner (4 rows each)
    const int g4 = (t & 31) * 4;  // col group 0..124
    for (int kk = 0; kk < NV; kk += 4) {
        // Phase A: ty==0 lane-set computes B and R -> LDS (short-lived regs)
        if (ty == 0) {
            float a[16], b[16];
            #pragma unroll
            for (int p = 0; p < 4; ++p) {
                float4 v = *(const float4*)&M[kk + p][kk];
                a[p*4+0] = v.x; a[p*4+1] = v.y; a[p*4+2] = v.z; a[p*4+3] = v.w;
            }
            inv4x4(a, b);
            float4 m0v = *(const float4*)&M[kk+0][g4];
            float4 m1v = *(const float4*)&M[kk+1][g4];
            float4 m2v = *(const float4*)&M[kk+2][g4];
            float4 m3v = *(const float4*)&M[kk+3][g4];
            #pragma unroll
            for (int p = 0; p < 4; ++p) {
                float4 r;
                r.x = b[p*4+0]*m0v.x + b[p*4+1]*m1v.x + b[p*4+2]*m2v.x + b[p*4+3]*m3v.x;
                r.y = b[p*4+0]*m0v.y + b[p*4+1]*m1v.y + b[p*4+2]*m2v.y + b[p*4+3]*m3v.y;
                r.z = b[p*4+0]*m0v.z + b[p*4+1]*m1v.z + b[p*4+2]*m2v.z + b[p*4+3]*m3v.z;
                r.w = b[p*4+0]*m0v.w + b[p*4+1]*m1v.w + b[p*4+2]*m2v.w + b[p*4+3]*m3v.w;
                *(float4*)&Rl[p][g4] = r;
            }
            if (t < 16) Bl[t] = b[t];
        }
        // all threads: F for my 4 rows (original M, read before barrier)
        float4 F[4];
        #pragma unroll
        for (int q = 0; q < 4; ++q) {
            int i = ty + 32*q;
            F[q] = (i < NV) ? *(const float4*)&M[i][kk] : float4{0.f,0.f,0.f,0.f};
        }
        __syncthreads();
        // Phase B: update from LDS R / B
        #pragma unroll
        for (int q = 0; q < 4; ++q) {
            int i = ty + 32*q;
            if (i < NV) {
                int dp = i - kk;
                bool ispiv = (dp >= 0) && (dp < 4);
                float4 v;
                if (g4 == kk) {
                    if (ispiv) {
                        v = *(const float4*)&Bl[dp*4];
                    } else {
                        v.x = -(F[q].x*Bl[0] + F[q].y*Bl[4] + F[q].z*Bl[8]  + F[q].w*Bl[12]);
                        v.y = -(F[q].x*Bl[1] + F[q].y*Bl[5] + F[q].z*Bl[9]  + F[q].w*Bl[13]);
                        v.z = -(F[q].x*Bl[2] + F[q].y*Bl[6] + F[q].z*Bl[10] + F[q].w*Bl[14]);
                        v.w = -(F[q].x*Bl[3] + F[q].y*Bl[7] + F[q].z*Bl[11] + F[q].w*Bl[15]);
                    }
                } else if (ispiv) {
                    v = *(const float4*)&Rl[dp][g4];
                } else {
                    float4 r0 = *(const float4*)&Rl[0][g4];
                    float4 r1 = *(const float4*)&Rl[1][g4];
                    float4 r2 = *(const float4*)&Rl[2][g4];
                    float4 r3 = *(const float4*)&Rl[3][g4];
                    v = *(const float4*)&M[i][g4];
                    v.x -= F[q].x*r0.x + F[q].y*r1.x + F[q].z*r2.x + F[q].w*r3.x;
                    v.y -= F[q].x*r0.y + F[q].y*r1.y + F[q].z*r2.y + F[q].w*r3.y;
                    v.z -= F[q].x*r0.z + F[q].y*r1.z + F[q].z*r2.z + F[q].w*r3.z;
                    v.w -= F[q].x*r0.w + F[q].y*r1.w + F[q].z*r2.w + F[q].w*r3.w;
                }
                *(float4*)&M[i][g4] = v;
            }
        }
        __syncthreads();
    }
    for (int idx = t; idx < NV*NV; idx += 1024) {
        int i = idx / NV, j = idx - i*NV;
        dst[idx] = M[i][j];
    }
}

// xi0 = (-g) @ Qinv0^T ; s0 = max(0, c - C xi0)   (batch-constant vectors)
__global__ void k_s0(const float* __restrict__ Qi0, const float* __restrict__ g,
                     const float* __restrict__ C, const float* __restrict__ c,
                     float* __restrict__ s0v) {
    __shared__ float xi0[NV];
    int t = threadIdx.x;
    if (t < NV) {
        float a = 0.f;
        for (int j = 0; j < NV; ++j) a += Qi0[t*NV + j] * g[j];
        xi0[t] = -a;
    }
    __syncthreads();
    if (t < NCN) {
        float a = 0.f;
        for (int j = 0; j < NV; ++j) a += C[t*NV + j] * xi0[j];
        s0v[t] = fmaxf(0.f, c[t] - a);
    }
}

// Initialize state: s = broadcast(s0), lam = lamda_init
__global__ void k_init(const float* __restrict__ s0v, const float* __restrict__ lam0,
                       float* __restrict__ s, float* __restrict__ lam) {
    int b0 = blockIdx.x * 8;
    int t = threadIdx.x;
    for (int idx = t; idx < 8*NCN; idx += 256) {
        int m = idx / NCN, k = idx % NCN;
        s[(size_t)(b0 + m)*NCN + k] = s0v[k];
    }
    for (int idx = t; idx < 8*NV; idx += 256) lam[(size_t)b0*NV + idx] = lam0[(size_t)b0*NV + idx];
}

// Pack h0 into act buffer h-section: [h_hi | h_lo]
__global__ void k_packH(const float* __restrict__ h0, u16* __restrict__ act) {
    int n = blockIdx.x;
    size_t base = (size_t)n * KCAT + HOFF;
    for (int k = threadIdx.x; k < HIDD; k += 256) {
        float x = h0[(size_t)n * HIDD + k];
        u16 hi = f2b(x);
        act[base + k] = hi;
        act[base + HIDD + k] = f2b(x - b2f(hi));
    }
}

// Pack Wih+Whh (hi only, once): [Wih_hi 1088 | Whh_hi 1024]
__global__ void k_packWcat(const float* __restrict__ Wih, const float* __restrict__ Whh,
                           u16* __restrict__ Wc) {
    int n = blockIdx.x;   // 0..3071
    size_t base = (size_t)n * KWC;
    for (int k = threadIdx.x; k < 1088; k += 256)
        Wc[base + k] = f2b(k < RINN ? Wih[(size_t)n * RINN + k] : 0.f);
    for (int k = threadIdx.x; k < HIDD; k += 256)
        Wc[base + 1088 + k] = f2b(Whh[(size_t)n * HIDD + k]);
}

// Pack W_out (hi only): [NOUTP rows][1024]
__global__ void k_packWo(const float* __restrict__ src, u16* __restrict__ dst) {
    int n = blockIdx.x;
    size_t row = (size_t)n * KWO;
    for (int k = threadIdx.x; k < KWO; k += 256)
        dst[row + k] = f2b(n < NOUTD ? src[(size_t)n * HIDD + k] : 0.f);
}

__device__ inline void write2(u16* __restrict__ act, size_t base, int pos, float x) {
    u16 hi = f2b(x);
    u16 lo = f2b(x - b2f(hi));
    act[base + pos] = hi;
    act[base + 1088 + pos] = lo;
}

// Fused: xi solve + projection + GRU-input pack into act r-section.
__global__ __launch_bounds__(512) void k_xiproj(
        const float* __restrict__ s, const float* __restrict__ lam,
        const float* __restrict__ C, const float* __restrict__ c,
        const float* __restrict__ g, const float* __restrict__ Qi,
        const float* __restrict__ H,
        float* __restrict__ xi, float* __restrict__ Y, float* __restrict__ wv,
        float* __restrict__ snew, float* __restrict__ lamn,
        u16* __restrict__ act, float* __restrict__ primal) {
    __shared__ float bd[16][NCN];
    __shared__ float ul[16][NV];
    __shared__ float xl[16][NV];
    __shared__ float resl[16][NCN];
    int b0 = blockIdx.x * 16;
    int t = threadIdx.x;
    for (int idx = t; idx < 16*NCN; idx += 512) {
        int m = idx / NCN, k = idx % NCN;
        bd[m][k] = c[k] - s[(size_t)(b0 + m)*NCN + k];
    }
    __syncthreads();
    for (int idx = t; idx < 16*NV; idx += 512) {
        int m = idx / NV, j = idx % NV;
        float a = lam[(size_t)(b0 + m)*NV + j] - g[j];
        for (int k = 0; k < NCN; ++k) a += bd[m][k] * C[k*NV + j];
        ul[m][j] = a;
    }
    __syncthreads();
    for (int idx = t; idx < 16*NV; idx += 512) {
        int m = idx / NV, i = idx % NV;
        float a = 0.f;
        for (int j = 0; j < NV; ++j) a += Qi[j*NV + i] * ul[m][j];  // Qinv symmetric
        xl[m][i] = a;
        xi[(size_t)(b0 + m)*NV + i] = a;
    }
    __syncthreads();
    for (int idx = t; idx < 16*NV; idx += 512) {
        int m = idx / NV, i = idx % NV;
        float a = 0.f;
        for (int j = 0; j < NV; ++j) a += xl[m][j] * H[j*NV + i];
        Y[(size_t)(b0 + m)*NV + i] = a;
    }
    if (t < 16) {
        float a = 0.f;
        for (int j = 0; j < NV; ++j) a += xl[t][j] * g[j];
        wv[b0 + t] = a;
    }
    for (int idx = t; idx < 16*NCN; idx += 512) {
        int m = idx / NCN, k = idx % NCN;
        float a = 0.f;
        for (int j = 0; j < NV; ++j) a += C[k*NV + j] * xl[m][j];
        float sn = fmaxf(0.f, c[k] - a);
        float rv = a - c[k] + sn;
        resl[m][k] = rv;
        int b = b0 + m;
        snew[(size_t)b*NCN + k] = sn;
        float so = s[(size_t)b*NCN + k];
        size_t base = (size_t)b * KCAT;
        write2(act, base, k, so);
        write2(act, base, 360 + k, sn);
        write2(act, base, 720 + k, sn - so);
    }
    __syncthreads();
    if (t < 16) {
        float a = 0.f;
        for (int k = 0; k < NCN; ++k) a += resl[t][k] * resl[t][k];
        primal[b0 + t] = sqrtf(a);
    }
    for (int idx = t; idx < 16*NV; idx += 512) {
        int m = idx / NV, i = idx % NV;
        float a = 0.f;
        for (int k = 0; k < NCN; ++k) a += resl[m][k] * C[k*NV + i];
        int b = b0 + m;
        float lo = lam[(size_t)b*NV + i];
        float ln = lo - a;
        lamn[(size_t)b*NV + i] = ln;
        size_t base = (size_t)b * KCAT;
        write2(act, base, 240 + i, lo);
        write2(act, base, 600 + i, ln);
        write2(act, base, 960 + i, ln - lo);
    }
    for (int idx = t; idx < 16*8; idx += 512) {
        int m = idx >> 3, k = 1080 + (idx & 7);
        size_t base = (size_t)(b0 + m) * KCAT;
        act[base + k] = 0;
        act[base + 1088 + k] = 0;
    }
}

// Partial Gram: G_p = sum_m xi_m xi_m^T, v_p = sum_m w_m xi_m, S_p = sum w^2
__global__ __launch_bounds__(256) void k_qp_part(const float* __restrict__ xi, const float* __restrict__ wv,
                         double* __restrict__ Gp, double* __restrict__ vp, double* __restrict__ Sp) {
    __shared__ float xl[32][NV];
    __shared__ float wl[32];
    int p = blockIdx.x;
    int b0 = p * 32;
    int t = threadIdx.x;
    for (int idx = t; idx < 32*NV; idx += 256) xl[idx/NV][idx%NV] = xi[(size_t)b0*NV + idx];
    if (t < 32) wl[t] = wv[b0 + t];
    __syncthreads();
    for (int idx = t; idx < NV*NV; idx += 256) {
        int i = idx / NV, j = idx % NV;
        double a = 0.0;
        for (int m = 0; m < 32; ++m) a += (double)xl[m][i] * (double)xl[m][j];
        Gp[(size_t)p*NV*NV + idx] = a;
    }
    if (t < NV) {
        double a = 0.0;
        for (int m = 0; m < 32; ++m) a += (double)wl[m] * (double)xl[m][t];
        vp[(size_t)p*NV + t] = a;
    }
    if (t == 0) {
        double a = 0.0;
        for (int m = 0; m < 32; ++m) a += (double)wl[m] * (double)wl[m];
        Sp[p] = a;
    }
}

__global__ void k_qp_red(const double* __restrict__ Gp, const double* __restrict__ vp,
                         const double* __restrict__ Sp,
                         double* __restrict__ G, double* __restrict__ v, double* __restrict__ S) {
    int idx = blockIdx.x * 256 + threadIdx.x;
    if (idx < NV*NV) {
        double a = 0.0;
        for (int p = 0; p < NPART; ++p) a += Gp[(size_t)p*NV*NV + idx];
        G[idx] = a;
    }
    if (idx < NV) {
        double a = 0.0;
        for (int p = 0; p < NPART; ++p) a += vp[(size_t)p*NV + idx];
        v[idx] = a;
    }
    if (idx == 0) {
        double a = 0.0;
        for (int p = 0; p < NPART; ++p) a += Sp[p];
        S[0] = a;
    }
}

// qp_norm[b] = sqrt(0.25*Y^T G Y + Y.v + S)
__global__ __launch_bounds__(256) void k_qp_norm(const float* __restrict__ Y, const double* __restrict__ G,
                         const double* __restrict__ v, const double* __restrict__ S,
                         float* __restrict__ qp) {
    __shared__ float Yl[16][NV];
    __shared__ double tl[16][NV];
    int b0 = blockIdx.x * 16;
    int t = threadIdx.x;
    for (int idx = t; idx < 16*NV; idx += 256) Yl[idx/NV][idx%NV] = Y[(size_t)b0*NV + idx];
    __syncthreads();
    for (int idx = t; idx < 16*NV; idx += 256) {
        int m = idx / NV, i = idx % NV;
        double a = 0.0;
        for (int j = 0; j < NV; ++j) a += G[j*NV + i] * (double)Yl[m][j];  // G symmetric
        tl[m][i] = a;
    }
    __syncthreads();
    if (t < 16) {
        double a = 0.0, bv = 0.0;
        for (int i = 0; i < NV; ++i) { a += (double)Yl[t][i] * tl[t][i]; bv += (double)Yl[t][i] * v[i]; }
        double q = 0.25 * a + bv + S[0];
        qp[b0 + t] = (float)sqrt(q > 0.0 ? q : 0.0);
    }
}

// ---------------------------------------------------------------------------
// Fused GRU cell, B-reuse pairing: per 32-wide K-step stage {A_hi 8K, A_lo 8K,
// B 24K}; B fragments held in regs and used for BOTH a_hi and a_lo MFMA into
// the SAME accumulator (dot = a_hi.w + a_lo.w). Block 128 rows x 128 cols x 3
// gates; 512 thr = 8 waves (2m x 4n); double-buffered 2x40KB; one barrier per
// step. Swizzle f(rr)=(rr>>1)&3 on 16B units of 64B rows, applied to GLOBAL
// source (gl_lds dest is linear, rule #21) and on ds_read -> 2-way (free).
#define GRUF_STEP(NSLOT) do {                                                    \
    char* Ah_ = lds + cur * 40960;                                               \
    char* Al_ = Ah_ + 8192;                                                      \
    char* Bb_ = Ah_ + 16384;                                                     \
    const int srow = lane & 15;                                                  \
    const int ksl = lane >> 4;                                                   \
    short8v ah[4], al[4];                                                        \
    _Pragma("unroll")                                                            \
    for (int fm = 0; fm < 4; ++fm) {                                             \
        int rr = wm * 64 + fm * 16 + srow;                                       \
        int off = rr * 64 + ((ksl ^ ((rr >> 1) & 3)) << 4);                      \
        ah[fm] = *(const short8v*)(Ah_ + off);                                   \
        al[fm] = *(const short8v*)(Al_ + off);                                   \
    }                                                                            \
    _Pragma("unroll")                                                            \
    for (int fn = 0; fn < 2; ++fn) {                                             \
        int rb = wn * 32 + fn * 16 + srow;                                       \
        int boff = rb * 64 + ((ksl ^ ((rb >> 1) & 3)) << 4);                     \
        short8v bfr = *(const short8v*)(Bb_ + boff);                             \
        short8v bfz = *(const short8v*)(Bb_ + 8192 + boff);                      \
        short8v bfn = *(const short8v*)(Bb_ + 16384 + boff);                     \
        _Pragma("unroll")                                                        \
        for (int fm = 0; fm < 4; ++fm) {                                         \
            acc[0][fn][fm] = __builtin_amdgcn_mfma_f32_16x16x32_bf16(ah[fm], bfr, acc[0][fn][fm], 0, 0, 0); \
            acc[0][fn][fm] = __builtin_amdgcn_mfma_f32_16x16x32_bf16(al[fm], bfr, acc[0][fn][fm], 0, 0, 0); \
            acc[1][fn][fm] = __builtin_amdgcn_mfma_f32_16x16x32_bf16(ah[fm], bfz, acc[1][fn][fm], 0, 0, 0); \
            acc[1][fn][fm] = __builtin_amdgcn_mfma_f32_16x16x32_bf16(al[fm], bfz, acc[1][fn][fm], 0, 0, 0); \
            acc[NSLOT][fn][fm] = __builtin_amdgcn_mfma_f32_16x16x32_bf16(ah[fm], bfn, acc[NSLOT][fn][fm], 0, 0, 0); \
            acc[NSLOT][fn][fm] = __builtin_amdgcn_mfma_f32_16x16x32_bf16(al[fm], bfn, acc[NSLOT][fn][fm], 0, 0, 0); \
        }                                                                        \
    }                                                                            \
} while (0)

__global__ __launch_bounds__(512, 2) void k_gruf(
        const u16* __restrict__ act,   // [NB][KCAT]: r filled + h_cur
        const u16* __restrict__ Wc,    // [3*1024][KWC]
        const float* __restrict__ bih, const float* __restrict__ bhh,
        u16* __restrict__ actn) {      // h_new -> h-section
    __shared__ char lds[81920];        // 2 x (A_hi 8K + A_lo 8K + B 24K)
    const int t = threadIdx.x;
    const int lane = t & 63;
    const int wid = t >> 6;          // 0..7
    const int wm = wid >> 2;         // 0..1
    const int wn = wid & 3;          // 0..3
    // grid 256 = 32 m-blocks x 8 n-strips; n-strip == XCD (round-robin)
    const int bid = blockIdx.x;
    const int n0 = (bid & 7) * 128;
    const int m0 = (bid >> 3) * 128;

    f32x4 acc[4][2][4];
    #pragma unroll
    for (int i = 0; i < 4; ++i)
        #pragma unroll
        for (int j = 0; j < 2; ++j)
            #pragma unroll
            for (int k = 0; k < 4; ++k) {
                f32x4 z = {0.f, 0.f, 0.f, 0.f};
                acc[i][j][k] = z;
            }

    auto stage = [&](int step, int buf) {
        char* Ah_ = lds + buf * 40960;
        char* Al_ = Ah_ + 8192;
        char* Bb_ = Ah_ + 16384;
        const int hiOff = (step < NSTEP_R) ? step * 32 : step * 32 + 1088;
        const int loOff = hiOff + ((step < NSTEP_R) ? 1088 : 1024);
        const int wOff = step * 32;
        {
            int s = (wid << 6) + lane;
            int rr = s >> 2;
            int kq = ((lane & 3) ^ ((rr >> 1) & 3)) << 3;
            gl16(act + (size_t)(m0 + rr) * KCAT + hiOff + kq, Ah_ + wid * 1024);
            gl16(act + (size_t)(m0 + rr) * KCAT + loOff + kq, Al_ + wid * 1024);
        }
        #pragma unroll
        for (int q = 0; q < 3; ++q) {
            int cb = q * 8 + wid;
            int s2 = (cb << 6) + lane;
            int rbg = s2 >> 2;
            int kq = ((lane & 3) ^ ((rbg >> 1) & 3)) << 3;
            gl16(Wc + (size_t)((rbg >> 7) * 1024 + n0 + (rbg & 127)) * KWC + wOff + kq,
                 Bb_ + cb * 1024);
        }
    };

    stage(0, 0);
    __syncthreads();
    int cur = 0;
    for (int step = 0; step < NSTEP_R; ++step) {       // r-part: n-gate -> i_n
        stage(step + 1, cur ^ 1);
        GRUF_STEP(2);
        __syncthreads();
        cur ^= 1;
    }
    for (int step = NSTEP_R; step < NSTEPS; ++step) {  // h-part: n-gate -> h_n
        if (step + 1 < NSTEPS) stage(step + 1, cur ^ 1);
        GRUF_STEP(3);
        __syncthreads();
        cur ^= 1;
    }

    #pragma unroll
    for (int fn = 0; fn < 2; ++fn) {
        const int jj = n0 + wn * 32 + fn * 16 + (lane & 15);
        const float bir = bih[jj],        bhr = bhh[jj];
        const float biz = bih[1024 + jj], bhz = bhh[1024 + jj];
        const float bin = bih[2048 + jj], bhn = bhh[2048 + jj];
        #pragma unroll
        for (int fm = 0; fm < 4; ++fm) {
            #pragma unroll
            for (int rg = 0; rg < 4; ++rg) {
                int m = m0 + wm * 64 + fm * 16 + (lane >> 4) * 4 + rg;
                float rz = acc[0][fn][fm][rg];
                float zz = acc[1][fn][fm][rg];
                float inn = acc[2][fn][fm][rg];
                float hnn = acc[3][fn][fm][rg];
                float rgate = 1.f / (1.f + expf(-(rz + bir + bhr)));
                float zgate = 1.f / (1.f + expf(-(zz + biz + bhz)));
                float ngate = tanhf(inn + bin + rgate * (hnn + bhn));
                size_t base = (size_t)m * KCAT + HOFF;
                float hv = b2f(act[base + jj]) + b2f(act[base + HIDD + jj]);
                float hnew = (1.f - zgate) * ngate + zgate * hv;
                u16 nh = f2b(hnew);
                actn[base + jj] = nh;
                actn[base + HIDD + jj] = f2b(hnew - b2f(nh));
            }
        }
    }
}

// out = h_new @ W_out^T + b_out, same pairing structure; M=4096 N=384 K=1024.
__global__ __launch_bounds__(512, 2) void k_outp(
        const u16* __restrict__ act, const u16* __restrict__ Wo,
        const float* __restrict__ bo, float* __restrict__ outb) {
    __shared__ char lds[49152];        // 2 x (A_hi 8K + A_lo 8K + B 8K)
    const int t = threadIdx.x;
    const int lane = t & 63;
    const int wid = t >> 6;
    const int wm = wid >> 2;           // 0..1
    const int wn = wid & 3;            // 0..3
    const int m0 = blockIdx.x * 128;
    const int n0 = blockIdx.y * 128;
    f32x4 acc[2][4];
    #pragma unroll
    for (int i = 0; i < 2; ++i)
        #pragma unroll
        for (int j = 0; j < 4; ++j) {
            f32x4 z = {0.f, 0.f, 0.f, 0.f};
            acc[i][j] = z;
        }

    auto stage = [&](int step, int buf) {
        char* Ah_ = lds + buf * 24576;
        char* Al_ = Ah_ + 8192;
        char* Bb_ = Ah_ + 16384;
        const int hiOff = HOFF + step * 32;
        const int loOff = HOFF + HIDD + step * 32;
        int s = (wid << 6) + lane;
        int rr = s >> 2;
        int kq = ((lane & 3) ^ ((rr >> 1) & 3)) << 3;
        gl16(act + (size_t)(m0 + rr) * KCAT + hiOff + kq, Ah_ + wid * 1024);
        gl16(act + (size_t)(m0 + rr) * KCAT + loOff + kq, Al_ + wid * 1024);
        gl16(Wo + (size_t)(n0 + rr) * KWO + step * 32 + kq, Bb_ + wid * 1024);
    };

    stage(0, 0);
    __syncthreads();
    int cur = 0;
    for (int step = 0; step < 32; ++step) {
        if (step + 1 < 32) stage(step + 1, cur ^ 1);
        {
            char* Ah_ = lds + cur * 24576;
            char* Al_ = Ah_ + 8192;
            char* Bb_ = Ah_ + 16384;
            const int srow = lane & 15;
            const int ksl = lane >> 4;
            short8v ah[4], al[4];
            #pragma unroll
            for (int fm = 0; fm < 4; ++fm) {
                int rr = wm * 64 + fm * 16 + srow;
                int off = rr * 64 + ((ksl ^ ((rr >> 1) & 3)) << 4);
                ah[fm] = *(const short8v*)(Ah_ + off);
                al[fm] = *(const short8v*)(Al_ + off);
            }
            #pragma unroll
            for (int fn = 0; fn < 2; ++fn) {
                int rb = wn * 32 + fn * 16 + srow;
                int boff = rb * 64 + ((ksl ^ ((rb >> 1) & 3)) << 4);
                short8v bf = *(const short8v*)(Bb_ + boff);
                #pragma unroll
                for (int fm = 0; fm < 4; ++fm) {
                    acc[fn][fm] = __builtin_amdgcn_mfma_f32_16x16x32_bf16(ah[fm], bf, acc[fn][fm], 0, 0, 0);
                    acc[fn][fm] = __builtin_amdgcn_mfma_f32_16x16x32_bf16(al[fm], bf, acc[fn][fm], 0, 0, 0);
                }
            }
        }
        __syncthreads();
        cur ^= 1;
    }
    #pragma unroll
    for (int fn = 0; fn < 2; ++fn) {
        int n = n0 + wn * 32 + fn * 16 + (lane & 15);
        if (n < NOUTD) {
            float bb = bo[n];
            #pragma unroll
            for (int fm = 0; fm < 4; ++fm) {
                #pragma unroll
                for (int rg = 0; rg < 4; ++rg) {
                    int m = m0 + wm * 64 + fm * 16 + (lane >> 4) * 4 + rg;
                    outb[(size_t)m * NOUTP + n] = acc[fn][fm][rg] + bb;
                }
            }
        }
    }
}

// s_fin/lam_fin (+ in-place state update) and fixed-point residual norm
__global__ __launch_bounds__(256) void k_fin(const float* __restrict__ snew, const float* __restrict__ lamn,
                     const float* __restrict__ outb,
                     float* __restrict__ s, float* __restrict__ lam,
                     float* __restrict__ fx) {
    __shared__ float redS[16][17];
    __shared__ float redL[16][17];
    int b0 = blockIdx.x * 16;
    int tm = threadIdx.x / 16;
    int tk = threadIdx.x % 16;
    int b = b0 + tm;
    float ds2 = 0.f, dl2 = 0.f;
    for (int k = tk; k < NCN; k += 16) {
        float o = outb[(size_t)b*NOUTP + k];
        float sf = fmaxf(0.f, snew[(size_t)b*NCN + k] + o);
        float so = s[(size_t)b*NCN + k];
        s[(size_t)b*NCN + k] = sf;
        float d = so - sf;
        ds2 += d * d;
    }
    for (int i = tk; i < NV; i += 16) {
        float o = outb[(size_t)b*NOUTP + NCN + i];
        float lf = lamn[(size_t)b*NV + i] + o;
        float lo = lam[(size_t)b*NV + i];
        lam[(size_t)b*NV + i] = lf;
        float d = lo - lf;
        dl2 += d * d;
    }
    redS[tm][tk] = ds2;
    redL[tm][tk] = dl2;
    __syncthreads();
    if (tk == 0) {
        float a = 0.f, l = 0.f;
        for (int q = 0; q < 16; ++q) { a += redS[tm][q]; l += redL[tm][q]; }
        fx[b] = sqrtf(l) + sqrtf(a);
    }
}

// ---------------------------------------------------------------------------
extern "C" void kernel_launch(void* const* d_in, const int* in_sizes, int n_in,
                              void* d_out, int out_size, void* d_ws, size_t ws_size,
                              hipStream_t stream) {
    const float* lamda_init = (const float*)d_in[0];
    // d_in[1] = s_init (unused: multiplied by 0 in reference)
    const float* h0    = (const float*)d_in[2];
    const float* H     = (const float*)d_in[3];
    const float* g     = (const float*)d_in[4];
    const float* C     = (const float*)d_in[5];
    const float* c     = (const float*)d_in[6];
    const float* W_ih  = (const float*)d_in[7];
    const float* b_ih  = (const float*)d_in[8];
    const float* W_hh  = (const float*)d_in[9];
    const float* b_hh  = (const float*)d_in[10];
    const float* W_out = (const float*)d_in[11];
    const float* b_out = (const float*)d_in[12];

    float* out    = (float*)d_out;
    float* xi_out = out;                       // [B,120]
    float* primal = out + (size_t)NB*NV;       // [8,B]
    float* fixedo = primal + (size_t)NITER*NB; // [8,B]
    float* qpres  = fixedo + (size_t)NITER*NB; // [8,B]

    char* wp = (char*)d_ws;
    auto alloc = [&](size_t bytes) {
        void* p = (void*)wp;
        wp += (bytes + 255) & ~(size_t)255;
        return p;
    };
    float* Amat  = (float*)alloc(NV*NV*4);
    float* A0m   = (float*)alloc(NV*NV*4);
    float* Qinv  = (float*)alloc(NV*NV*4);
    float* Qinv0 = (float*)alloc(NV*NV*4);
    float* s0v   = (float*)alloc(NCN*4);
    float* sbuf  = (float*)alloc((size_t)NB*NCN*4);
    float* snew  = (float*)alloc((size_t)NB*NCN*4);
    float* lam   = (float*)alloc((size_t)NB*NV*4);
    float* lamn  = (float*)alloc((size_t)NB*NV*4);
    float* xib   = (float*)alloc((size_t)NB*NV*4);
    float* Yb    = (float*)alloc((size_t)NB*NV*4);
    float* wb    = (float*)alloc(NB*4);
    float* outb  = (float*)alloc((size_t)NB*NOUTP*4);
    u16* actA    = (u16*)alloc((size_t)NB*KCAT*2);
    u16* actB    = (u16*)alloc((size_t)NB*KCAT*2);
    u16* Wcat    = (u16*)alloc((size_t)3072*KWC*2);
    u16* Wopk    = (u16*)alloc((size_t)NOUTP*KWO*2);
    double* Gpart = (double*)alloc((size_t)NPART*NV*NV*8);
    double* vpart = (double*)alloc((size_t)NPART*NV*8);
    double* Spart = (double*)alloc(NPART*8);
    double* Gfin  = (double*)alloc(NV*NV*8);
    double* vfin  = (double*)alloc(NV*8);
    double* Sfin  = (double*)alloc(8);

    k_buildA<<<dim3(NV, 2), dim3(128), 0, stream>>>(H, C, Amat, A0m);
    k_invert<<<dim3(2), dim3(1024), 0, stream>>>(Amat, A0m, Qinv, Qinv0);
    k_s0<<<dim3(1), dim3(256), 0, stream>>>(Qinv0, g, C, c, s0v);
    k_init<<<dim3(NB/8), dim3(256), 0, stream>>>(s0v, lamda_init, sbuf, lam);
    k_packWcat<<<dim3(3072), dim3(256), 0, stream>>>(W_ih, W_hh, Wcat);
    k_packWo<<<dim3(NOUTP), dim3(256), 0, stream>>>(W_out, Wopk);
    k_packH<<<dim3(NB), dim3(256), 0, stream>>>(h0, actA);

    u16* hc = actA;
    u16* hn2 = actB;
    for (int it = 0; it < NITER; ++it) {
        k_xiproj<<<dim3(NB/16), dim3(512), 0, stream>>>(sbuf, lam, C, c, g, Qinv, H,
                                                        xib, Yb, wb, snew, lamn, hc,
                                                        primal + (size_t)it*NB);
        k_qp_part<<<dim3(NPART), dim3(256), 0, stream>>>(xib, wb, Gpart, vpart, Spart);
        k_qp_red<<<dim3((NV*NV + 255)/256), dim3(256), 0, stream>>>(Gpart, vpart, Spart, Gfin, vfin, Sfin);
        k_qp_norm<<<dim3(NB/16), dim3(256), 0, stream>>>(Yb, Gfin, vfin, Sfin, qpres + (size_t)it*NB);
        k_gruf<<<dim3(256), dim3(512), 0, stream>>>(hc, Wcat, b_ih, b_hh, hn2);
        k_outp<<<dim3(NB/128, 3), dim3(512), 0, stream>>>(hn2, Wopk, b_out, outb);
        k_fin<<<dim3(NB/16), dim3(256), 0, stream>>>(snew, lamn, outb, sbuf, lam, fixedo + (size_t)it*NB);
        u16* tmp = hc; hc = hn2; hn2 = tmp;
    }
    hipMemcpyAsync(xi_out, xib, (size_t)NB*NV*sizeof(float), hipMemcpyDeviceToDevice, stream);
}

// Round 9
// 2585.632 us; speedup vs baseline: 5.7434x; 1.0321x over previous
//
#include <hip/hip_runtime.h>
#include <hip/hip_bf16.h>
#include <math.h>

// Problem constants (match reference)
#define NB    4096   // num_batch
#define NV    120    // NVAR
#define NCN   240    // num constraints
#define HIDD  1024   // GRU hidden
#define RINN  1080   // GRU input dim
#define NOUTD 360    // NC+NVAR
#define NOUTP 384    // padded out cols
#define NITER 8
#define REGEPS 1e-4f
#define NPART 128    // partial blocks for G reduction

// 2-term split: activations [hi|lo] (exact), weights stored ONCE (hi).
// act row: [r_hi 1088 | r_lo 1088 | h_hi 1024 | h_lo 1024] = 4224
// Wcat row: [Wih_hi 1088 | Whh_hi 1024] = 2112 (B-reuse pairing: each W
// block staged once, multiplied by both a_hi and a_lo into the same acc)
#define KCAT 4224
#define HOFF 2176    // h section start within an act row
#define KWC  2112    // Wcat K
#define KWO  1024    // W_out packed K
#define NSTEP_R 34   // r-section 32-wide K-steps (1088/32)
#define NSTEPS  66   // total (2112/32)

typedef unsigned short u16;
typedef __attribute__((ext_vector_type(8))) short short8v;
typedef __attribute__((ext_vector_type(4))) float f32x4;

__device__ inline u16 f2b(float x) {
    __hip_bfloat16 h = __float2bfloat16(x);
    return __builtin_bit_cast(u16, h);
}
__device__ inline float b2f(u16 u) {
    __hip_bfloat16 h = __builtin_bit_cast(__hip_bfloat16, u);
    return __bfloat162float(h);
}

// async global -> LDS, 16B per lane (wave-uniform LDS base + lane*16)
__device__ inline void gl16(const void* g, void* l) {
    __builtin_amdgcn_global_load_lds(
        (__attribute__((address_space(1))) void*)(void*)g,
        (__attribute__((address_space(3))) void*)l, 16, 0, 0);
}

// ---------------------------------------------------------------------------
// Build A = H + C^T C + REG*I (which==0) and A0 = H + REG*I (which==1)
__global__ void k_buildA(const float* __restrict__ H, const float* __restrict__ C,
                         float* __restrict__ A, float* __restrict__ A0) {
    int i = blockIdx.x;
    int which = blockIdx.y;
    for (int j = threadIdx.x; j < NV; j += blockDim.x) {
        float v = H[i*NV + j] + (i == j ? REGEPS : 0.f);
        if (which == 0) {
            float acc = 0.f;
            for (int k = 0; k < NCN; ++k) acc += C[k*NV + i] * C[k*NV + j];
            A[i*NV + j] = v + acc;   // RHO = 1
        } else {
            A0[i*NV + j] = v;
        }
    }
}

// Row-major 4x4 inverse via 2x2-subdeterminant adjugate (ILP-friendly).
__device__ inline void inv4x4(const float* m, float* inv) {
    float s0 = m[0]*m[5] - m[1]*m[4];
    float s1 = m[0]*m[6] - m[2]*m[4];
    float s2 = m[0]*m[7] - m[3]*m[4];
    float s3 = m[1]*m[6] - m[2]*m[5];
    float s4 = m[1]*m[7] - m[3]*m[5];
    float s5 = m[2]*m[7] - m[3]*m[6];
    float c5 = m[10]*m[15] - m[11]*m[14];
    float c4 = m[9]*m[15] - m[11]*m[13];
    float c3 = m[9]*m[14] - m[10]*m[13];
    float c2 = m[8]*m[15] - m[11]*m[12];
    float c1 = m[8]*m[14] - m[10]*m[12];
    float c0 = m[8]*m[13] - m[9]*m[12];
    float det = s0*c5 - s1*c4 + s2*c3 + s3*c2 - s4*c1 + s5*c0;
    float id = 1.0f / det;
    inv[0]  = ( m[5]*c5 - m[6]*c4 + m[7]*c3) * id;
    inv[1]  = (-m[1]*c5 + m[2]*c4 - m[3]*c3) * id;
    inv[2]  = ( m[13]*s5 - m[14]*s4 + m[15]*s3) * id;
    inv[3]  = (-m[9]*s5 + m[10]*s4 - m[11]*s3) * id;
    inv[4]  = (-m[4]*c5 + m[6]*c2 - m[7]*c1) * id;
    inv[5]  = ( m[0]*c5 - m[2]*c2 + m[3]*c1) * id;
    inv[6]  = (-m[12]*s5 + m[14]*s2 - m[15]*s1) * id;
    inv[7]  = ( m[8]*s5 - m[10]*s2 + m[11]*s1) * id;
    inv[8]  = ( m[4]*c4 - m[5]*c2 + m[7]*c0) * id;
    inv[9]  = (-m[0]*c4 + m[1]*c2 - m[3]*c0) * id;
    inv[10] = ( m[12]*s4 - m[13]*s2 + m[15]*s0) * id;
    inv[11] = (-m[8]*s4 + m[9]*s2 - m[11]*s0) * id;
    inv[12] = (-m[4]*c3 + m[5]*c1 - m[6]*c0) * id;
    inv[13] = ( m[0]*c3 - m[1]*c1 + m[2]*c0) * id;
    inv[14] = (-m[12]*s3 + m[13]*s1 - m[14]*s0) * id;
    inv[15] = ( m[8]*s3 - m[9]*s1 + m[10]*s0) * id;
}

// Blocked rank-4 Gauss-Jordan, phase-split (nothing long-lived crosses a
// barrier). 2 barriers/chunk, 30 chunks.
__global__ __launch_bounds__(1024) void k_invert(const float* __restrict__ Ain,
                                                 const float* __restrict__ A0in,
                                                 float* __restrict__ Qi,
                                                 float* __restrict__ Qi0) {
    __shared__ float M[NV][132];
    __shared__ float Rl[4][132];
    __shared__ float Bl[16];
    const float* src = (blockIdx.x == 0) ? Ain : A0in;
    float* dst = (blockIdx.x == 0) ? Qi : Qi0;
    const int t = threadIdx.x;
    for (int idx = t; idx < NV*132; idx += 1024) {
        int i = idx / 132, j = idx - i*132;
        M[i][j] = (j < NV) ? src[i*NV + j] : 0.f;
    }
    __syncthreads();
    const int ty = t >> 5;        // 0..31 row owner (4 rows each)
    const int g4 = (t & 31) * 4;  // col group 0..124
    for (int kk = 0; kk < NV; kk += 4) {
        if (ty == 0) {
            float a[16], b[16];
            #pragma unroll
            for (int p = 0; p < 4; ++p) {
                float4 v = *(const float4*)&M[kk + p][kk];
                a[p*4+0] = v.x; a[p*4+1] = v.y; a[p*4+2] = v.z; a[p*4+3] = v.w;
            }
            inv4x4(a, b);
            float4 m0v = *(const float4*)&M[kk+0][g4];
            float4 m1v = *(const float4*)&M[kk+1][g4];
            float4 m2v = *(const float4*)&M[kk+2][g4];
            float4 m3v = *(const float4*)&M[kk+3][g4];
            #pragma unroll
            for (int p = 0; p < 4; ++p) {
                float4 r;
                r.x = b[p*4+0]*m0v.x + b[p*4+1]*m1v.x + b[p*4+2]*m2v.x + b[p*4+3]*m3v.x;
                r.y = b[p*4+0]*m0v.y + b[p*4+1]*m1v.y + b[p*4+2]*m2v.y + b[p*4+3]*m3v.y;
                r.z = b[p*4+0]*m0v.z + b[p*4+1]*m1v.z + b[p*4+2]*m2v.z + b[p*4+3]*m3v.z;
                r.w = b[p*4+0]*m0v.w + b[p*4+1]*m1v.w + b[p*4+2]*m2v.w + b[p*4+3]*m3v.w;
                *(float4*)&Rl[p][g4] = r;
            }
            if (t < 16) Bl[t] = b[t];
        }
        float4 F[4];
        #pragma unroll
        for (int q = 0; q < 4; ++q) {
            int i = ty + 32*q;
            F[q] = (i < NV) ? *(const float4*)&M[i][kk] : float4{0.f,0.f,0.f,0.f};
        }
        __syncthreads();
        #pragma unroll
        for (int q = 0; q < 4; ++q) {
            int i = ty + 32*q;
            if (i < NV) {
                int dp = i - kk;
                bool ispiv = (dp >= 0) && (dp < 4);
                float4 v;
                if (g4 == kk) {
                    if (ispiv) {
                        v = *(const float4*)&Bl[dp*4];
                    } else {
                        v.x = -(F[q].x*Bl[0] + F[q].y*Bl[4] + F[q].z*Bl[8]  + F[q].w*Bl[12]);
                        v.y = -(F[q].x*Bl[1] + F[q].y*Bl[5] + F[q].z*Bl[9]  + F[q].w*Bl[13]);
                        v.z = -(F[q].x*Bl[2] + F[q].y*Bl[6] + F[q].z*Bl[10] + F[q].w*Bl[14]);
                        v.w = -(F[q].x*Bl[3] + F[q].y*Bl[7] + F[q].z*Bl[11] + F[q].w*Bl[15]);
                    }
                } else if (ispiv) {
                    v = *(const float4*)&Rl[dp][g4];
                } else {
                    float4 r0 = *(const float4*)&Rl[0][g4];
                    float4 r1 = *(const float4*)&Rl[1][g4];
                    float4 r2 = *(const float4*)&Rl[2][g4];
                    float4 r3 = *(const float4*)&Rl[3][g4];
                    v = *(const float4*)&M[i][g4];
                    v.x -= F[q].x*r0.x + F[q].y*r1.x + F[q].z*r2.x + F[q].w*r3.x;
                    v.y -= F[q].x*r0.y + F[q].y*r1.y + F[q].z*r2.y + F[q].w*r3.y;
                    v.z -= F[q].x*r0.z + F[q].y*r1.z + F[q].z*r2.z + F[q].w*r3.z;
                    v.w -= F[q].x*r0.w + F[q].y*r1.w + F[q].z*r2.w + F[q].w*r3.w;
                }
                *(float4*)&M[i][g4] = v;
            }
        }
        __syncthreads();
    }
    for (int idx = t; idx < NV*NV; idx += 1024) {
        int i = idx / NV, j = idx - i*NV;
        dst[idx] = M[i][j];
    }
}

// xi0 = (-g) @ Qinv0^T ; s0 = max(0, c - C xi0)   (batch-constant vectors)
__global__ void k_s0(const float* __restrict__ Qi0, const float* __restrict__ g,
                     const float* __restrict__ C, const float* __restrict__ c,
                     float* __restrict__ s0v) {
    __shared__ float xi0[NV];
    int t = threadIdx.x;
    if (t < NV) {
        float a = 0.f;
        for (int j = 0; j < NV; ++j) a += Qi0[t*NV + j] * g[j];
        xi0[t] = -a;
    }
    __syncthreads();
    if (t < NCN) {
        float a = 0.f;
        for (int j = 0; j < NV; ++j) a += C[t*NV + j] * xi0[j];
        s0v[t] = fmaxf(0.f, c[t] - a);
    }
}

// Initialize state: s = broadcast(s0), lam = lamda_init
__global__ void k_init(const float* __restrict__ s0v, const float* __restrict__ lam0,
                       float* __restrict__ s, float* __restrict__ lam) {
    int b0 = blockIdx.x * 8;
    int t = threadIdx.x;
    for (int idx = t; idx < 8*NCN; idx += 256) {
        int m = idx / NCN, k = idx % NCN;
        s[(size_t)(b0 + m)*NCN + k] = s0v[k];
    }
    for (int idx = t; idx < 8*NV; idx += 256) lam[(size_t)b0*NV + idx] = lam0[(size_t)b0*NV + idx];
}

// Pack h0 into act buffer h-section: [h_hi | h_lo]
__global__ void k_packH(const float* __restrict__ h0, u16* __restrict__ act) {
    int n = blockIdx.x;
    size_t base = (size_t)n * KCAT + HOFF;
    for (int k = threadIdx.x; k < HIDD; k += 256) {
        float x = h0[(size_t)n * HIDD + k];
        u16 hi = f2b(x);
        act[base + k] = hi;
        act[base + HIDD + k] = f2b(x - b2f(hi));
    }
}

// Pack Wih+Whh (hi only, once): [Wih_hi 1088 | Whh_hi 1024]
__global__ void k_packWcat(const float* __restrict__ Wih, const float* __restrict__ Whh,
                           u16* __restrict__ Wc) {
    int n = blockIdx.x;   // 0..3071
    size_t base = (size_t)n * KWC;
    for (int k = threadIdx.x; k < 1088; k += 256)
        Wc[base + k] = f2b(k < RINN ? Wih[(size_t)n * RINN + k] : 0.f);
    for (int k = threadIdx.x; k < HIDD; k += 256)
        Wc[base + 1088 + k] = f2b(Whh[(size_t)n * HIDD + k]);
}

// Pack W_out (hi only): [NOUTP rows][1024]
__global__ void k_packWo(const float* __restrict__ src, u16* __restrict__ dst) {
    int n = blockIdx.x;
    size_t row = (size_t)n * KWO;
    for (int k = threadIdx.x; k < KWO; k += 256)
        dst[row + k] = f2b(n < NOUTD ? src[(size_t)n * HIDD + k] : 0.f);
}

__device__ inline void write2(u16* __restrict__ act, size_t base, int pos, float x) {
    u16 hi = f2b(x);
    u16 lo = f2b(x - b2f(hi));
    act[base + pos] = hi;
    act[base + 1088 + pos] = lo;
}

// Fused: xi solve + projection + GRU-input pack into act r-section.
__global__ __launch_bounds__(512) void k_xiproj(
        const float* __restrict__ s, const float* __restrict__ lam,
        const float* __restrict__ C, const float* __restrict__ c,
        const float* __restrict__ g, const float* __restrict__ Qi,
        const float* __restrict__ H,
        float* __restrict__ xi, float* __restrict__ Y, float* __restrict__ wv,
        float* __restrict__ snew, float* __restrict__ lamn,
        u16* __restrict__ act, float* __restrict__ primal) {
    __shared__ float bd[16][NCN];
    __shared__ float ul[16][NV];
    __shared__ float xl[16][NV];
    __shared__ float resl[16][NCN];
    int b0 = blockIdx.x * 16;
    int t = threadIdx.x;
    for (int idx = t; idx < 16*NCN; idx += 512) {
        int m = idx / NCN, k = idx % NCN;
        bd[m][k] = c[k] - s[(size_t)(b0 + m)*NCN + k];
    }
    __syncthreads();
    for (int idx = t; idx < 16*NV; idx += 512) {
        int m = idx / NV, j = idx % NV;
        float a = lam[(size_t)(b0 + m)*NV + j] - g[j];
        for (int k = 0; k < NCN; ++k) a += bd[m][k] * C[k*NV + j];
        ul[m][j] = a;
    }
    __syncthreads();
    for (int idx = t; idx < 16*NV; idx += 512) {
        int m = idx / NV, i = idx % NV;
        float a = 0.f;
        for (int j = 0; j < NV; ++j) a += Qi[j*NV + i] * ul[m][j];  // Qinv symmetric
        xl[m][i] = a;
        xi[(size_t)(b0 + m)*NV + i] = a;
    }
    __syncthreads();
    for (int idx = t; idx < 16*NV; idx += 512) {
        int m = idx / NV, i = idx % NV;
        float a = 0.f;
        for (int j = 0; j < NV; ++j) a += xl[m][j] * H[j*NV + i];
        Y[(size_t)(b0 + m)*NV + i] = a;
    }
    if (t < 16) {
        float a = 0.f;
        for (int j = 0; j < NV; ++j) a += xl[t][j] * g[j];
        wv[b0 + t] = a;
    }
    for (int idx = t; idx < 16*NCN; idx += 512) {
        int m = idx / NCN, k = idx % NCN;
        float a = 0.f;
        for (int j = 0; j < NV; ++j) a += C[k*NV + j] * xl[m][j];
        float sn = fmaxf(0.f, c[k] - a);
        float rv = a - c[k] + sn;
        resl[m][k] = rv;
        int b = b0 + m;
        snew[(size_t)b*NCN + k] = sn;
        float so = s[(size_t)b*NCN + k];
        size_t base = (size_t)b * KCAT;
        write2(act, base, k, so);
        write2(act, base, 360 + k, sn);
        write2(act, base, 720 + k, sn - so);
    }
    __syncthreads();
    if (t < 16) {
        float a = 0.f;
        for (int k = 0; k < NCN; ++k) a += resl[t][k] * resl[t][k];
        primal[b0 + t] = sqrtf(a);
    }
    for (int idx = t; idx < 16*NV; idx += 512) {
        int m = idx / NV, i = idx % NV;
        float a = 0.f;
        for (int k = 0; k < NCN; ++k) a += resl[m][k] * C[k*NV + i];
        int b = b0 + m;
        float lo = lam[(size_t)b*NV + i];
        float ln = lo - a;
        lamn[(size_t)b*NV + i] = ln;
        size_t base = (size_t)b * KCAT;
        write2(act, base, 240 + i, lo);
        write2(act, base, 600 + i, ln);
        write2(act, base, 960 + i, ln - lo);
    }
    for (int idx = t; idx < 16*8; idx += 512) {
        int m = idx >> 3, k = 1080 + (idx & 7);
        size_t base = (size_t)(b0 + m) * KCAT;
        act[base + k] = 0;
        act[base + 1088 + k] = 0;
    }
}

// Partial Gram: G_p = sum_m xi_m xi_m^T, v_p = sum_m w_m xi_m, S_p = sum w^2
__global__ __launch_bounds__(256) void k_qp_part(const float* __restrict__ xi, const float* __restrict__ wv,
                         double* __restrict__ Gp, double* __restrict__ vp, double* __restrict__ Sp) {
    __shared__ float xl[32][NV];
    __shared__ float wl[32];
    int p = blockIdx.x;
    int b0 = p * 32;
    int t = threadIdx.x;
    for (int idx = t; idx < 32*NV; idx += 256) xl[idx/NV][idx%NV] = xi[(size_t)b0*NV + idx];
    if (t < 32) wl[t] = wv[b0 + t];
    __syncthreads();
    for (int idx = t; idx < NV*NV; idx += 256) {
        int i = idx / NV, j = idx % NV;
        double a = 0.0;
        for (int m = 0; m < 32; ++m) a += (double)xl[m][i] * (double)xl[m][j];
        Gp[(size_t)p*NV*NV + idx] = a;
    }
    if (t < NV) {
        double a = 0.0;
        for (int m = 0; m < 32; ++m) a += (double)wl[m] * (double)xl[m][t];
        vp[(size_t)p*NV + t] = a;
    }
    if (t == 0) {
        double a = 0.0;
        for (int m = 0; m < 32; ++m) a += (double)wl[m] * (double)wl[m];
        Sp[p] = a;
    }
}

__global__ void k_qp_red(const double* __restrict__ Gp, const double* __restrict__ vp,
                         const double* __restrict__ Sp,
                         double* __restrict__ G, double* __restrict__ v, double* __restrict__ S) {
    int idx = blockIdx.x * 256 + threadIdx.x;
    if (idx < NV*NV) {
        double a = 0.0;
        for (int p = 0; p < NPART; ++p) a += Gp[(size_t)p*NV*NV + idx];
        G[idx] = a;
    }
    if (idx < NV) {
        double a = 0.0;
        for (int p = 0; p < NPART; ++p) a += vp[(size_t)p*NV + idx];
        v[idx] = a;
    }
    if (idx == 0) {
        double a = 0.0;
        for (int p = 0; p < NPART; ++p) a += Sp[p];
        S[0] = a;
    }
}

// qp_norm[b] = sqrt(0.25*Y^T G Y + Y.v + S)
__global__ __launch_bounds__(256) void k_qp_norm(const float* __restrict__ Y, const double* __restrict__ G,
                         const double* __restrict__ v, const double* __restrict__ S,
                         float* __restrict__ qp) {
    __shared__ float Yl[16][NV];
    __shared__ double tl[16][NV];
    int b0 = blockIdx.x * 16;
    int t = threadIdx.x;
    for (int idx = t; idx < 16*NV; idx += 256) Yl[idx/NV][idx%NV] = Y[(size_t)b0*NV + idx];
    __syncthreads();
    for (int idx = t; idx < 16*NV; idx += 256) {
        int m = idx / NV, i = idx % NV;
        double a = 0.0;
        for (int j = 0; j < NV; ++j) a += G[j*NV + i] * (double)Yl[m][j];  // G symmetric
        tl[m][i] = a;
    }
    __syncthreads();
    if (t < 16) {
        double a = 0.0, bv = 0.0;
        for (int i = 0; i < NV; ++i) { a += (double)Yl[t][i] * tl[t][i]; bv += (double)Yl[t][i] * v[i]; }
        double q = 0.25 * a + bv + S[0];
        qp[b0 + t] = (float)sqrt(q > 0.0 ? q : 0.0);
    }
}

// ---------------------------------------------------------------------------
// Fused GRU cell, B-reuse pairing + T4 counted-vmcnt 3-buffer pipeline.
// Per 32-wide K-step each thread issues EXACTLY 5 global_load_lds (2 A + 3 B).
// Stage 2 steps ahead into buf[(step+2)%3]; end-of-step waits vmcnt(5)
// (= newest stage still in flight) + raw s_barrier, so loads span barriers.
// XCD remap: xcd=bid&7 owns 4 m-blocks x all 8 n-strips -> act rows re-read
// only within one XCD's L2; weights stream via L3 (shared across XCDs).
#define GRUF_STEP(NSLOT, BUFI) do {                                              \
    char* Ah_ = lds + (BUFI) * 40960;                                            \
    char* Al_ = Ah_ + 8192;                                                      \
    char* Bb_ = Ah_ + 16384;                                                     \
    const int srow = lane & 15;                                                  \
    const int ksl = lane >> 4;                                                   \
    short8v ah[4], al[4];                                                        \
    _Pragma("unroll")                                                            \
    for (int fm = 0; fm < 4; ++fm) {                                             \
        int rr = wm * 64 + fm * 16 + srow;                                       \
        int off = rr * 64 + ((ksl ^ ((rr >> 1) & 3)) << 4);                      \
        ah[fm] = *(const short8v*)(Ah_ + off);                                   \
        al[fm] = *(const short8v*)(Al_ + off);                                   \
    }                                                                            \
    _Pragma("unroll")                                                            \
    for (int fn = 0; fn < 2; ++fn) {                                             \
        int rb = wn * 32 + fn * 16 + srow;                                       \
        int boff = rb * 64 + ((ksl ^ ((rb >> 1) & 3)) << 4);                     \
        short8v bfr = *(const short8v*)(Bb_ + boff);                             \
        short8v bfz = *(const short8v*)(Bb_ + 8192 + boff);                      \
        short8v bfn = *(const short8v*)(Bb_ + 16384 + boff);                     \
        _Pragma("unroll")                                                        \
        for (int fm = 0; fm < 4; ++fm) {                                         \
            acc[0][fn][fm] = __builtin_amdgcn_mfma_f32_16x16x32_bf16(ah[fm], bfr, acc[0][fn][fm], 0, 0, 0); \
            acc[0][fn][fm] = __builtin_amdgcn_mfma_f32_16x16x32_bf16(al[fm], bfr, acc[0][fn][fm], 0, 0, 0); \
            acc[1][fn][fm] = __builtin_amdgcn_mfma_f32_16x16x32_bf16(ah[fm], bfz, acc[1][fn][fm], 0, 0, 0); \
            acc[1][fn][fm] = __builtin_amdgcn_mfma_f32_16x16x32_bf16(al[fm], bfz, acc[1][fn][fm], 0, 0, 0); \
            acc[NSLOT][fn][fm] = __builtin_amdgcn_mfma_f32_16x16x32_bf16(ah[fm], bfn, acc[NSLOT][fn][fm], 0, 0, 0); \
            acc[NSLOT][fn][fm] = __builtin_amdgcn_mfma_f32_16x16x32_bf16(al[fm], bfn, acc[NSLOT][fn][fm], 0, 0, 0); \
        }                                                                        \
    }                                                                            \
} while (0)

#define GRUF_SYNC5 do {                                                          \
    asm volatile("s_waitcnt vmcnt(5)" ::: "memory");                             \
    __builtin_amdgcn_s_barrier();                                                \
    __builtin_amdgcn_sched_barrier(0);                                           \
} while (0)
#define GRUF_SYNC0 do {                                                          \
    asm volatile("s_waitcnt vmcnt(0)" ::: "memory");                             \
    __builtin_amdgcn_s_barrier();                                                \
    __builtin_amdgcn_sched_barrier(0);                                           \
} while (0)

__global__ __launch_bounds__(512, 2) void k_gruf(
        const u16* __restrict__ act,   // [NB][KCAT]: r filled + h_cur
        const u16* __restrict__ Wc,    // [3*1024][KWC]
        const float* __restrict__ bih, const float* __restrict__ bhh,
        u16* __restrict__ actn) {      // h_new -> h-section
    __shared__ char lds[122880];       // 3 x (A_hi 8K + A_lo 8K + B 24K)
    const int t = threadIdx.x;
    const int lane = t & 63;
    const int wid = t >> 6;          // 0..7
    const int wm = wid >> 2;         // 0..1
    const int wn = wid & 3;          // 0..3
    // grid 256: xcd = bid&7 gets 4 consecutive m-blocks x 8 n-strips
    const int bid = blockIdx.x;
    const int xcd = bid & 7;
    const int slot = bid >> 3;       // 0..31
    const int m0 = (xcd * 4 + (slot & 3)) * 128;
    const int n0 = (slot >> 2) * 128;

    f32x4 acc[4][2][4];
    #pragma unroll
    for (int i = 0; i < 4; ++i)
        #pragma unroll
        for (int j = 0; j < 2; ++j)
            #pragma unroll
            for (int k = 0; k < 4; ++k) {
                f32x4 z = {0.f, 0.f, 0.f, 0.f};
                acc[i][j][k] = z;
            }

    auto stage = [&](int step) {     // exactly 5 gl16 per thread
        char* Ah_ = lds + (step % 3) * 40960;
        char* Al_ = Ah_ + 8192;
        char* Bb_ = Ah_ + 16384;
        const int hiOff = (step < NSTEP_R) ? step * 32 : step * 32 + 1088;
        const int loOff = hiOff + ((step < NSTEP_R) ? 1088 : 1024);
        const int wOff = step * 32;
        {
            int s = (wid << 6) + lane;
            int rr = s >> 2;
            int kq = ((lane & 3) ^ ((rr >> 1) & 3)) << 3;
            gl16(act + (size_t)(m0 + rr) * KCAT + hiOff + kq, Ah_ + wid * 1024);
            gl16(act + (size_t)(m0 + rr) * KCAT + loOff + kq, Al_ + wid * 1024);
        }
        #pragma unroll
        for (int q = 0; q < 3; ++q) {
            int cb = q * 8 + wid;
            int s2 = (cb << 6) + lane;
            int rbg = s2 >> 2;
            int kq = ((lane & 3) ^ ((rbg >> 1) & 3)) << 3;
            gl16(Wc + (size_t)((rbg >> 7) * 1024 + n0 + (rbg & 127)) * KWC + wOff + kq,
                 Bb_ + cb * 1024);
        }
    };

    // prologue: stage 0 and 1; wait stage(0) (5 newest = stage(1) in flight)
    stage(0);
    stage(1);
    GRUF_SYNC5;
    for (int step = 0; step < NSTEP_R; ++step) {       // r-part: n-gate -> i_n
        stage(step + 2);                               // step+2 <= 35 < 66
        GRUF_STEP(2, step % 3);
        GRUF_SYNC5;
    }
    for (int step = NSTEP_R; step < NSTEPS; ++step) {  // h-part: n-gate -> h_n
        if (step + 2 < NSTEPS) {
            stage(step + 2);
            GRUF_STEP(3, step % 3);
            GRUF_SYNC5;
        } else {
            GRUF_STEP(3, step % 3);
            GRUF_SYNC0;
        }
    }

    #pragma unroll
    for (int fn = 0; fn < 2; ++fn) {
        const int jj = n0 + wn * 32 + fn * 16 + (lane & 15);
        const float bir = bih[jj],        bhr = bhh[jj];
        const float biz = bih[1024 + jj], bhz = bhh[1024 + jj];
        const float bin = bih[2048 + jj], bhn = bhh[2048 + jj];
        #pragma unroll
        for (int fm = 0; fm < 4; ++fm) {
            #pragma unroll
            for (int rg = 0; rg < 4; ++rg) {
                int m = m0 + wm * 64 + fm * 16 + (lane >> 4) * 4 + rg;
                float rz = acc[0][fn][fm][rg];
                float zz = acc[1][fn][fm][rg];
                float inn = acc[2][fn][fm][rg];
                float hnn = acc[3][fn][fm][rg];
                float rgate = 1.f / (1.f + expf(-(rz + bir + bhr)));
                float zgate = 1.f / (1.f + expf(-(zz + biz + bhz)));
                float ngate = tanhf(inn + bin + rgate * (hnn + bhn));
                size_t base = (size_t)m * KCAT + HOFF;
                float hv = b2f(act[base + jj]) + b2f(act[base + HIDD + jj]);
                float hnew = (1.f - zgate) * ngate + zgate * hv;
                u16 nh = f2b(hnew);
                actn[base + jj] = nh;
                actn[base + HIDD + jj] = f2b(hnew - b2f(nh));
            }
        }
    }
}

// out = h_new @ W_out^T + b_out, pairing structure; M=4096 N=384 K=1024.
__global__ __launch_bounds__(512, 2) void k_outp(
        const u16* __restrict__ act, const u16* __restrict__ Wo,
        const float* __restrict__ bo, float* __restrict__ outb) {
    __shared__ char lds[49152];        // 2 x (A_hi 8K + A_lo 8K + B 8K)
    const int t = threadIdx.x;
    const int lane = t & 63;
    const int wid = t >> 6;
    const int wm = wid >> 2;           // 0..1
    const int wn = wid & 3;            // 0..3
    const int m0 = blockIdx.x * 128;
    const int n0 = blockIdx.y * 128;
    f32x4 acc[2][4];
    #pragma unroll
    for (int i = 0; i < 2; ++i)
        #pragma unroll
        for (int j = 0; j < 4; ++j) {
            f32x4 z = {0.f, 0.f, 0.f, 0.f};
            acc[i][j] = z;
        }

    auto stage = [&](int step, int buf) {
        char* Ah_ = lds + buf * 24576;
        char* Al_ = Ah_ + 8192;
        char* Bb_ = Ah_ + 16384;
        const int hiOff = HOFF + step * 32;
        const int loOff = HOFF + HIDD + step * 32;
        int s = (wid << 6) + lane;
        int rr = s >> 2;
        int kq = ((lane & 3) ^ ((rr >> 1) & 3)) << 3;
        gl16(act + (size_t)(m0 + rr) * KCAT + hiOff + kq, Ah_ + wid * 1024);
        gl16(act + (size_t)(m0 + rr) * KCAT + loOff + kq, Al_ + wid * 1024);
        gl16(Wo + (size_t)(n0 + rr) * KWO + step * 32 + kq, Bb_ + wid * 1024);
    };

    stage(0, 0);
    __syncthreads();
    int cur = 0;
    for (int step = 0; step < 32; ++step) {
        if (step + 1 < 32) stage(step + 1, cur ^ 1);
        {
            char* Ah_ = lds + cur * 24576;
            char* Al_ = Ah_ + 8192;
            char* Bb_ = Ah_ + 16384;
            const int srow = lane & 15;
            const int ksl = lane >> 4;
            short8v ah[4], al[4];
            #pragma unroll
            for (int fm = 0; fm < 4; ++fm) {
                int rr = wm * 64 + fm * 16 + srow;
                int off = rr * 64 + ((ksl ^ ((rr >> 1) & 3)) << 4);
                ah[fm] = *(const short8v*)(Ah_ + off);
                al[fm] = *(const short8v*)(Al_ + off);
            }
            #pragma unroll
            for (int fn = 0; fn < 2; ++fn) {
                int rb = wn * 32 + fn * 16 + srow;
                int boff = rb * 64 + ((ksl ^ ((rb >> 1) & 3)) << 4);
                short8v bf = *(const short8v*)(Bb_ + boff);
                #pragma unroll
                for (int fm = 0; fm < 4; ++fm) {
                    acc[fn][fm] = __builtin_amdgcn_mfma_f32_16x16x32_bf16(ah[fm], bf, acc[fn][fm], 0, 0, 0);
                    acc[fn][fm] = __builtin_amdgcn_mfma_f32_16x16x32_bf16(al[fm], bf, acc[fn][fm], 0, 0, 0);
                }
            }
        }
        __syncthreads();
        cur ^= 1;
    }
    #pragma unroll
    for (int fn = 0; fn < 2; ++fn) {
        int n = n0 + wn * 32 + fn * 16 + (lane & 15);
        if (n < NOUTD) {
            float bb = bo[n];
            #pragma unroll
            for (int fm = 0; fm < 4; ++fm) {
                #pragma unroll
                for (int rg = 0; rg < 4; ++rg) {
                    int m = m0 + wm * 64 + fm * 16 + (lane >> 4) * 4 + rg;
                    outb[(size_t)m * NOUTP + n] = acc[fn][fm][rg] + bb;
                }
            }
        }
    }
}

// s_fin/lam_fin (+ in-place state update) and fixed-point residual norm
__global__ __launch_bounds__(256) void k_fin(const float* __restrict__ snew, const float* __restrict__ lamn,
                     const float* __restrict__ outb,
                     float* __restrict__ s, float* __restrict__ lam,
                     float* __restrict__ fx) {
    __shared__ float redS[16][17];
    __shared__ float redL[16][17];
    int b0 = blockIdx.x * 16;
    int tm = threadIdx.x / 16;
    int tk = threadIdx.x % 16;
    int b = b0 + tm;
    float ds2 = 0.f, dl2 = 0.f;
    for (int k = tk; k < NCN; k += 16) {
        float o = outb[(size_t)b*NOUTP + k];
        float sf = fmaxf(0.f, snew[(size_t)b*NCN + k] + o);
        float so = s[(size_t)b*NCN + k];
        s[(size_t)b*NCN + k] = sf;
        float d = so - sf;
        ds2 += d * d;
    }
    for (int i = tk; i < NV; i += 16) {
        float o = outb[(size_t)b*NOUTP + NCN + i];
        float lf = lamn[(size_t)b*NV + i] + o;
        float lo = lam[(size_t)b*NV + i];
        lam[(size_t)b*NV + i] = lf;
        float d = lo - lf;
        dl2 += d * d;
    }
    redS[tm][tk] = ds2;
    redL[tm][tk] = dl2;
    __syncthreads();
    if (tk == 0) {
        float a = 0.f, l = 0.f;
        for (int q = 0; q < 16; ++q) { a += redS[tm][q]; l += redL[tm][q]; }
        fx[b] = sqrtf(l) + sqrtf(a);
    }
}

// ---------------------------------------------------------------------------
extern "C" void kernel_launch(void* const* d_in, const int* in_sizes, int n_in,
                              void* d_out, int out_size, void* d_ws, size_t ws_size,
                              hipStream_t stream) {
    const float* lamda_init = (const float*)d_in[0];
    // d_in[1] = s_init (unused: multiplied by 0 in reference)
    const float* h0    = (const float*)d_in[2];
    const float* H     = (const float*)d_in[3];
    const float* g     = (const float*)d_in[4];
    const float* C     = (const float*)d_in[5];
    const float* c     = (const float*)d_in[6];
    const float* W_ih  = (const float*)d_in[7];
    const float* b_ih  = (const float*)d_in[8];
    const float* W_hh  = (const float*)d_in[9];
    const float* b_hh  = (const float*)d_in[10];
    const float* W_out = (const float*)d_in[11];
    const float* b_out = (const float*)d_in[12];

    float* out    = (float*)d_out;
    float* xi_out = out;                       // [B,120]
    float* primal = out + (size_t)NB*NV;       // [8,B]
    float* fixedo = primal + (size_t)NITER*NB; // [8,B]
    float* qpres  = fixedo + (size_t)NITER*NB; // [8,B]

    char* wp = (char*)d_ws;
    auto alloc = [&](size_t bytes) {
        void* p = (void*)wp;
        wp += (bytes + 255) & ~(size_t)255;
        return p;
    };
    float* Amat  = (float*)alloc(NV*NV*4);
    float* A0m   = (float*)alloc(NV*NV*4);
    float* Qinv  = (float*)alloc(NV*NV*4);
    float* Qinv0 = (float*)alloc(NV*NV*4);
    float* s0v   = (float*)alloc(NCN*4);
    float* sbuf  = (float*)alloc((size_t)NB*NCN*4);
    float* snew  = (float*)alloc((size_t)NB*NCN*4);
    float* lam   = (float*)alloc((size_t)NB*NV*4);
    float* lamn  = (float*)alloc((size_t)NB*NV*4);
    float* xib   = (float*)alloc((size_t)NB*NV*4);
    float* Yb    = (float*)alloc((size_t)NB*NV*4);
    float* wb    = (float*)alloc(NB*4);
    float* outb  = (float*)alloc((size_t)NB*NOUTP*4);
    u16* actA    = (u16*)alloc((size_t)NB*KCAT*2);
    u16* actB    = (u16*)alloc((size_t)NB*KCAT*2);
    u16* Wcat    = (u16*)alloc((size_t)3072*KWC*2);
    u16* Wopk    = (u16*)alloc((size_t)NOUTP*KWO*2);
    double* Gpart = (double*)alloc((size_t)NPART*NV*NV*8);
    double* vpart = (double*)alloc((size_t)NPART*NV*8);
    double* Spart = (double*)alloc(NPART*8);
    double* Gfin  = (double*)alloc(NV*NV*8);
    double* vfin  = (double*)alloc(NV*8);
    double* Sfin  = (double*)alloc(8);

    k_buildA<<<dim3(NV, 2), dim3(128), 0, stream>>>(H, C, Amat, A0m);
    k_invert<<<dim3(2), dim3(1024), 0, stream>>>(Amat, A0m, Qinv, Qinv0);
    k_s0<<<dim3(1), dim3(256), 0, stream>>>(Qinv0, g, C, c, s0v);
    k_init<<<dim3(NB/8), dim3(256), 0, stream>>>(s0v, lamda_init, sbuf, lam);
    k_packWcat<<<dim3(3072), dim3(256), 0, stream>>>(W_ih, W_hh, Wcat);
    k_packWo<<<dim3(NOUTP), dim3(256), 0, stream>>>(W_out, Wopk);
    k_packH<<<dim3(NB), dim3(256), 0, stream>>>(h0, actA);

    u16* hc = actA;
    u16* hn2 = actB;
    for (int it = 0; it < NITER; ++it) {
        k_xiproj<<<dim3(NB/16), dim3(512), 0, stream>>>(sbuf, lam, C, c, g, Qinv, H,
                                                        xib, Yb, wb, snew, lamn, hc,
                                                        primal + (size_t)it*NB);
        k_qp_part<<<dim3(NPART), dim3(256), 0, stream>>>(xib, wb, Gpart, vpart, Spart);
        k_qp_red<<<dim3((NV*NV + 255)/256), dim3(256), 0, stream>>>(Gpart, vpart, Spart, Gfin, vfin, Sfin);
        k_qp_norm<<<dim3(NB/16), dim3(256), 0, stream>>>(Yb, Gfin, vfin, Sfin, qpres + (size_t)it*NB);
        k_gruf<<<dim3(256), dim3(512), 0, stream>>>(hc, Wcat, b_ih, b_hh, hn2);
        k_outp<<<dim3(NB/128, 3), dim3(512), 0, stream>>>(hn2, Wopk, b_out, outb);
        k_fin<<<dim3(NB/16), dim3(256), 0, stream>>>(snew, lamn, outb, sbuf, lam, fixedo + (size_t)it*NB);
        u16* tmp = hc; hc = hn2; hn2 = tmp;
    }
    hipMemcpyAsync(xi_out, xib, (size_t)NB*NV*sizeof(float), hipMemcpyDeviceToDevice, stream);
}